// Round 13
// baseline (448.666 us; speedup 1.0000x reference)
//
#include <hip/hip_runtime.h>

// ---------------------------------------------------------------------------
// MiniMax-M1 Lightning Attention forward, MI355X / gfx950.
//   0. castk3: fp32->bf16 for hidden + w_qkv + w_gate in ONE launch
//   1. fused qkv+gate via 256x256 lockstep GEMM (R11 rotated-read schedule)
//      epilogue: q,k,gate row-major; v -> vT directly; k ALSO -> kTs
//      (kTs[d][m] = silu_k * exp(-s*(255-m)), replacing the transpose_k kernel)
//   3. KVT_j = vT @ kTs^T  (= KV_j^T, fp32)
//   4. scan: S_{j+1} = e^{-256 s} S_j + KV_j ; store S_j^T bf16  [512 WGs]
//   5+6 FUSED (fused_pv): inter (q@S^T, q_decay) + per-32-kv-chunk P in-reg
//      -> LDS round-trip -> acc += P@v   (no global P buffer)
//   7. y = gate * rmsnorm(attn) * norm_w
//   8. out = y @ w_out^T via same 256 GEMM [fp32 -> d_out]
// Workspace: 7 slots x 33,554,432 B = 234,881,024 B peak.
// ---------------------------------------------------------------------------

typedef unsigned short u16;
typedef __bf16 bf16x8 __attribute__((ext_vector_type(8)));
typedef float f32x4 __attribute__((ext_vector_type(4)));

#define SEQ 4096
#define HID 2048

__device__ __forceinline__ u16 f2bf(float f) {
    union { float f; unsigned u; } v; v.f = f;
    unsigned r = v.u + 0x7fffu + ((v.u >> 16) & 1u);   // round-to-nearest-even
    return (u16)(r >> 16);
}
__device__ __forceinline__ float bf2f(u16 u) {
    union { unsigned u; float f; } v; v.u = ((unsigned)u) << 16; return v.f;
}

// async global->LDS, 16B per lane; lds dest must be wave-uniform base (+lane*16)
typedef __attribute__((address_space(1))) unsigned char gas_u8;
typedef __attribute__((address_space(3))) unsigned char las_u8;
__device__ __forceinline__ void gld16(const void* g, void* l) {
    __builtin_amdgcn_global_load_lds((gas_u8*)g, (las_u8*)l, 16, 0, 0);
}

// ---------------------------------------------------------------------------
// fp32 -> bf16 casts.  castk: single region.  castk3: hidden|w_qkv|w_gate
// fused into one launch (region-select on blockIdx; 4 elems/thread).
// ---------------------------------------------------------------------------
__global__ __launch_bounds__(256) void castk(const float* __restrict__ in,
                                             u16* __restrict__ out) {
    const size_t i = (size_t)blockIdx.x * 256 + threadIdx.x;
    const float4 f = *(const float4*)&in[i * 4];
    uint2 o;
    o.x = (unsigned)f2bf(f.x) | ((unsigned)f2bf(f.y) << 16);
    o.y = (unsigned)f2bf(f.z) | ((unsigned)f2bf(f.w) << 16);
    *(uint2*)&out[i * 4] = o;
}

__global__ __launch_bounds__(256) void castk3(const float* __restrict__ a, u16* __restrict__ ao,
                                              const float* __restrict__ b, u16* __restrict__ bo,
                                              const float* __restrict__ c, u16* __restrict__ co) {
    const int bid = blockIdx.x;
    const float* src; u16* dst; size_t i;
    if (bid < 16384)      { src = a; dst = ao; i = (size_t)bid * 256 + threadIdx.x; }
    else if (bid < 28672) { src = b; dst = bo; i = (size_t)(bid - 16384) * 256 + threadIdx.x; }
    else                  { src = c; dst = co; i = (size_t)(bid - 28672) * 256 + threadIdx.x; }
    const float4 f = *(const float4*)&src[i * 4];
    uint2 o;
    o.x = (unsigned)f2bf(f.x) | ((unsigned)f2bf(f.y) << 16);
    o.y = (unsigned)f2bf(f.z) | ((unsigned)f2bf(f.w) << 16);
    *(uint2*)&dst[i * 4] = o;
}

// ---------------------------------------------------------------------------
// 256x256-tile lockstep pipelined NT GEMM (R11 rotated-read schedule).
// MODE 0: fused QKV+gate epilogue (q,k row-major; vT; kTs; gate); MODE 1: f32.
// ---------------------------------------------------------------------------
template <int MODE>
__global__ __launch_bounds__(512, 2) void gemm256(const u16* __restrict__ A,
                                                  const u16* __restrict__ Bm,
                                                  void* __restrict__ Cv,
                                                  void* __restrict__ aux,
                                                  void* __restrict__ aux2,
                                                  u16* __restrict__ kTs,
                                                  const float* __restrict__ slope) {
    constexpr int NTN = (MODE == 0) ? 32 : 8;     // tiles along N
    constexpr int NT  = 32;                       // K tiles (2048 / 64)
    extern __shared__ u16 smem[];                 // [2][A 16384 | B 16384]

    // XCD swizzle: 8 XCDs; per-XCD 4-row x 8-col rectangular supertiles
    const int bid = blockIdx.x;
    const int xcd = bid & 7, l = bid >> 3;
    int tm, tn;
    if constexpr (MODE == 0) {       // 32x32 tile grid, 128 WGs per XCD
        tm = xcd * 4 + (l & 3);
        tn = ((l >> 2) & 7) | ((l >> 5) << 3);
    } else {                         // 32x8 grid, 32 WGs per XCD (4x8 rect)
        const int wgid = xcd * 32 + l;
        tm = wgid / NTN; tn = wgid % NTN;
    }

    const int tid  = threadIdx.x;
    const int lane = tid & 63, wv = tid >> 6;
    const int quad = lane >> 4, cl = lane & 15;
    const int wm = (wv & 1) * 128, wn = (wv >> 1) * 64;

    const int srw  = tid >> 3;
    const int colo = ((tid & 7) ^ (srw & 7)) * 8;
    const u16* gA0 = A  + (size_t)(tm * 256 + srw) * HID + colo;
    const u16* gB0 = Bm + (size_t)(tn * 256 + srw) * HID + colo;

    const int x0 = ((quad       ^ (cl & 7)) * 8);
    const int x1 = (((4 + quad) ^ (cl & 7)) * 8);

    f32x4 acc[8][4];
    const f32x4 zero = {0.f, 0.f, 0.f, 0.f};
    #pragma unroll
    for (int a = 0; a < 8; a++)
        #pragma unroll
        for (int b = 0; b < 4; b++) acc[a][b] = zero;

    bf16x8 af[8], b0[4], b1[4];

    auto STG = [&](int kt, int mat, int hh) {   // stage one 128x64 half-tile
        const u16* g = (mat ? gB0 : gA0) + (size_t)(hh * 128) * HID + kt * 64;
        u16* lp = smem + (kt & 1) * 32768 + mat * 16384 + hh * 8192 + wv * 512;
        gld16(g, lp);
        gld16(g + (size_t)64 * HID, lp + 4096);
    };
    auto LDA = [&](int qm, int ab) {
        #pragma unroll
        for (int mi = 0; mi < 4; mi++) {
            const int rr = (wm + qm * 64 + mi * 16 + cl) * 64 + ab;
            af[mi * 2 + 0] = *(const bf16x8*)&smem[rr + x0];
            af[mi * 2 + 1] = *(const bf16x8*)&smem[rr + x1];
        }
    };
    auto LDB = [&](bf16x8* d, int qn, int bb2) {
        #pragma unroll
        for (int ni = 0; ni < 2; ni++) {
            const int rr = (wn + qn * 32 + ni * 16 + cl) * 64 + bb2;
            d[ni * 2 + 0] = *(const bf16x8*)&smem[rr + x0];
            d[ni * 2 + 1] = *(const bf16x8*)&smem[rr + x1];
        }
    };
    auto MM = [&](int qm, int qn, const bf16x8* bv) {
        #pragma unroll
        for (int mi = 0; mi < 4; mi++)
            #pragma unroll
            for (int ni = 0; ni < 2; ni++) {
                f32x4 c = acc[qm * 4 + mi][qn * 2 + ni];
                c = __builtin_amdgcn_mfma_f32_16x16x32_bf16(af[mi * 2 + 0], bv[ni * 2 + 0], c, 0, 0, 0);
                c = __builtin_amdgcn_mfma_f32_16x16x32_bf16(af[mi * 2 + 1], bv[ni * 2 + 1], c, 0, 0, 0);
                acc[qm * 4 + mi][qn * 2 + ni] = c;
            }
    };

    // prologue: issue stream per tile = B.lo, B.hi, A.lo, A.hi
    STG(0, 1, 0); STG(0, 1, 1); STG(0, 0, 0); STG(0, 0, 1);
    STG(1, 1, 0); STG(1, 1, 1); STG(1, 0, 0);
    asm volatile("s_waitcnt vmcnt(6)" ::: "memory");   // tile 0 resident
    __builtin_amdgcn_s_barrier();
    LDA(0, 0); LDB(b0, 0, 16384);      // ph0 operands (drain at ph0 lgkm(0))

    #pragma unroll 2
    for (int t = 0; t < NT; ++t) {
        const int ab  = (t & 1) * 32768;
        const int bb2 = ab + 16384;
        const int nab = ((t + 1) & 1) * 32768;
        // phase 0: MM(0,0)=A0*b0 (reads from prev ph3/prologue); read b1
        if (t + 1 < NT) STG(t + 1, 0, 1);
        __builtin_amdgcn_s_barrier();
        asm volatile("s_waitcnt lgkmcnt(0)" ::: "memory");
        __builtin_amdgcn_s_setprio(1); MM(0, 0, b0); __builtin_amdgcn_s_setprio(0);
        LDB(b1, 1, bb2);
        __builtin_amdgcn_s_barrier();
        // phase 1: MM(0,1)=A0*b1; read A1
        if (t + 2 < NT) STG(t + 2, 1, 0);
        __builtin_amdgcn_s_barrier();
        asm volatile("s_waitcnt lgkmcnt(0)" ::: "memory");
        __builtin_amdgcn_s_setprio(1); MM(0, 1, b1); __builtin_amdgcn_s_setprio(0);
        LDA(1, ab);
        __builtin_amdgcn_s_barrier();
        // phase 2: MM(1,1)=A1*b1
        if (t + 2 < NT) STG(t + 2, 1, 1);
        __builtin_amdgcn_s_barrier();
        asm volatile("s_waitcnt lgkmcnt(0)" ::: "memory");
        __builtin_amdgcn_s_setprio(1); MM(1, 1, b1); __builtin_amdgcn_s_setprio(0);
        __builtin_amdgcn_s_barrier();
        // phase 3: MM(1,0)=A1*b0; boundary vmcnt(6); post-MFMA next A0,b0
        if (t + 2 < NT) {
            STG(t + 2, 0, 0);
            asm volatile("s_waitcnt vmcnt(6)" ::: "memory");
        } else {
            asm volatile("s_waitcnt vmcnt(0)" ::: "memory");
        }
        __builtin_amdgcn_s_barrier();
        __builtin_amdgcn_s_setprio(1); MM(1, 0, b0); __builtin_amdgcn_s_setprio(0);
        if (t + 1 < NT) { LDA(0, nab); LDB(b0, 0, nab + 16384); }
        __builtin_amdgcn_s_barrier();
    }

    // epilogue
    if constexpr (MODE == 0) {
        const int grp = tn * 2 + (wn >> 7);
        const int which = grp >> 4, hd = grp & 15;
        const int n64 = wn & 64;
        if (which == 2) {
            // vT[bz][d][m]: lane holds 4 consecutive m at fixed d -> uint2
            const size_t bz = (size_t)((tm >> 4) * 256 + hd * 16 + (tm & 15));
            u16* tdst = (u16*)aux + bz * 32768;
            #pragma unroll
            for (int a = 0; a < 8; a++) {
                const int mm = wm + (a >> 2) * 64 + (a & 3) * 16 + quad * 4;
                #pragma unroll
                for (int b = 0; b < 4; b++) {
                    const int d = n64 + (b >> 1) * 32 + (b & 1) * 16 + cl;
                    u16 p[4];
                    #pragma unroll
                    for (int r = 0; r < 4; r++) {
                        const float x = acc[a][b][r];
                        p[r] = f2bf(x / (1.f + __expf(-x)));
                    }
                    uint2 pk;
                    pk.x = (unsigned)p[0] | ((unsigned)p[1] << 16);
                    pk.y = (unsigned)p[2] | ((unsigned)p[3] << 16);
                    *(uint2*)&tdst[(size_t)d * 256 + mm] = pk;
                }
            }
            return;
        }
        u16* dst = (which == 0) ? (u16*)Cv
                 : (which == 1) ? (u16*)Cv + (size_t)16777216   // k slot (S1)
                                : (u16*)aux2;                   // gate slot
        #pragma unroll
        for (int a = 0; a < 8; a++)
            #pragma unroll
            for (int b = 0; b < 4; b++)
                #pragma unroll
                for (int r = 0; r < 4; r++) {
                    const int m = tm * 256 + wm + (a >> 2) * 64 + (a & 3) * 16 + quad * 4 + r;
                    const int col = hd * 128 + n64 + (b >> 1) * 32 + (b & 1) * 16 + cl;
                    const float x = acc[a][b][r];
                    const float v = (which == 3) ? 1.f / (1.f + __expf(-x))
                                                 : x / (1.f + __expf(-x));
                    dst[(size_t)m * HID + col] = f2bf(v);
                }
        if (which == 1) {
            // ALSO emit kTs[bz][d][m] = silu_k * exp(-s*(255-m))
            // (replaces the transpose_k kernel; same uint2 pattern as vT)
            const float s_ = slope[hd];
            const size_t bz = (size_t)((tm >> 4) * 256 + hd * 16 + (tm & 15));
            u16* tdst = kTs + bz * 32768;
            #pragma unroll
            for (int a = 0; a < 8; a++) {
                const int mm = wm + (a >> 2) * 64 + (a & 3) * 16 + quad * 4;
                #pragma unroll
                for (int b = 0; b < 4; b++) {
                    const int d = n64 + (b >> 1) * 32 + (b & 1) * 16 + cl;
                    u16 p[4];
                    #pragma unroll
                    for (int r = 0; r < 4; r++) {
                        const float x = acc[a][b][r];
                        const float sv = x / (1.f + __expf(-x));
                        p[r] = f2bf(sv * __expf(-s_ * (float)(255 - (mm + r))));
                    }
                    uint2 pk;
                    pk.x = (unsigned)p[0] | ((unsigned)p[1] << 16);
                    pk.y = (unsigned)p[2] | ((unsigned)p[3] << 16);
                    *(uint2*)&tdst[(size_t)d * 256 + mm] = pk;
                }
            }
        }
        return;
    } else {
        float* C = (float*)Cv;
        #pragma unroll
        for (int a = 0; a < 8; a++)
            #pragma unroll
            for (int b = 0; b < 4; b++)
                #pragma unroll
                for (int r = 0; r < 4; r++) {
                    const int m = tm * 256 + wm + (a >> 2) * 64 + (a & 3) * 16 + quad * 4 + r;
                    const int n = tn * 256 + wn + (b >> 1) * 32 + (b & 1) * 16 + cl;
                    C[(size_t)m * HID + n] = acc[a][b][r];
                }
    }
}

// ---------------------------------------------------------------------------
// Generic 128x128-tile NT GEMM (kept for M_KVT).
// ---------------------------------------------------------------------------
#define M_KVT   4

template <int MODE>
__global__ __launch_bounds__(256) void gemm_nt(const u16* __restrict__ A,
                                               const u16* __restrict__ Bm,
                                               void* __restrict__ Cv,
                                               const float* __restrict__ slope,
                                               int bz0,
                                               void* __restrict__ aux,
                                               void* __restrict__ aux2) {
    const int tid = threadIdx.x;
    const int bz  = blockIdx.z + bz0;

    __shared__ u16 smem[8192];            // As/Bs staging, 16,384 B
    u16 (*As)[32] = (u16(*)[32])smem;
    u16 (*Bs)[32] = (u16(*)[32])(smem + 4096);

    const int lane = tid & 63, wv = tid >> 6;
    const int wm = (wv & 1) * 64, wn = (wv >> 1) * 64;
    const int quad = lane >> 4, cl = lane & 15;
    const int lr = lane >> 2;
    const int lc = (lane & 3) * 8;
    u16* lA = &As[wv * 32][0];
    u16* lB = &Bs[wv * 32][0];

    f32x4 acc[4][4];
    const f32x4 zero = {0.f, 0.f, 0.f, 0.f};
    #pragma unroll
    for (int mi = 0; mi < 4; mi++)
        #pragma unroll
        for (int ni = 0; ni < 4; ni++) acc[mi][ni] = zero;

    // M_KVT: A = vT[bz], B = kTs[bz], both ld 256, kmax 256
    const u16* Ab = A + (size_t)bz * 32768;
    const u16* Bb = Bm + (size_t)bz * 32768;
    const u16* gA = Ab + (size_t)(wv * 32 + lr) * 256 + lc;
    const u16* gB = Bb + (size_t)(wv * 32 + lr) * 256 + lc;

    for (int k0 = 0; k0 < 256; k0 += 32) {
        __syncthreads();
        gld16(gA + k0,                  lA);
        gld16(gA + k0 + (size_t)16 * 256, lA + 16 * 32);
        gld16(gB + k0,                  lB);
        gld16(gB + k0 + (size_t)16 * 256, lB + 16 * 32);
        __syncthreads();
        const int ko = quad * 8;
        bf16x8 af[4], bfv[4];
        #pragma unroll
        for (int mi = 0; mi < 4; mi++) af[mi] = *(const bf16x8*)&As[wm + mi * 16 + cl][ko];
        #pragma unroll
        for (int ni = 0; ni < 4; ni++) bfv[ni] = *(const bf16x8*)&Bs[wn + ni * 16 + cl][ko];
        #pragma unroll
        for (int mi = 0; mi < 4; mi++)
            #pragma unroll
            for (int ni = 0; ni < 4; ni++)
                acc[mi][ni] = __builtin_amdgcn_mfma_f32_16x16x32_bf16(af[mi], bfv[ni], acc[mi][ni], 0, 0, 0);
    }

    #pragma unroll
    for (int mi = 0; mi < 4; mi++)
        #pragma unroll
        for (int ni = 0; ni < 4; ni++)
            #pragma unroll
            for (int r = 0; r < 4; r++) {
                const int m = wm + mi * 16 + quad * 4 + r;
                const int n = wn + ni * 16 + cl;
                ((float*)Cv)[(size_t)bz * 16384 + m * 128 + n] = acc[mi][ni][r];
            }
}

// ---------------------------------------------------------------------------
// FUSED P+INTRA: grid (2,1,512) = (row-half tm, -, bz); 256 thr = 4 waves 2x2.
// ---------------------------------------------------------------------------
__global__ __launch_bounds__(256) void fused_pv(const u16* __restrict__ qb,
                                                const u16* __restrict__ kb,
                                                const u16* __restrict__ ST,
                                                const u16* __restrict__ vT,
                                                u16* __restrict__ attn,
                                                const float* __restrict__ slope) {
    __shared__ u16 smem[28672];   // q 16384 | k 4096 | P 4096 | Bs 4096
    u16* q_lds = smem;            // [4][128][32]
    u16* k_lds = smem + 16384;    // [32][128] row-XOR swizzled
    u16* P_lds = smem + 20480;    // [128][32]
    u16* Bs    = smem + 24576;    // [128][32]

    const int tm = blockIdx.x;           // row half within the 256-block
    const int bz = blockIdx.z;
    const int bb = bz >> 8, hh = (bz >> 4) & 15, jb = bz & 15;
    const float s_ = slope[hh];

    const int tid  = threadIdx.x;
    const int lane = tid & 63, wv = tid >> 6;
    const int quad = lane >> 4, cl = lane & 15;
    const int wm = (wv & 1) * 64, wn = (wv >> 1) * 64;
    const int lr = lane >> 2, lc = (lane & 3) * 8;
    const int pcb = (wv >> 1) * 16;      // P kv-col base for this wave

    const size_t rowbase = (size_t)(bb * SEQ + jb * 256);

    // ---- stage q: 4 ks x 2 gld16 (gemm_nt A-tile pattern, linear) ----
    const u16* gq = qb + (rowbase + tm * 128 + wv * 32 + lr) * HID + hh * 128 + lc;
    u16* lq = q_lds + wv * 1024 + lr * 32 + lc;
    #pragma unroll
    for (int ks = 0; ks < 4; ks++) {
        gld16(gq + ks * 32,                 lq + ks * 4096);
        gld16(gq + ks * 32 + 16 * HID,      lq + ks * 4096 + 512);
    }

    f32x4 acc[4][4];
    const f32x4 zero = {0.f, 0.f, 0.f, 0.f};
    #pragma unroll
    for (int mi = 0; mi < 4; mi++)
        #pragma unroll
        for (int ni = 0; ni < 4; ni++) acc[mi][ni] = zero;

    // ---- inter: acc = q @ S^T ----
    const u16* gS = ST + (size_t)bz * 16384 + (size_t)(wv * 32 + lr) * 128 + lc;
    u16* lB = Bs + wv * 1024 + lr * 32 + lc;
    #pragma unroll
    for (int ks = 0; ks < 4; ks++) {
        __syncthreads();
        gld16(gS + ks * 32,            lB);
        gld16(gS + ks * 32 + 16 * 128, lB + 512);
        __syncthreads();
        bf16x8 af[4], bfv[4];
        #pragma unroll
        for (int mi = 0; mi < 4; mi++)
            af[mi] = *(const bf16x8*)&q_lds[ks * 4096 + (wm + mi * 16 + cl) * 32 + quad * 8];
        #pragma unroll
        for (int ni = 0; ni < 4; ni++)
            bfv[ni] = *(const bf16x8*)&Bs[(wn + ni * 16 + cl) * 32 + quad * 8];
        #pragma unroll
        for (int mi = 0; mi < 4; mi++)
            #pragma unroll
            for (int ni = 0; ni < 4; ni++)
                acc[mi][ni] = __builtin_amdgcn_mfma_f32_16x16x32_bf16(af[mi], bfv[ni], acc[mi][ni], 0, 0, 0);
    }
    // q_decay scale
    #pragma unroll
    for (int mi = 0; mi < 4; mi++)
        #pragma unroll
        for (int r = 0; r < 4; r++) {
            const int m = tm * 128 + wm + mi * 16 + quad * 4 + r;
            const float qd = __expf(-s_ * (float)(m + 1));
            #pragma unroll
            for (int ni = 0; ni < 4; ni++) acc[mi][ni][r] *= qd;
        }

    // ---- intra: per 32-kv chunk, compute P then acc += P@v ----
    const int kmax = (tm == 0) ? 128 : 256;
    const u16* gV = vT + (size_t)bz * 32768 + (size_t)(wv * 32 + lr) * 256 + lc;
    // k staging addresses (row-XOR pre-swizzled global source, linear dest)
    const int krow = tid >> 4;                       // 0..15 per issue
    const int kcol = (((tid & 15) ^ (krow & 7)) * 8);
    u16* lk = k_lds + wv * 512 + lane * 8;
    const int kvr = pcb + cl;                        // this lane's P kv-row for B-frag

    for (int kv0 = 0; kv0 < kmax; kv0 += 32) {
        __syncthreads();
        gld16(kb + (rowbase + kv0 +      krow) * HID + hh * 128 + kcol, lk);
        gld16(kb + (rowbase + kv0 + 16 + krow) * HID + hh * 128 + kcol, lk + 2048);
        gld16(gV + kv0,            lB);
        gld16(gV + kv0 + 16 * 256, lB + 512);
        __syncthreads();
        // P-GEMM: C[m(64 rows @wm)][kv(16 cols @pcb)] over d=128
        f32x4 acc2[4];
        #pragma unroll
        for (int mi = 0; mi < 4; mi++) acc2[mi] = zero;
        #pragma unroll
        for (int ds = 0; ds < 4; ds++) {
            bf16x8 bk = *(const bf16x8*)&k_lds[kvr * 128 + (((ds * 4 + quad) ^ (kvr & 7)) * 8)];
            #pragma unroll
            for (int mi = 0; mi < 4; mi++) {
                bf16x8 aq = *(const bf16x8*)&q_lds[ds * 4096 + (wm + mi * 16 + cl) * 32 + quad * 8];
                acc2[mi] = __builtin_amdgcn_mfma_f32_16x16x32_bf16(aq, bk, acc2[mi], 0, 0, 0);
            }
        }
        // mask + decay + bf16 -> P_lds[128][32]
        #pragma unroll
        for (int mi = 0; mi < 4; mi++)
            #pragma unroll
            for (int r = 0; r < 4; r++) {
                const int row = wm + mi * 16 + quad * 4 + r;
                const int mb  = tm * 128 + row;
                const int kv  = kv0 + pcb + cl;
                const int d   = mb - kv;
                const float x = acc2[mi][r];
                P_lds[row * 32 + pcb + cl] = f2bf(d >= 0 ? x * __expf(-s_ * (float)d) : 0.f);
            }
        __syncthreads();
        // PV: acc += P @ vT^T
        bf16x8 afp[4], bfv[4];
        #pragma unroll
        for (int mi = 0; mi < 4; mi++)
            afp[mi] = *(const bf16x8*)&P_lds[(wm + mi * 16 + cl) * 32 + quad * 8];
        #pragma unroll
        for (int ni = 0; ni < 4; ni++)
            bfv[ni] = *(const bf16x8*)&Bs[(wn + ni * 16 + cl) * 32 + quad * 8];
        #pragma unroll
        for (int mi = 0; mi < 4; mi++)
            #pragma unroll
            for (int ni = 0; ni < 4; ni++)
                acc[mi][ni] = __builtin_amdgcn_mfma_f32_16x16x32_bf16(afp[mi], bfv[ni], acc[mi][ni], 0, 0, 0);
    }

    // ---- epilogue: attn write (verbatim M_INTRA) ----
    #pragma unroll
    for (int mi = 0; mi < 4; mi++)
        #pragma unroll
        for (int ni = 0; ni < 4; ni++)
            #pragma unroll
            for (int r = 0; r < 4; r++) {
                const int m = tm * 128 + wm + mi * 16 + quad * 4 + r;
                const int n = wn + ni * 16 + cl;
                attn[(rowbase + m) * HID + hh * 128 + n] = f2bf(acc[mi][ni][r]);
            }
}

// ---------------------------------------------------------------------------
// S_0 = 0; write S_j^T (bf16); S_{j+1} = e^{-256 s} S_j + KV_j
// ---------------------------------------------------------------------------
__global__ __launch_bounds__(256) void scan_kv(const float* __restrict__ KVT,
                                               u16* __restrict__ ST,
                                               const float* __restrict__ slope) {
    const int bh = blockIdx.x >> 4, ch = blockIdx.x & 15;
    const int off = ch * 1024 + threadIdx.x * 4;
    const float bd = __expf(-256.f * slope[bh & 15]);
    float4 st = {0.f, 0.f, 0.f, 0.f};
    for (int j = 0; j < 16; j++) {
        const size_t base = ((size_t)(bh * 16 + j)) * 16384 + off;
        uint2 o;
        o.x = (unsigned)f2bf(st.x) | ((unsigned)f2bf(st.y) << 16);
        o.y = (unsigned)f2bf(st.z) | ((unsigned)f2bf(st.w) << 16);
        *(uint2*)&ST[base] = o;
        const float4 kv = *(const float4*)&KVT[base];
        st.x = bd * st.x + kv.x;
        st.y = bd * st.y + kv.y;
        st.z = bd * st.z + kv.z;
        st.w = bd * st.w + kv.w;
    }
}

// ---------------------------------------------------------------------------
// y = gate * (attn * rsqrt(mean(attn^2)+eps)) * norm_w   (one WG per row)
// ---------------------------------------------------------------------------
__global__ __launch_bounds__(256) void rmsnorm_gate(const u16* __restrict__ attn,
                                                    const u16* __restrict__ gate,
                                                    const float* __restrict__ nw,
                                                    u16* __restrict__ y) {
    const int r = blockIdx.x, tid = threadIdx.x;
    const size_t base = (size_t)r * HID + tid * 8;
    const uint4 a = *(const uint4*)&attn[base];
    float x[8];
    x[0] = bf2f(a.x & 0xffff); x[1] = bf2f(a.x >> 16);
    x[2] = bf2f(a.y & 0xffff); x[3] = bf2f(a.y >> 16);
    x[4] = bf2f(a.z & 0xffff); x[5] = bf2f(a.z >> 16);
    x[6] = bf2f(a.w & 0xffff); x[7] = bf2f(a.w >> 16);
    float s = 0.f;
    #pragma unroll
    for (int i = 0; i < 8; i++) s += x[i] * x[i];
    #pragma unroll
    for (int off = 32; off > 0; off >>= 1) s += __shfl_down(s, off);
    __shared__ float red[4];
    if ((tid & 63) == 0) red[tid >> 6] = s;
    __syncthreads();
    const float tot = red[0] + red[1] + red[2] + red[3];
    const float sc = rsqrtf(tot * (1.f / 2048.f) + 1e-6f);
    const uint4 g = *(const uint4*)&gate[base];
    float gv[8];
    gv[0] = bf2f(g.x & 0xffff); gv[1] = bf2f(g.x >> 16);
    gv[2] = bf2f(g.y & 0xffff); gv[3] = bf2f(g.y >> 16);
    gv[4] = bf2f(g.z & 0xffff); gv[5] = bf2f(g.z >> 16);
    gv[6] = bf2f(g.w & 0xffff); gv[7] = bf2f(g.w >> 16);
    const float4 w0 = *(const float4*)&nw[tid * 8];
    const float4 w1 = *(const float4*)&nw[tid * 8 + 4];
    const float wv[8] = {w0.x, w0.y, w0.z, w0.w, w1.x, w1.y, w1.z, w1.w};
    u16 o[8];
    #pragma unroll
    for (int i = 0; i < 8; i++) o[i] = f2bf(gv[i] * x[i] * sc * wv[i]);
    uint4 ov;
    ov.x = (unsigned)o[0] | ((unsigned)o[1] << 16);
    ov.y = (unsigned)o[2] | ((unsigned)o[3] << 16);
    ov.z = (unsigned)o[4] | ((unsigned)o[5] << 16);
    ov.w = (unsigned)o[6] | ((unsigned)o[7] << 16);
    *(uint4*)&y[base] = ov;
}

// ---------------------------------------------------------------------------
extern "C" void kernel_launch(void* const* d_in, const int* in_sizes, int n_in,
                              void* d_out, int out_size, void* d_ws, size_t ws_size,
                              hipStream_t stream) {
    const float* hidden = (const float*)d_in[0];
    const float* slope  = (const float*)d_in[1];
    const float* w_qkv  = (const float*)d_in[2];
    const float* w_gate = (const float*)d_in[3];
    const float* w_out  = (const float*)d_in[4];
    const float* norm_w = (const float*)d_in[5];
    float* out = (float*)d_out;

    // 7 slots x 33,554,432 B = 234,881,024 B total
    char* w = (char*)d_ws;
    u16* qb   = (u16*)(w);                 // S0: q                 [QKV .. fused_pv]
    u16* kb   = (u16*)(w +  33554432);     // S1: k                 [QKV .. fused_pv]
    u16* kTs  = (u16*)(w +  67108864);     // S2: kTs (via QKV)     [QKV .. KVT]
    u16* hid_bf = (u16*)(w + 100663296);   // S3: hidden bf16       [cast .. QKV]
    u16* vT   = (u16*)(w + 134217728);     // S4: vT (via QKV)      [QKV .. fused_pv]
    u16* gate = (u16*)(w + 167772160);     // S5: gate (via QKV)    [QKV .. rms]
    u16* wqkv_bf  = (u16*)(w + 201326592); // S6: w_qkv bf16 25.17M [cast .. QKV]
    u16* wgate_bf = (u16*)(w + 201326592 + 25165824); // S6 tail 8.39M, contiguous
    // aliases (disjoint lifetimes):
    float* KVT  = (float*)hid_bf;          // S3: KV^T fp32         [KVT .. scan]
    u16*   ST   = kTs;                     // S2: S^T bf16 16.8M    [scan .. fused_pv]
    u16*   wout_bf = kb;                   // S1: w_out bf16        [cast .. OUT]
    u16*   attn = wqkv_bf;                 // S6: attn              [fused_pv .. rms]
    u16*   y    = kTs;                     // S2: y                 [rms .. OUT]

    static bool s_attr = false;
    if (!s_attr) {
        (void)hipFuncSetAttribute((const void*)gemm256<0>,
                                  hipFuncAttributeMaxDynamicSharedMemorySize, 131072);
        (void)hipFuncSetAttribute((const void*)gemm256<1>,
                                  hipFuncAttributeMaxDynamicSharedMemorySize, 131072);
        s_attr = true;
    }

    // fused casts: hidden | w_qkv | w_gate in one launch
    castk3<<<32768, 256, 0, stream>>>(hidden, hid_bf, w_qkv, wqkv_bf, w_gate, wgate_bf);

    // fused qkv+gate: B = [w_qkv ; w_gate]; epilogue also emits vT and kTs
    gemm256<0><<<dim3(1024), dim3(512), 131072, stream>>>(hid_bf, wqkv_bf, qb, vT, gate, kTs, slope);
    gemm_nt<M_KVT ><<<dim3(1, 1, 512),  256, 0, stream>>>(vT, kTs, KVT, slope, 0, nullptr, nullptr);
    scan_kv         <<<512,             256, 0, stream>>>(KVT, ST, slope);
    fused_pv        <<<dim3(2, 1, 512), 256, 0, stream>>>(qb, kb, ST, vT, attn, slope);
    castk<<< 4096, 256, 0, stream>>>(w_out, wout_bf);
    rmsnorm_gate    <<<8192,            256, 0, stream>>>(attn, gate, norm_w, y);
    gemm256<1><<<dim3(256), dim3(512), 131072, stream>>>(y, wout_bf, (void*)out, nullptr, nullptr, nullptr, nullptr);
}

// Round 14
// 443.384 us; speedup vs baseline: 1.0119x; 1.0119x over previous
//
#include <hip/hip_runtime.h>

// ---------------------------------------------------------------------------
// MiniMax-M1 Lightning Attention forward, MI355X / gfx950.
//   0. castk3: fp32->bf16 for hidden + w_qkv + w_gate in ONE launch
//   1. fused qkv+gate via 256x256 lockstep GEMM (R11 rotated-read schedule)
//      epilogue: q,k,gate row-major; v stored DIRECTLY transposed (vT)
//   2. transpose_k: kTs[d][m] = silu_k[m][d] * exp(-s*(255-m))
//   3. KVT_j = vT @ kTs^T  (= KV_j^T, fp32)
//   4. scan: S_{j+1} = e^{-256 s} S_j + KV_j ; store S_j^T bf16  [512 WGs]
//   5+6 FUSED (fused_pv): inter (q@S^T, q_decay) + per-32-kv-chunk P in-reg
//      -> LDS round-trip -> acc += P@v.  Intra loop DOUBLE-BUFFERED with
//      counted vmcnt(4) (chunk c+1 loads stay in flight under c's MFMA).
//   7. y = gate * rmsnorm(attn) * norm_w
//   8. out = y @ w_out^T via same 256 GEMM [fp32 -> d_out]
// Workspace: 7 slots x 33,554,432 B = 234,881,024 B peak.
// ---------------------------------------------------------------------------

typedef unsigned short u16;
typedef __bf16 bf16x8 __attribute__((ext_vector_type(8)));
typedef float f32x4 __attribute__((ext_vector_type(4)));

#define SEQ 4096
#define HID 2048

__device__ __forceinline__ u16 f2bf(float f) {
    union { float f; unsigned u; } v; v.f = f;
    unsigned r = v.u + 0x7fffu + ((v.u >> 16) & 1u);   // round-to-nearest-even
    return (u16)(r >> 16);
}
__device__ __forceinline__ float bf2f(u16 u) {
    union { unsigned u; float f; } v; v.u = ((unsigned)u) << 16; return v.f;
}

// async global->LDS, 16B per lane; lds dest must be wave-uniform base (+lane*16)
typedef __attribute__((address_space(1))) unsigned char gas_u8;
typedef __attribute__((address_space(3))) unsigned char las_u8;
__device__ __forceinline__ void gld16(const void* g, void* l) {
    __builtin_amdgcn_global_load_lds((gas_u8*)g, (las_u8*)l, 16, 0, 0);
}

// ---------------------------------------------------------------------------
// fp32 -> bf16 casts.  castk: single region.  castk3: hidden|w_qkv|w_gate.
// ---------------------------------------------------------------------------
__global__ __launch_bounds__(256) void castk(const float* __restrict__ in,
                                             u16* __restrict__ out) {
    const size_t i = (size_t)blockIdx.x * 256 + threadIdx.x;
    const float4 f = *(const float4*)&in[i * 4];
    uint2 o;
    o.x = (unsigned)f2bf(f.x) | ((unsigned)f2bf(f.y) << 16);
    o.y = (unsigned)f2bf(f.z) | ((unsigned)f2bf(f.w) << 16);
    *(uint2*)&out[i * 4] = o;
}

__global__ __launch_bounds__(256) void castk3(const float* __restrict__ a, u16* __restrict__ ao,
                                              const float* __restrict__ b, u16* __restrict__ bo,
                                              const float* __restrict__ c, u16* __restrict__ co) {
    const int bid = blockIdx.x;
    const float* src; u16* dst; size_t i;
    if (bid < 16384)      { src = a; dst = ao; i = (size_t)bid * 256 + threadIdx.x; }
    else if (bid < 28672) { src = b; dst = bo; i = (size_t)(bid - 16384) * 256 + threadIdx.x; }
    else                  { src = c; dst = co; i = (size_t)(bid - 28672) * 256 + threadIdx.x; }
    const float4 f = *(const float4*)&src[i * 4];
    uint2 o;
    o.x = (unsigned)f2bf(f.x) | ((unsigned)f2bf(f.y) << 16);
    o.y = (unsigned)f2bf(f.z) | ((unsigned)f2bf(f.w) << 16);
    *(uint2*)&dst[i * 4] = o;
}

// ---------------------------------------------------------------------------
// 256x256-tile lockstep pipelined NT GEMM (R11 rotated-read schedule).
// MODE 0: fused QKV+gate epilogue; MODE 1: f32 out.
// ---------------------------------------------------------------------------
template <int MODE>
__global__ __launch_bounds__(512, 2) void gemm256(const u16* __restrict__ A,
                                                  const u16* __restrict__ Bm,
                                                  void* __restrict__ Cv,
                                                  void* __restrict__ aux,
                                                  void* __restrict__ aux2) {
    constexpr int NTN = (MODE == 0) ? 32 : 8;     // tiles along N
    constexpr int NT  = 32;                       // K tiles (2048 / 64)
    extern __shared__ u16 smem[];                 // [2][A 16384 | B 16384]

    // XCD swizzle: 8 XCDs; per-XCD 4-row x 8-col rectangular supertiles
    const int bid = blockIdx.x;
    const int xcd = bid & 7, l = bid >> 3;
    int tm, tn;
    if constexpr (MODE == 0) {       // 32x32 tile grid, 128 WGs per XCD
        tm = xcd * 4 + (l & 3);
        tn = ((l >> 2) & 7) | ((l >> 5) << 3);
    } else {                         // 32x8 grid, 32 WGs per XCD (4x8 rect)
        const int wgid = xcd * 32 + l;
        tm = wgid / NTN; tn = wgid % NTN;
    }

    const int tid  = threadIdx.x;
    const int lane = tid & 63, wv = tid >> 6;
    const int quad = lane >> 4, cl = lane & 15;
    const int wm = (wv & 1) * 128, wn = (wv >> 1) * 64;

    const int srw  = tid >> 3;
    const int colo = ((tid & 7) ^ (srw & 7)) * 8;
    const u16* gA0 = A  + (size_t)(tm * 256 + srw) * HID + colo;
    const u16* gB0 = Bm + (size_t)(tn * 256 + srw) * HID + colo;

    const int x0 = ((quad       ^ (cl & 7)) * 8);
    const int x1 = (((4 + quad) ^ (cl & 7)) * 8);

    f32x4 acc[8][4];
    const f32x4 zero = {0.f, 0.f, 0.f, 0.f};
    #pragma unroll
    for (int a = 0; a < 8; a++)
        #pragma unroll
        for (int b = 0; b < 4; b++) acc[a][b] = zero;

    bf16x8 af[8], b0[4], b1[4];

    auto STG = [&](int kt, int mat, int hh) {   // stage one 128x64 half-tile
        const u16* g = (mat ? gB0 : gA0) + (size_t)(hh * 128) * HID + kt * 64;
        u16* lp = smem + (kt & 1) * 32768 + mat * 16384 + hh * 8192 + wv * 512;
        gld16(g, lp);
        gld16(g + (size_t)64 * HID, lp + 4096);
    };
    auto LDA = [&](int qm, int ab) {
        #pragma unroll
        for (int mi = 0; mi < 4; mi++) {
            const int rr = (wm + qm * 64 + mi * 16 + cl) * 64 + ab;
            af[mi * 2 + 0] = *(const bf16x8*)&smem[rr + x0];
            af[mi * 2 + 1] = *(const bf16x8*)&smem[rr + x1];
        }
    };
    auto LDB = [&](bf16x8* d, int qn, int bb2) {
        #pragma unroll
        for (int ni = 0; ni < 2; ni++) {
            const int rr = (wn + qn * 32 + ni * 16 + cl) * 64 + bb2;
            d[ni * 2 + 0] = *(const bf16x8*)&smem[rr + x0];
            d[ni * 2 + 1] = *(const bf16x8*)&smem[rr + x1];
        }
    };
    auto MM = [&](int qm, int qn, const bf16x8* bv) {
        #pragma unroll
        for (int mi = 0; mi < 4; mi++)
            #pragma unroll
            for (int ni = 0; ni < 2; ni++) {
                f32x4 c = acc[qm * 4 + mi][qn * 2 + ni];
                c = __builtin_amdgcn_mfma_f32_16x16x32_bf16(af[mi * 2 + 0], bv[ni * 2 + 0], c, 0, 0, 0);
                c = __builtin_amdgcn_mfma_f32_16x16x32_bf16(af[mi * 2 + 1], bv[ni * 2 + 1], c, 0, 0, 0);
                acc[qm * 4 + mi][qn * 2 + ni] = c;
            }
    };

    // prologue: issue stream per tile = B.lo, B.hi, A.lo, A.hi
    STG(0, 1, 0); STG(0, 1, 1); STG(0, 0, 0); STG(0, 0, 1);
    STG(1, 1, 0); STG(1, 1, 1); STG(1, 0, 0);
    asm volatile("s_waitcnt vmcnt(6)" ::: "memory");   // tile 0 resident
    __builtin_amdgcn_s_barrier();
    LDA(0, 0); LDB(b0, 0, 16384);      // ph0 operands (drain at ph0 lgkm(0))

    #pragma unroll 2
    for (int t = 0; t < NT; ++t) {
        const int ab  = (t & 1) * 32768;
        const int bb2 = ab + 16384;
        const int nab = ((t + 1) & 1) * 32768;
        // phase 0: MM(0,0)=A0*b0 (reads from prev ph3/prologue); read b1
        if (t + 1 < NT) STG(t + 1, 0, 1);
        __builtin_amdgcn_s_barrier();
        asm volatile("s_waitcnt lgkmcnt(0)" ::: "memory");
        __builtin_amdgcn_s_setprio(1); MM(0, 0, b0); __builtin_amdgcn_s_setprio(0);
        LDB(b1, 1, bb2);
        __builtin_amdgcn_s_barrier();
        // phase 1: MM(0,1)=A0*b1; read A1
        if (t + 2 < NT) STG(t + 2, 1, 0);
        __builtin_amdgcn_s_barrier();
        asm volatile("s_waitcnt lgkmcnt(0)" ::: "memory");
        __builtin_amdgcn_s_setprio(1); MM(0, 1, b1); __builtin_amdgcn_s_setprio(0);
        LDA(1, ab);
        __builtin_amdgcn_s_barrier();
        // phase 2: MM(1,1)=A1*b1
        if (t + 2 < NT) STG(t + 2, 1, 1);
        __builtin_amdgcn_s_barrier();
        asm volatile("s_waitcnt lgkmcnt(0)" ::: "memory");
        __builtin_amdgcn_s_setprio(1); MM(1, 1, b1); __builtin_amdgcn_s_setprio(0);
        __builtin_amdgcn_s_barrier();
        // phase 3: MM(1,0)=A1*b0; boundary vmcnt(6); post-MFMA next A0,b0
        if (t + 2 < NT) {
            STG(t + 2, 0, 0);
            asm volatile("s_waitcnt vmcnt(6)" ::: "memory");
        } else {
            asm volatile("s_waitcnt vmcnt(0)" ::: "memory");
        }
        __builtin_amdgcn_s_barrier();
        __builtin_amdgcn_s_setprio(1); MM(1, 0, b0); __builtin_amdgcn_s_setprio(0);
        if (t + 1 < NT) { LDA(0, nab); LDB(b0, 0, nab + 16384); }
        __builtin_amdgcn_s_barrier();
    }

    // epilogue
    if constexpr (MODE == 0) {
        const int grp = tn * 2 + (wn >> 7);
        const int which = grp >> 4, hd = grp & 15;
        const int n64 = wn & 64;
        if (which == 2) {
            const size_t bz = (size_t)((tm >> 4) * 256 + hd * 16 + (tm & 15));
            u16* tdst = (u16*)aux + bz * 32768;
            #pragma unroll
            for (int a = 0; a < 8; a++) {
                const int mm = wm + (a >> 2) * 64 + (a & 3) * 16 + quad * 4;
                #pragma unroll
                for (int b = 0; b < 4; b++) {
                    const int d = n64 + (b >> 1) * 32 + (b & 1) * 16 + cl;
                    u16 p[4];
                    #pragma unroll
                    for (int r = 0; r < 4; r++) {
                        const float x = acc[a][b][r];
                        p[r] = f2bf(x / (1.f + __expf(-x)));
                    }
                    uint2 pk;
                    pk.x = (unsigned)p[0] | ((unsigned)p[1] << 16);
                    pk.y = (unsigned)p[2] | ((unsigned)p[3] << 16);
                    *(uint2*)&tdst[(size_t)d * 256 + mm] = pk;
                }
            }
            return;
        }
        u16* dst = (which == 0) ? (u16*)Cv
                 : (which == 1) ? (u16*)Cv + (size_t)16777216   // k slot (S1)
                                : (u16*)aux2;                   // gate slot
        #pragma unroll
        for (int a = 0; a < 8; a++)
            #pragma unroll
            for (int b = 0; b < 4; b++)
                #pragma unroll
                for (int r = 0; r < 4; r++) {
                    const int m = tm * 256 + wm + (a >> 2) * 64 + (a & 3) * 16 + quad * 4 + r;
                    const int col = hd * 128 + n64 + (b >> 1) * 32 + (b & 1) * 16 + cl;
                    const float x = acc[a][b][r];
                    const float v = (which == 3) ? 1.f / (1.f + __expf(-x))
                                                 : x / (1.f + __expf(-x));
                    dst[(size_t)m * HID + col] = f2bf(v);
                }
        return;
    } else {
        float* C = (float*)Cv;
        #pragma unroll
        for (int a = 0; a < 8; a++)
            #pragma unroll
            for (int b = 0; b < 4; b++)
                #pragma unroll
                for (int r = 0; r < 4; r++) {
                    const int m = tm * 256 + wm + (a >> 2) * 64 + (a & 3) * 16 + quad * 4 + r;
                    const int n = tn * 256 + wn + (b >> 1) * 32 + (b & 1) * 16 + cl;
                    C[(size_t)m * HID + n] = acc[a][b][r];
                }
    }
}

// ---------------------------------------------------------------------------
// Generic 128x128-tile NT GEMM (kept for M_KVT).
// ---------------------------------------------------------------------------
#define M_KVT   4

template <int MODE>
__global__ __launch_bounds__(256) void gemm_nt(const u16* __restrict__ A,
                                               const u16* __restrict__ Bm,
                                               void* __restrict__ Cv,
                                               const float* __restrict__ slope,
                                               int bz0,
                                               void* __restrict__ aux,
                                               void* __restrict__ aux2) {
    const int tid = threadIdx.x;
    const int bz  = blockIdx.z + bz0;

    __shared__ u16 smem[8192];            // As/Bs staging, 16,384 B
    u16 (*As)[32] = (u16(*)[32])smem;
    u16 (*Bs)[32] = (u16(*)[32])(smem + 4096);

    const int lane = tid & 63, wv = tid >> 6;
    const int wm = (wv & 1) * 64, wn = (wv >> 1) * 64;
    const int quad = lane >> 4, cl = lane & 15;
    const int lr = lane >> 2;
    const int lc = (lane & 3) * 8;
    u16* lA = &As[wv * 32][0];
    u16* lB = &Bs[wv * 32][0];

    f32x4 acc[4][4];
    const f32x4 zero = {0.f, 0.f, 0.f, 0.f};
    #pragma unroll
    for (int mi = 0; mi < 4; mi++)
        #pragma unroll
        for (int ni = 0; ni < 4; ni++) acc[mi][ni] = zero;

    // M_KVT: A = vT[bz], B = kTs[bz], both ld 256, kmax 256
    const u16* Ab = A + (size_t)bz * 32768;
    const u16* Bb = Bm + (size_t)bz * 32768;
    const u16* gA = Ab + (size_t)(wv * 32 + lr) * 256 + lc;
    const u16* gB = Bb + (size_t)(wv * 32 + lr) * 256 + lc;

    for (int k0 = 0; k0 < 256; k0 += 32) {
        __syncthreads();
        gld16(gA + k0,                  lA);
        gld16(gA + k0 + (size_t)16 * 256, lA + 16 * 32);
        gld16(gB + k0,                  lB);
        gld16(gB + k0 + (size_t)16 * 256, lB + 16 * 32);
        __syncthreads();
        const int ko = quad * 8;
        bf16x8 af[4], bfv[4];
        #pragma unroll
        for (int mi = 0; mi < 4; mi++) af[mi] = *(const bf16x8*)&As[wm + mi * 16 + cl][ko];
        #pragma unroll
        for (int ni = 0; ni < 4; ni++) bfv[ni] = *(const bf16x8*)&Bs[wn + ni * 16 + cl][ko];
        #pragma unroll
        for (int mi = 0; mi < 4; mi++)
            #pragma unroll
            for (int ni = 0; ni < 4; ni++)
                acc[mi][ni] = __builtin_amdgcn_mfma_f32_16x16x32_bf16(af[mi], bfv[ni], acc[mi][ni], 0, 0, 0);
    }

    #pragma unroll
    for (int mi = 0; mi < 4; mi++)
        #pragma unroll
        for (int ni = 0; ni < 4; ni++)
            #pragma unroll
            for (int r = 0; r < 4; r++) {
                const int m = wm + mi * 16 + quad * 4 + r;
                const int n = wn + ni * 16 + cl;
                ((float*)Cv)[(size_t)bz * 16384 + m * 128 + n] = acc[mi][ni][r];
            }
}

// ---------------------------------------------------------------------------
// FUSED P+INTRA: grid (2,1,512) = (row-half tm, -, bz); 256 thr = 4 waves 2x2.
// Intra loop DOUBLE-BUFFERED: stage chunk c+1 first, counted vmcnt(4) keeps
// it in flight while chunk c's P-GEMM + PV run; loop-end barrier gives WAR.
// ---------------------------------------------------------------------------
__global__ __launch_bounds__(256) void fused_pv(const u16* __restrict__ qb,
                                                const u16* __restrict__ kb,
                                                const u16* __restrict__ ST,
                                                const u16* __restrict__ vT,
                                                u16* __restrict__ attn,
                                                const float* __restrict__ slope) {
    __shared__ u16 smem[36864];   // q 16384 | k 2x4096 | P 4096 | Bs 2x4096
    u16* q_lds = smem;            // [4][128][32]
    u16* k_lds = smem + 16384;    // [2][32][128] row-XOR swizzled
    u16* P_lds = smem + 24576;    // [128][32]
    u16* Bs    = smem + 28672;    // [2][128][32]  (v chunks; also inter ST)

    const int tm = blockIdx.x;           // row half within the 256-block
    const int bz = blockIdx.z;
    const int bb = bz >> 8, hh = (bz >> 4) & 15, jb = bz & 15;
    const float s_ = slope[hh];

    const int tid  = threadIdx.x;
    const int lane = tid & 63, wv = tid >> 6;
    const int quad = lane >> 4, cl = lane & 15;
    const int wm = (wv & 1) * 64, wn = (wv >> 1) * 64;
    const int lr = lane >> 2, lc = (lane & 3) * 8;
    const int pcb = (wv >> 1) * 16;      // P kv-col base for this wave

    const size_t rowbase = (size_t)(bb * SEQ + jb * 256);

    // ---- stage q: 4 ks x 2 gld16 (gemm_nt A-tile pattern, linear) ----
    const u16* gq = qb + (rowbase + tm * 128 + wv * 32 + lr) * HID + hh * 128 + lc;
    u16* lq = q_lds + wv * 1024 + lr * 32 + lc;
    #pragma unroll
    for (int ks = 0; ks < 4; ks++) {
        gld16(gq + ks * 32,                 lq + ks * 4096);
        gld16(gq + ks * 32 + 16 * HID,      lq + ks * 4096 + 512);
    }

    f32x4 acc[4][4];
    const f32x4 zero = {0.f, 0.f, 0.f, 0.f};
    #pragma unroll
    for (int mi = 0; mi < 4; mi++)
        #pragma unroll
        for (int ni = 0; ni < 4; ni++) acc[mi][ni] = zero;

    // ---- inter: acc = q @ S^T  (Bs buf 0 only; lockstep) ----
    const u16* gS = ST + (size_t)bz * 16384 + (size_t)(wv * 32 + lr) * 128 + lc;
    u16* lB = Bs + wv * 1024 + lr * 32 + lc;
    #pragma unroll
    for (int ks = 0; ks < 4; ks++) {
        __syncthreads();
        gld16(gS + ks * 32,            lB);
        gld16(gS + ks * 32 + 16 * 128, lB + 512);
        __syncthreads();
        bf16x8 af[4], bfv[4];
        #pragma unroll
        for (int mi = 0; mi < 4; mi++)
            af[mi] = *(const bf16x8*)&q_lds[ks * 4096 + (wm + mi * 16 + cl) * 32 + quad * 8];
        #pragma unroll
        for (int ni = 0; ni < 4; ni++)
            bfv[ni] = *(const bf16x8*)&Bs[(wn + ni * 16 + cl) * 32 + quad * 8];
        #pragma unroll
        for (int mi = 0; mi < 4; mi++)
            #pragma unroll
            for (int ni = 0; ni < 4; ni++)
                acc[mi][ni] = __builtin_amdgcn_mfma_f32_16x16x32_bf16(af[mi], bfv[ni], acc[mi][ni], 0, 0, 0);
    }
    // q_decay scale
    #pragma unroll
    for (int mi = 0; mi < 4; mi++)
        #pragma unroll
        for (int r = 0; r < 4; r++) {
            const int m = tm * 128 + wm + mi * 16 + quad * 4 + r;
            const float qd = __expf(-s_ * (float)(m + 1));
            #pragma unroll
            for (int ni = 0; ni < 4; ni++) acc[mi][ni][r] *= qd;
        }
    __syncthreads();    // inter Bs reads done before intra overwrites Bs

    // ---- intra: double-buffered chunk pipeline ----
    const int kmax = (tm == 0) ? 128 : 256;
    const int nc   = kmax >> 5;
    const u16* gV = vT + (size_t)bz * 32768 + (size_t)(wv * 32 + lr) * 256 + lc;
    const int krow = tid >> 4;                       // 0..15 per issue
    const int kcol = (((tid & 15) ^ (krow & 7)) * 8);
    const int kvr = pcb + cl;                        // lane's P kv-row (B-frag)

    auto stage_chunk = [&](int c, int buf) {         // 4 gld16
        u16* lk = k_lds + buf * 4096 + wv * 512 + lane * 8;
        u16* lv = Bs + buf * 4096 + wv * 1024 + lr * 32 + lc;
        const int kv0 = c * 32;
        gld16(kb + (rowbase + kv0 +      krow) * HID + hh * 128 + kcol, lk);
        gld16(kb + (rowbase + kv0 + 16 + krow) * HID + hh * 128 + kcol, lk + 2048);
        gld16(gV + kv0,            lv);
        gld16(gV + kv0 + 16 * 256, lv + 512);
    };

    stage_chunk(0, 0);
    for (int c = 0; c < nc; ++c) {
        const int cb = c & 1;
        if (c + 1 < nc) {
            stage_chunk(c + 1, cb ^ 1);
            asm volatile("s_waitcnt vmcnt(4)" ::: "memory");   // chunk c landed
        } else {
            asm volatile("s_waitcnt vmcnt(0)" ::: "memory");
        }
        __builtin_amdgcn_s_barrier();
        // P-GEMM: C[m(64 rows @wm)][kv(16 cols @pcb)] over d=128
        f32x4 acc2[4];
        #pragma unroll
        for (int mi = 0; mi < 4; mi++) acc2[mi] = zero;
        #pragma unroll
        for (int ds = 0; ds < 4; ds++) {
            bf16x8 bk = *(const bf16x8*)&k_lds[cb * 4096 + kvr * 128 + (((ds * 4 + quad) ^ (kvr & 7)) * 8)];
            #pragma unroll
            for (int mi = 0; mi < 4; mi++) {
                bf16x8 aq = *(const bf16x8*)&q_lds[ds * 4096 + (wm + mi * 16 + cl) * 32 + quad * 8];
                acc2[mi] = __builtin_amdgcn_mfma_f32_16x16x32_bf16(aq, bk, acc2[mi], 0, 0, 0);
            }
        }
        // mask + decay + bf16 -> P_lds[128][32]
        const int kv0 = c * 32;
        #pragma unroll
        for (int mi = 0; mi < 4; mi++)
            #pragma unroll
            for (int r = 0; r < 4; r++) {
                const int row = wm + mi * 16 + quad * 4 + r;
                const int mb  = tm * 128 + row;
                const int kv  = kv0 + pcb + cl;
                const int d   = mb - kv;
                const float x = acc2[mi][r];
                P_lds[row * 32 + pcb + cl] = f2bf(d >= 0 ? x * __expf(-s_ * (float)d) : 0.f);
            }
        asm volatile("s_waitcnt lgkmcnt(0)" ::: "memory");
        __builtin_amdgcn_s_barrier();
        // PV: acc += P @ vT^T
        bf16x8 afp[4], bfv[4];
        #pragma unroll
        for (int mi = 0; mi < 4; mi++)
            afp[mi] = *(const bf16x8*)&P_lds[(wm + mi * 16 + cl) * 32 + quad * 8];
        #pragma unroll
        for (int ni = 0; ni < 4; ni++)
            bfv[ni] = *(const bf16x8*)&Bs[cb * 4096 + (wn + ni * 16 + cl) * 32 + quad * 8];
        #pragma unroll
        for (int mi = 0; mi < 4; mi++)
            #pragma unroll
            for (int ni = 0; ni < 4; ni++)
                acc[mi][ni] = __builtin_amdgcn_mfma_f32_16x16x32_bf16(afp[mi], bfv[ni], acc[mi][ni], 0, 0, 0);
        __builtin_amdgcn_s_barrier();   // WAR: all waves' buf/P reads done
    }

    // ---- epilogue: attn write (verbatim M_INTRA) ----
    #pragma unroll
    for (int mi = 0; mi < 4; mi++)
        #pragma unroll
        for (int ni = 0; ni < 4; ni++)
            #pragma unroll
            for (int r = 0; r < 4; r++) {
                const int m = tm * 128 + wm + mi * 16 + quad * 4 + r;
                const int n = wn + ni * 16 + cl;
                attn[(rowbase + m) * HID + hh * 128 + n] = f2bf(acc[mi][ni][r]);
            }
}

// ---------------------------------------------------------------------------
// Per (b,h,block): kTs[d][m] = k[m][d] * exp(-s*(255-m))  (vectorized stores)
// ---------------------------------------------------------------------------
__global__ __launch_bounds__(256) void transpose_k(const u16* __restrict__ kb,
                                                   u16* __restrict__ kTs,
                                                   const float* __restrict__ slope) {
    __shared__ u16 t[128][137];   // pad 137: transposed-read lanes land 2-way max
    const int bz = blockIdx.x;
    const int bb = bz >> 8, hh = (bz >> 4) & 15, jb = bz & 15;
    const int tid = threadIdx.x;
    const float s_ = slope[hh];
    const u16* src = kb + ((size_t)(bb * SEQ + jb * 256)) * HID + hh * 128;
    u16* dst = kTs + (size_t)bz * 32768;

    for (int half = 0; half < 2; half++) {
        #pragma unroll
        for (int i = 0; i < 8; i++) {
            const int flat = tid + 256 * i;
            const int row = flat >> 4, c8 = (flat & 15) * 8;
            *(uint4*)&t[row][c8] = *(const uint4*)&src[(size_t)(half * 128 + row) * HID + c8];
        }
        __syncthreads();
        #pragma unroll
        for (int i = 0; i < 8; i++) {
            const int flat = tid + 256 * i;
            const int d = flat >> 4, mc = (flat & 15) * 8;
            u16 p[8];
            #pragma unroll
            for (int j = 0; j < 8; j++) {
                const int m = half * 128 + mc + j;
                p[j] = f2bf(bf2f(t[mc + j][d]) * __expf(-s_ * (float)(255 - m)));
            }
            uint4 pk;
            pk.x = (unsigned)p[0] | ((unsigned)p[1] << 16);
            pk.y = (unsigned)p[2] | ((unsigned)p[3] << 16);
            pk.z = (unsigned)p[4] | ((unsigned)p[5] << 16);
            pk.w = (unsigned)p[6] | ((unsigned)p[7] << 16);
            *(uint4*)&dst[(size_t)d * 256 + half * 128 + mc] = pk;
        }
        __syncthreads();
    }
}

// ---------------------------------------------------------------------------
// S_0 = 0; write S_j^T (bf16); S_{j+1} = e^{-256 s} S_j + KV_j
// ---------------------------------------------------------------------------
__global__ __launch_bounds__(256) void scan_kv(const float* __restrict__ KVT,
                                               u16* __restrict__ ST,
                                               const float* __restrict__ slope) {
    const int bh = blockIdx.x >> 4, ch = blockIdx.x & 15;
    const int off = ch * 1024 + threadIdx.x * 4;
    const float bd = __expf(-256.f * slope[bh & 15]);
    float4 st = {0.f, 0.f, 0.f, 0.f};
    for (int j = 0; j < 16; j++) {
        const size_t base = ((size_t)(bh * 16 + j)) * 16384 + off;
        uint2 o;
        o.x = (unsigned)f2bf(st.x) | ((unsigned)f2bf(st.y) << 16);
        o.y = (unsigned)f2bf(st.z) | ((unsigned)f2bf(st.w) << 16);
        *(uint2*)&ST[base] = o;
        const float4 kv = *(const float4*)&KVT[base];
        st.x = bd * st.x + kv.x;
        st.y = bd * st.y + kv.y;
        st.z = bd * st.z + kv.z;
        st.w = bd * st.w + kv.w;
    }
}

// ---------------------------------------------------------------------------
// y = gate * (attn * rsqrt(mean(attn^2)+eps)) * norm_w   (one WG per row)
// ---------------------------------------------------------------------------
__global__ __launch_bounds__(256) void rmsnorm_gate(const u16* __restrict__ attn,
                                                    const u16* __restrict__ gate,
                                                    const float* __restrict__ nw,
                                                    u16* __restrict__ y) {
    const int r = blockIdx.x, tid = threadIdx.x;
    const size_t base = (size_t)r * HID + tid * 8;
    const uint4 a = *(const uint4*)&attn[base];
    float x[8];
    x[0] = bf2f(a.x & 0xffff); x[1] = bf2f(a.x >> 16);
    x[2] = bf2f(a.y & 0xffff); x[3] = bf2f(a.y >> 16);
    x[4] = bf2f(a.z & 0xffff); x[5] = bf2f(a.z >> 16);
    x[6] = bf2f(a.w & 0xffff); x[7] = bf2f(a.w >> 16);
    float s = 0.f;
    #pragma unroll
    for (int i = 0; i < 8; i++) s += x[i] * x[i];
    #pragma unroll
    for (int off = 32; off > 0; off >>= 1) s += __shfl_down(s, off);
    __shared__ float red[4];
    if ((tid & 63) == 0) red[tid >> 6] = s;
    __syncthreads();
    const float tot = red[0] + red[1] + red[2] + red[3];
    const float sc = rsqrtf(tot * (1.f / 2048.f) + 1e-6f);
    const uint4 g = *(const uint4*)&gate[base];
    float gv[8];
    gv[0] = bf2f(g.x & 0xffff); gv[1] = bf2f(g.x >> 16);
    gv[2] = bf2f(g.y & 0xffff); gv[3] = bf2f(g.y >> 16);
    gv[4] = bf2f(g.z & 0xffff); gv[5] = bf2f(g.z >> 16);
    gv[6] = bf2f(g.w & 0xffff); gv[7] = bf2f(g.w >> 16);
    const float4 w0 = *(const float4*)&nw[tid * 8];
    const float4 w1 = *(const float4*)&nw[tid * 8 + 4];
    const float wv[8] = {w0.x, w0.y, w0.z, w0.w, w1.x, w1.y, w1.z, w1.w};
    u16 o[8];
    #pragma unroll
    for (int i = 0; i < 8; i++) o[i] = f2bf(gv[i] * x[i] * sc * wv[i]);
    uint4 ov;
    ov.x = (unsigned)o[0] | ((unsigned)o[1] << 16);
    ov.y = (unsigned)o[2] | ((unsigned)o[3] << 16);
    ov.z = (unsigned)o[4] | ((unsigned)o[5] << 16);
    ov.w = (unsigned)o[6] | ((unsigned)o[7] << 16);
    *(uint4*)&y[base] = ov;
}

// ---------------------------------------------------------------------------
extern "C" void kernel_launch(void* const* d_in, const int* in_sizes, int n_in,
                              void* d_out, int out_size, void* d_ws, size_t ws_size,
                              hipStream_t stream) {
    const float* hidden = (const float*)d_in[0];
    const float* slope  = (const float*)d_in[1];
    const float* w_qkv  = (const float*)d_in[2];
    const float* w_gate = (const float*)d_in[3];
    const float* w_out  = (const float*)d_in[4];
    const float* norm_w = (const float*)d_in[5];
    float* out = (float*)d_out;

    // 7 slots x 33,554,432 B = 234,881,024 B total
    char* w = (char*)d_ws;
    u16* qb   = (u16*)(w);                 // S0: q                 [QKV .. fused_pv]
    u16* kb   = (u16*)(w +  33554432);     // S1: k                 [QKV .. fused_pv]
    u16* kTs  = (u16*)(w +  67108864);     // S2: kTs               [transpose .. KVT]
    u16* hid_bf = (u16*)(w + 100663296);   // S3: hidden bf16       [cast .. QKV]
    u16* vT   = (u16*)(w + 134217728);     // S4: vT (via QKV)      [QKV .. fused_pv]
    u16* gate = (u16*)(w + 167772160);     // S5: gate (via QKV)    [QKV .. rms]
    u16* wqkv_bf  = (u16*)(w + 201326592); // S6: w_qkv bf16 25.17M [cast .. QKV]
    u16* wgate_bf = (u16*)(w + 201326592 + 25165824); // S6 tail 8.39M, contiguous
    // aliases (disjoint lifetimes):
    float* KVT  = (float*)hid_bf;          // S3: KV^T fp32         [KVT .. scan]
    u16*   ST   = kTs;                     // S2: S^T bf16 16.8M    [scan .. fused_pv]
    u16*   wout_bf = kb;                   // S1: w_out bf16        [cast .. OUT]
    u16*   attn = wqkv_bf;                 // S6: attn              [fused_pv .. rms]
    u16*   y    = kTs;                     // S2: y                 [rms .. OUT]

    static bool s_attr = false;
    if (!s_attr) {
        (void)hipFuncSetAttribute((const void*)gemm256<0>,
                                  hipFuncAttributeMaxDynamicSharedMemorySize, 131072);
        (void)hipFuncSetAttribute((const void*)gemm256<1>,
                                  hipFuncAttributeMaxDynamicSharedMemorySize, 131072);
        s_attr = true;
    }

    // fused casts: hidden | w_qkv | w_gate in one launch
    castk3<<<32768, 256, 0, stream>>>(hidden, hid_bf, w_qkv, wqkv_bf, w_gate, wgate_bf);

    // fused qkv+gate: B = [w_qkv ; w_gate] (8192 x 2048 contiguous)
    gemm256<0><<<dim3(1024), dim3(512), 131072, stream>>>(hid_bf, wqkv_bf, qb, vT, gate);
    transpose_k     <<<512,             256, 0, stream>>>(kb, kTs, slope);
    gemm_nt<M_KVT ><<<dim3(1, 1, 512),  256, 0, stream>>>(vT, kTs, KVT, slope, 0, nullptr, nullptr);
    scan_kv         <<<512,             256, 0, stream>>>(KVT, ST, slope);
    fused_pv        <<<dim3(2, 1, 512), 256, 0, stream>>>(qb, kb, ST, vT, attn, slope);
    castk<<< 4096, 256, 0, stream>>>(w_out, wout_bf);
    rmsnorm_gate    <<<8192,            256, 0, stream>>>(attn, gate, norm_w, y);
    gemm256<1><<<dim3(256), dim3(512), 131072, stream>>>(y, wout_bf, (void*)out, nullptr, nullptr);
}

// Round 15
// 442.340 us; speedup vs baseline: 1.0143x; 1.0024x over previous
//
#include <hip/hip_runtime.h>

// ---------------------------------------------------------------------------
// MiniMax-M1 Lightning Attention forward, MI355X / gfx950.
//   0. castk3: fp32->bf16 for hidden + w_qkv + w_gate in ONE launch
//   1. fused qkv+gate via 256x256 lockstep GEMM (R11 rotated-read schedule)
//      epilogue: q,k,gate row-major; v stored DIRECTLY transposed (vT)
//   2. transpose_k: kTs[d][m] = silu_k[m][d] * exp(-s*(255-m))
//   3. KVT_j = vT @ kTs^T  (fp32), DOUBLE-BUFFERED staging (vmcnt(4)/chunk)
//   4. scan: S_{j+1} = e^{-256 s} S_j + KV_j ; store S_j^T bf16  [512 WGs]
//   5+6 FUSED (fused_pv): inter (q@S^T, q_decay) + per-32-kv-chunk P in-reg
//      -> LDS round-trip -> acc += P@v.  BOTH loops double-buffered with
//      counted vmcnt (chunk c+1 loads stay in flight under c's MFMA).
//   7. y = gate * rmsnorm(attn) * norm_w
//   8. out = y @ w_out^T via same 256 GEMM [fp32 -> d_out]
// Workspace: 7 slots x 33,554,432 B = 234,881,024 B peak.
// ---------------------------------------------------------------------------

typedef unsigned short u16;
typedef __bf16 bf16x8 __attribute__((ext_vector_type(8)));
typedef float f32x4 __attribute__((ext_vector_type(4)));

#define SEQ 4096
#define HID 2048

__device__ __forceinline__ u16 f2bf(float f) {
    union { float f; unsigned u; } v; v.f = f;
    unsigned r = v.u + 0x7fffu + ((v.u >> 16) & 1u);   // round-to-nearest-even
    return (u16)(r >> 16);
}
__device__ __forceinline__ float bf2f(u16 u) {
    union { unsigned u; float f; } v; v.u = ((unsigned)u) << 16; return v.f;
}

// async global->LDS, 16B per lane; lds dest must be wave-uniform base (+lane*16)
typedef __attribute__((address_space(1))) unsigned char gas_u8;
typedef __attribute__((address_space(3))) unsigned char las_u8;
__device__ __forceinline__ void gld16(const void* g, void* l) {
    __builtin_amdgcn_global_load_lds((gas_u8*)g, (las_u8*)l, 16, 0, 0);
}

// ---------------------------------------------------------------------------
// fp32 -> bf16 casts.  castk: single region.  castk3: hidden|w_qkv|w_gate.
// ---------------------------------------------------------------------------
__global__ __launch_bounds__(256) void castk(const float* __restrict__ in,
                                             u16* __restrict__ out) {
    const size_t i = (size_t)blockIdx.x * 256 + threadIdx.x;
    const float4 f = *(const float4*)&in[i * 4];
    uint2 o;
    o.x = (unsigned)f2bf(f.x) | ((unsigned)f2bf(f.y) << 16);
    o.y = (unsigned)f2bf(f.z) | ((unsigned)f2bf(f.w) << 16);
    *(uint2*)&out[i * 4] = o;
}

__global__ __launch_bounds__(256) void castk3(const float* __restrict__ a, u16* __restrict__ ao,
                                              const float* __restrict__ b, u16* __restrict__ bo,
                                              const float* __restrict__ c, u16* __restrict__ co) {
    const int bid = blockIdx.x;
    const float* src; u16* dst; size_t i;
    if (bid < 16384)      { src = a; dst = ao; i = (size_t)bid * 256 + threadIdx.x; }
    else if (bid < 28672) { src = b; dst = bo; i = (size_t)(bid - 16384) * 256 + threadIdx.x; }
    else                  { src = c; dst = co; i = (size_t)(bid - 28672) * 256 + threadIdx.x; }
    const float4 f = *(const float4*)&src[i * 4];
    uint2 o;
    o.x = (unsigned)f2bf(f.x) | ((unsigned)f2bf(f.y) << 16);
    o.y = (unsigned)f2bf(f.z) | ((unsigned)f2bf(f.w) << 16);
    *(uint2*)&dst[i * 4] = o;
}

// ---------------------------------------------------------------------------
// 256x256-tile lockstep pipelined NT GEMM (R11 rotated-read schedule).
// MODE 0: fused QKV+gate epilogue; MODE 1: f32 out.
// ---------------------------------------------------------------------------
template <int MODE>
__global__ __launch_bounds__(512, 2) void gemm256(const u16* __restrict__ A,
                                                  const u16* __restrict__ Bm,
                                                  void* __restrict__ Cv,
                                                  void* __restrict__ aux,
                                                  void* __restrict__ aux2) {
    constexpr int NTN = (MODE == 0) ? 32 : 8;     // tiles along N
    constexpr int NT  = 32;                       // K tiles (2048 / 64)
    extern __shared__ u16 smem[];                 // [2][A 16384 | B 16384]

    // XCD swizzle: 8 XCDs; per-XCD 4-row x 8-col rectangular supertiles
    const int bid = blockIdx.x;
    const int xcd = bid & 7, l = bid >> 3;
    int tm, tn;
    if constexpr (MODE == 0) {       // 32x32 tile grid, 128 WGs per XCD
        tm = xcd * 4 + (l & 3);
        tn = ((l >> 2) & 7) | ((l >> 5) << 3);
    } else {                         // 32x8 grid, 32 WGs per XCD (4x8 rect)
        const int wgid = xcd * 32 + l;
        tm = wgid / NTN; tn = wgid % NTN;
    }

    const int tid  = threadIdx.x;
    const int lane = tid & 63, wv = tid >> 6;
    const int quad = lane >> 4, cl = lane & 15;
    const int wm = (wv & 1) * 128, wn = (wv >> 1) * 64;

    const int srw  = tid >> 3;
    const int colo = ((tid & 7) ^ (srw & 7)) * 8;
    const u16* gA0 = A  + (size_t)(tm * 256 + srw) * HID + colo;
    const u16* gB0 = Bm + (size_t)(tn * 256 + srw) * HID + colo;

    const int x0 = ((quad       ^ (cl & 7)) * 8);
    const int x1 = (((4 + quad) ^ (cl & 7)) * 8);

    f32x4 acc[8][4];
    const f32x4 zero = {0.f, 0.f, 0.f, 0.f};
    #pragma unroll
    for (int a = 0; a < 8; a++)
        #pragma unroll
        for (int b = 0; b < 4; b++) acc[a][b] = zero;

    bf16x8 af[8], b0[4], b1[4];

    auto STG = [&](int kt, int mat, int hh) {   // stage one 128x64 half-tile
        const u16* g = (mat ? gB0 : gA0) + (size_t)(hh * 128) * HID + kt * 64;
        u16* lp = smem + (kt & 1) * 32768 + mat * 16384 + hh * 8192 + wv * 512;
        gld16(g, lp);
        gld16(g + (size_t)64 * HID, lp + 4096);
    };
    auto LDA = [&](int qm, int ab) {
        #pragma unroll
        for (int mi = 0; mi < 4; mi++) {
            const int rr = (wm + qm * 64 + mi * 16 + cl) * 64 + ab;
            af[mi * 2 + 0] = *(const bf16x8*)&smem[rr + x0];
            af[mi * 2 + 1] = *(const bf16x8*)&smem[rr + x1];
        }
    };
    auto LDB = [&](bf16x8* d, int qn, int bb2) {
        #pragma unroll
        for (int ni = 0; ni < 2; ni++) {
            const int rr = (wn + qn * 32 + ni * 16 + cl) * 64 + bb2;
            d[ni * 2 + 0] = *(const bf16x8*)&smem[rr + x0];
            d[ni * 2 + 1] = *(const bf16x8*)&smem[rr + x1];
        }
    };
    auto MM = [&](int qm, int qn, const bf16x8* bv) {
        #pragma unroll
        for (int mi = 0; mi < 4; mi++)
            #pragma unroll
            for (int ni = 0; ni < 2; ni++) {
                f32x4 c = acc[qm * 4 + mi][qn * 2 + ni];
                c = __builtin_amdgcn_mfma_f32_16x16x32_bf16(af[mi * 2 + 0], bv[ni * 2 + 0], c, 0, 0, 0);
                c = __builtin_amdgcn_mfma_f32_16x16x32_bf16(af[mi * 2 + 1], bv[ni * 2 + 1], c, 0, 0, 0);
                acc[qm * 4 + mi][qn * 2 + ni] = c;
            }
    };

    // prologue: issue stream per tile = B.lo, B.hi, A.lo, A.hi
    STG(0, 1, 0); STG(0, 1, 1); STG(0, 0, 0); STG(0, 0, 1);
    STG(1, 1, 0); STG(1, 1, 1); STG(1, 0, 0);
    asm volatile("s_waitcnt vmcnt(6)" ::: "memory");   // tile 0 resident
    __builtin_amdgcn_s_barrier();
    LDA(0, 0); LDB(b0, 0, 16384);      // ph0 operands (drain at ph0 lgkm(0))

    #pragma unroll 2
    for (int t = 0; t < NT; ++t) {
        const int ab  = (t & 1) * 32768;
        const int bb2 = ab + 16384;
        const int nab = ((t + 1) & 1) * 32768;
        // phase 0: MM(0,0)=A0*b0 (reads from prev ph3/prologue); read b1
        if (t + 1 < NT) STG(t + 1, 0, 1);
        __builtin_amdgcn_s_barrier();
        asm volatile("s_waitcnt lgkmcnt(0)" ::: "memory");
        __builtin_amdgcn_s_setprio(1); MM(0, 0, b0); __builtin_amdgcn_s_setprio(0);
        LDB(b1, 1, bb2);
        __builtin_amdgcn_s_barrier();
        // phase 1: MM(0,1)=A0*b1; read A1
        if (t + 2 < NT) STG(t + 2, 1, 0);
        __builtin_amdgcn_s_barrier();
        asm volatile("s_waitcnt lgkmcnt(0)" ::: "memory");
        __builtin_amdgcn_s_setprio(1); MM(0, 1, b1); __builtin_amdgcn_s_setprio(0);
        LDA(1, ab);
        __builtin_amdgcn_s_barrier();
        // phase 2: MM(1,1)=A1*b1
        if (t + 2 < NT) STG(t + 2, 1, 1);
        __builtin_amdgcn_s_barrier();
        asm volatile("s_waitcnt lgkmcnt(0)" ::: "memory");
        __builtin_amdgcn_s_setprio(1); MM(1, 1, b1); __builtin_amdgcn_s_setprio(0);
        __builtin_amdgcn_s_barrier();
        // phase 3: MM(1,0)=A1*b0; boundary vmcnt(6); post-MFMA next A0,b0
        if (t + 2 < NT) {
            STG(t + 2, 0, 0);
            asm volatile("s_waitcnt vmcnt(6)" ::: "memory");
        } else {
            asm volatile("s_waitcnt vmcnt(0)" ::: "memory");
        }
        __builtin_amdgcn_s_barrier();
        __builtin_amdgcn_s_setprio(1); MM(1, 0, b0); __builtin_amdgcn_s_setprio(0);
        if (t + 1 < NT) { LDA(0, nab); LDB(b0, 0, nab + 16384); }
        __builtin_amdgcn_s_barrier();
    }

    // epilogue
    if constexpr (MODE == 0) {
        const int grp = tn * 2 + (wn >> 7);
        const int which = grp >> 4, hd = grp & 15;
        const int n64 = wn & 64;
        if (which == 2) {
            const size_t bz = (size_t)((tm >> 4) * 256 + hd * 16 + (tm & 15));
            u16* tdst = (u16*)aux + bz * 32768;
            #pragma unroll
            for (int a = 0; a < 8; a++) {
                const int mm = wm + (a >> 2) * 64 + (a & 3) * 16 + quad * 4;
                #pragma unroll
                for (int b = 0; b < 4; b++) {
                    const int d = n64 + (b >> 1) * 32 + (b & 1) * 16 + cl;
                    u16 p[4];
                    #pragma unroll
                    for (int r = 0; r < 4; r++) {
                        const float x = acc[a][b][r];
                        p[r] = f2bf(x / (1.f + __expf(-x)));
                    }
                    uint2 pk;
                    pk.x = (unsigned)p[0] | ((unsigned)p[1] << 16);
                    pk.y = (unsigned)p[2] | ((unsigned)p[3] << 16);
                    *(uint2*)&tdst[(size_t)d * 256 + mm] = pk;
                }
            }
            return;
        }
        u16* dst = (which == 0) ? (u16*)Cv
                 : (which == 1) ? (u16*)Cv + (size_t)16777216   // k slot (S1)
                                : (u16*)aux2;                   // gate slot
        #pragma unroll
        for (int a = 0; a < 8; a++)
            #pragma unroll
            for (int b = 0; b < 4; b++)
                #pragma unroll
                for (int r = 0; r < 4; r++) {
                    const int m = tm * 256 + wm + (a >> 2) * 64 + (a & 3) * 16 + quad * 4 + r;
                    const int col = hd * 128 + n64 + (b >> 1) * 32 + (b & 1) * 16 + cl;
                    const float x = acc[a][b][r];
                    const float v = (which == 3) ? 1.f / (1.f + __expf(-x))
                                                 : x / (1.f + __expf(-x));
                    dst[(size_t)m * HID + col] = f2bf(v);
                }
        return;
    } else {
        float* C = (float*)Cv;
        #pragma unroll
        for (int a = 0; a < 8; a++)
            #pragma unroll
            for (int b = 0; b < 4; b++)
                #pragma unroll
                for (int r = 0; r < 4; r++) {
                    const int m = tm * 256 + wm + (a >> 2) * 64 + (a & 3) * 16 + quad * 4 + r;
                    const int n = tn * 256 + wn + (b >> 1) * 32 + (b & 1) * 16 + cl;
                    C[(size_t)m * HID + n] = acc[a][b][r];
                }
    }
}

// ---------------------------------------------------------------------------
// 128x128-tile NT GEMM for M_KVT, DOUBLE-BUFFERED (vmcnt(4) per chunk).
// ---------------------------------------------------------------------------
#define M_KVT   4

template <int MODE>
__global__ __launch_bounds__(256) void gemm_nt(const u16* __restrict__ A,
                                               const u16* __restrict__ Bm,
                                               void* __restrict__ Cv,
                                               const float* __restrict__ slope,
                                               int bz0,
                                               void* __restrict__ aux,
                                               void* __restrict__ aux2) {
    const int tid = threadIdx.x;
    const int bz  = blockIdx.z + bz0;

    __shared__ u16 smem[16384];           // 2 x (As 4096 + Bs 4096), 32 KB

    const int lane = tid & 63, wv = tid >> 6;
    const int wm = (wv & 1) * 64, wn = (wv >> 1) * 64;
    const int quad = lane >> 4, cl = lane & 15;
    const int lr = lane >> 2;
    const int lc = (lane & 3) * 8;

    f32x4 acc[4][4];
    const f32x4 zero = {0.f, 0.f, 0.f, 0.f};
    #pragma unroll
    for (int mi = 0; mi < 4; mi++)
        #pragma unroll
        for (int ni = 0; ni < 4; ni++) acc[mi][ni] = zero;

    // M_KVT: A = vT[bz], B = kTs[bz], both ld 256, kmax 256 (8 chunks)
    const u16* gA = A  + (size_t)bz * 32768 + (size_t)(wv * 32 + lr) * 256 + lc;
    const u16* gB = Bm + (size_t)bz * 32768 + (size_t)(wv * 32 + lr) * 256 + lc;

    auto stage = [&](int c, int buf) {    // 4 gld16
        u16* lA = smem + buf * 8192 + wv * 1024;
        u16* lB = lA + 4096;
        const int k0 = c * 32;
        gld16(gA + k0,                    lA);
        gld16(gA + k0 + (size_t)16 * 256, lA + 512);
        gld16(gB + k0,                    lB);
        gld16(gB + k0 + (size_t)16 * 256, lB + 512);
    };

    stage(0, 0);
    for (int c = 0; c < 8; ++c) {
        const int cb = c & 1;
        if (c + 1 < 8) {
            stage(c + 1, cb ^ 1);
            asm volatile("s_waitcnt vmcnt(4)" ::: "memory");   // chunk c landed
        } else {
            asm volatile("s_waitcnt vmcnt(0)" ::: "memory");
        }
        __builtin_amdgcn_s_barrier();
        const u16* As = smem + cb * 8192;
        const u16* Bs = As + 4096;
        const int ko = quad * 8;
        bf16x8 af[4], bfv[4];
        #pragma unroll
        for (int mi = 0; mi < 4; mi++) af[mi] = *(const bf16x8*)&As[(wm + mi * 16 + cl) * 32 + ko];
        #pragma unroll
        for (int ni = 0; ni < 4; ni++) bfv[ni] = *(const bf16x8*)&Bs[(wn + ni * 16 + cl) * 32 + ko];
        #pragma unroll
        for (int mi = 0; mi < 4; mi++)
            #pragma unroll
            for (int ni = 0; ni < 4; ni++)
                acc[mi][ni] = __builtin_amdgcn_mfma_f32_16x16x32_bf16(af[mi], bfv[ni], acc[mi][ni], 0, 0, 0);
        __builtin_amdgcn_s_barrier();   // WAR: all waves' reads of buf cb done
    }

    #pragma unroll
    for (int mi = 0; mi < 4; mi++)
        #pragma unroll
        for (int ni = 0; ni < 4; ni++)
            #pragma unroll
            for (int r = 0; r < 4; r++) {
                const int m = wm + mi * 16 + quad * 4 + r;
                const int n = wn + ni * 16 + cl;
                ((float*)Cv)[(size_t)bz * 16384 + m * 128 + n] = acc[mi][ni][r];
            }
}

// ---------------------------------------------------------------------------
// FUSED P+INTRA: grid (2,1,512) = (row-half tm, -, bz); 256 thr = 4 waves 2x2.
// BOTH loops double-buffered with counted vmcnt.
// ---------------------------------------------------------------------------
__global__ __launch_bounds__(256) void fused_pv(const u16* __restrict__ qb,
                                                const u16* __restrict__ kb,
                                                const u16* __restrict__ ST,
                                                const u16* __restrict__ vT,
                                                u16* __restrict__ attn,
                                                const float* __restrict__ slope) {
    __shared__ u16 smem[36864];   // q 16384 | k 2x4096 | P 4096 | Bs 2x4096
    u16* q_lds = smem;            // [4][128][32]
    u16* k_lds = smem + 16384;    // [2][32][128] row-XOR swizzled
    u16* P_lds = smem + 24576;    // [128][32]
    u16* Bs    = smem + 28672;    // [2][128][32]  (ST chunks / v chunks)

    const int tm = blockIdx.x;           // row half within the 256-block
    const int bz = blockIdx.z;
    const int bb = bz >> 8, hh = (bz >> 4) & 15, jb = bz & 15;
    const float s_ = slope[hh];

    const int tid  = threadIdx.x;
    const int lane = tid & 63, wv = tid >> 6;
    const int quad = lane >> 4, cl = lane & 15;
    const int wm = (wv & 1) * 64, wn = (wv >> 1) * 64;
    const int lr = lane >> 2, lc = (lane & 3) * 8;
    const int pcb = (wv >> 1) * 16;      // P kv-col base for this wave

    const size_t rowbase = (size_t)(bb * SEQ + jb * 256);

    // ---- stage q: 4 ks x 2 gld16 (gemm_nt A-tile pattern, linear) ----
    const u16* gq = qb + (rowbase + tm * 128 + wv * 32 + lr) * HID + hh * 128 + lc;
    u16* lq = q_lds + wv * 1024 + lr * 32 + lc;
    #pragma unroll
    for (int ks = 0; ks < 4; ks++) {
        gld16(gq + ks * 32,                 lq + ks * 4096);
        gld16(gq + ks * 32 + 16 * HID,      lq + ks * 4096 + 512);
    }

    f32x4 acc[4][4];
    const f32x4 zero = {0.f, 0.f, 0.f, 0.f};
    #pragma unroll
    for (int mi = 0; mi < 4; mi++)
        #pragma unroll
        for (int ni = 0; ni < 4; ni++) acc[mi][ni] = zero;

    // ---- inter: acc = q @ S^T  (double-buffered ST chunks) ----
    const u16* gS = ST + (size_t)bz * 16384 + (size_t)(wv * 32 + lr) * 128 + lc;
    auto stage_st = [&](int ks, int buf) {       // 2 gld16
        u16* lB = Bs + buf * 4096 + wv * 1024 + lr * 32 + lc;
        gld16(gS + ks * 32,            lB);
        gld16(gS + ks * 32 + 16 * 128, lB + 512);
    };
    stage_st(0, 0);
    #pragma unroll
    for (int ks = 0; ks < 4; ks++) {
        const int sb = ks & 1;
        if (ks + 1 < 4) {
            stage_st(ks + 1, sb ^ 1);
            asm volatile("s_waitcnt vmcnt(2)" ::: "memory");   // q + chunk ks landed
        } else {
            asm volatile("s_waitcnt vmcnt(0)" ::: "memory");
        }
        __builtin_amdgcn_s_barrier();
        bf16x8 af[4], bfv[4];
        #pragma unroll
        for (int mi = 0; mi < 4; mi++)
            af[mi] = *(const bf16x8*)&q_lds[ks * 4096 + (wm + mi * 16 + cl) * 32 + quad * 8];
        #pragma unroll
        for (int ni = 0; ni < 4; ni++)
            bfv[ni] = *(const bf16x8*)&Bs[sb * 4096 + (wn + ni * 16 + cl) * 32 + quad * 8];
        #pragma unroll
        for (int mi = 0; mi < 4; mi++)
            #pragma unroll
            for (int ni = 0; ni < 4; ni++)
                acc[mi][ni] = __builtin_amdgcn_mfma_f32_16x16x32_bf16(af[mi], bfv[ni], acc[mi][ni], 0, 0, 0);
        __builtin_amdgcn_s_barrier();   // WAR: buf sb reads done before restage
    }
    // q_decay scale
    #pragma unroll
    for (int mi = 0; mi < 4; mi++)
        #pragma unroll
        for (int r = 0; r < 4; r++) {
            const int m = tm * 128 + wm + mi * 16 + quad * 4 + r;
            const float qd = __expf(-s_ * (float)(m + 1));
            #pragma unroll
            for (int ni = 0; ni < 4; ni++) acc[mi][ni][r] *= qd;
        }

    // ---- intra: double-buffered chunk pipeline ----
    const int kmax = (tm == 0) ? 128 : 256;
    const int nc   = kmax >> 5;
    const u16* gV = vT + (size_t)bz * 32768 + (size_t)(wv * 32 + lr) * 256 + lc;
    const int krow = tid >> 4;                       // 0..15 per issue
    const int kcol = (((tid & 15) ^ (krow & 7)) * 8);
    const int kvr = pcb + cl;                        // lane's P kv-row (B-frag)

    auto stage_chunk = [&](int c, int buf) {         // 4 gld16
        u16* lk = k_lds + buf * 4096 + wv * 512 + lane * 8;
        u16* lv = Bs + buf * 4096 + wv * 1024 + lr * 32 + lc;
        const int kv0 = c * 32;
        gld16(kb + (rowbase + kv0 +      krow) * HID + hh * 128 + kcol, lk);
        gld16(kb + (rowbase + kv0 + 16 + krow) * HID + hh * 128 + kcol, lk + 2048);
        gld16(gV + kv0,            lv);
        gld16(gV + kv0 + 16 * 256, lv + 512);
    };

    stage_chunk(0, 0);
    for (int c = 0; c < nc; ++c) {
        const int cb = c & 1;
        if (c + 1 < nc) {
            stage_chunk(c + 1, cb ^ 1);
            asm volatile("s_waitcnt vmcnt(4)" ::: "memory");   // chunk c landed
        } else {
            asm volatile("s_waitcnt vmcnt(0)" ::: "memory");
        }
        __builtin_amdgcn_s_barrier();
        // P-GEMM: C[m(64 rows @wm)][kv(16 cols @pcb)] over d=128
        f32x4 acc2[4];
        #pragma unroll
        for (int mi = 0; mi < 4; mi++) acc2[mi] = zero;
        #pragma unroll
        for (int ds = 0; ds < 4; ds++) {
            bf16x8 bk = *(const bf16x8*)&k_lds[cb * 4096 + kvr * 128 + (((ds * 4 + quad) ^ (kvr & 7)) * 8)];
            #pragma unroll
            for (int mi = 0; mi < 4; mi++) {
                bf16x8 aq = *(const bf16x8*)&q_lds[ds * 4096 + (wm + mi * 16 + cl) * 32 + quad * 8];
                acc2[mi] = __builtin_amdgcn_mfma_f32_16x16x32_bf16(aq, bk, acc2[mi], 0, 0, 0);
            }
        }
        // mask + decay + bf16 -> P_lds[128][32]
        const int kv0 = c * 32;
        #pragma unroll
        for (int mi = 0; mi < 4; mi++)
            #pragma unroll
            for (int r = 0; r < 4; r++) {
                const int row = wm + mi * 16 + quad * 4 + r;
                const int mb  = tm * 128 + row;
                const int kv  = kv0 + pcb + cl;
                const int d   = mb - kv;
                const float x = acc2[mi][r];
                P_lds[row * 32 + pcb + cl] = f2bf(d >= 0 ? x * __expf(-s_ * (float)d) : 0.f);
            }
        asm volatile("s_waitcnt lgkmcnt(0)" ::: "memory");
        __builtin_amdgcn_s_barrier();
        // PV: acc += P @ vT^T
        bf16x8 afp[4], bfv[4];
        #pragma unroll
        for (int mi = 0; mi < 4; mi++)
            afp[mi] = *(const bf16x8*)&P_lds[(wm + mi * 16 + cl) * 32 + quad * 8];
        #pragma unroll
        for (int ni = 0; ni < 4; ni++)
            bfv[ni] = *(const bf16x8*)&Bs[cb * 4096 + (wn + ni * 16 + cl) * 32 + quad * 8];
        #pragma unroll
        for (int mi = 0; mi < 4; mi++)
            #pragma unroll
            for (int ni = 0; ni < 4; ni++)
                acc[mi][ni] = __builtin_amdgcn_mfma_f32_16x16x32_bf16(afp[mi], bfv[ni], acc[mi][ni], 0, 0, 0);
        __builtin_amdgcn_s_barrier();   // WAR: all waves' buf/P reads done
    }

    // ---- epilogue: attn write (verbatim M_INTRA) ----
    #pragma unroll
    for (int mi = 0; mi < 4; mi++)
        #pragma unroll
        for (int ni = 0; ni < 4; ni++)
            #pragma unroll
            for (int r = 0; r < 4; r++) {
                const int m = tm * 128 + wm + mi * 16 + quad * 4 + r;
                const int n = wn + ni * 16 + cl;
                attn[(rowbase + m) * HID + hh * 128 + n] = f2bf(acc[mi][ni][r]);
            }
}

// ---------------------------------------------------------------------------
// Per (b,h,block): kTs[d][m] = k[m][d] * exp(-s*(255-m))  (vectorized stores)
// ---------------------------------------------------------------------------
__global__ __launch_bounds__(256) void transpose_k(const u16* __restrict__ kb,
                                                   u16* __restrict__ kTs,
                                                   const float* __restrict__ slope) {
    __shared__ u16 t[128][137];   // pad 137: transposed-read lanes land 2-way max
    const int bz = blockIdx.x;
    const int bb = bz >> 8, hh = (bz >> 4) & 15, jb = bz & 15;
    const int tid = threadIdx.x;
    const float s_ = slope[hh];
    const u16* src = kb + ((size_t)(bb * SEQ + jb * 256)) * HID + hh * 128;
    u16* dst = kTs + (size_t)bz * 32768;

    for (int half = 0; half < 2; half++) {
        #pragma unroll
        for (int i = 0; i < 8; i++) {
            const int flat = tid + 256 * i;
            const int row = flat >> 4, c8 = (flat & 15) * 8;
            *(uint4*)&t[row][c8] = *(const uint4*)&src[(size_t)(half * 128 + row) * HID + c8];
        }
        __syncthreads();
        #pragma unroll
        for (int i = 0; i < 8; i++) {
            const int flat = tid + 256 * i;
            const int d = flat >> 4, mc = (flat & 15) * 8;
            u16 p[8];
            #pragma unroll
            for (int j = 0; j < 8; j++) {
                const int m = half * 128 + mc + j;
                p[j] = f2bf(bf2f(t[mc + j][d]) * __expf(-s_ * (float)(255 - m)));
            }
            uint4 pk;
            pk.x = (unsigned)p[0] | ((unsigned)p[1] << 16);
            pk.y = (unsigned)p[2] | ((unsigned)p[3] << 16);
            pk.z = (unsigned)p[4] | ((unsigned)p[5] << 16);
            pk.w = (unsigned)p[6] | ((unsigned)p[7] << 16);
            *(uint4*)&dst[(size_t)d * 256 + half * 128 + mc] = pk;
        }
        __syncthreads();
    }
}

// ---------------------------------------------------------------------------
// S_0 = 0; write S_j^T (bf16); S_{j+1} = e^{-256 s} S_j + KV_j
// ---------------------------------------------------------------------------
__global__ __launch_bounds__(256) void scan_kv(const float* __restrict__ KVT,
                                               u16* __restrict__ ST,
                                               const float* __restrict__ slope) {
    const int bh = blockIdx.x >> 4, ch = blockIdx.x & 15;
    const int off = ch * 1024 + threadIdx.x * 4;
    const float bd = __expf(-256.f * slope[bh & 15]);
    float4 st = {0.f, 0.f, 0.f, 0.f};
    for (int j = 0; j < 16; j++) {
        const size_t base = ((size_t)(bh * 16 + j)) * 16384 + off;
        uint2 o;
        o.x = (unsigned)f2bf(st.x) | ((unsigned)f2bf(st.y) << 16);
        o.y = (unsigned)f2bf(st.z) | ((unsigned)f2bf(st.w) << 16);
        *(uint2*)&ST[base] = o;
        const float4 kv = *(const float4*)&KVT[base];
        st.x = bd * st.x + kv.x;
        st.y = bd * st.y + kv.y;
        st.z = bd * st.z + kv.z;
        st.w = bd * st.w + kv.w;
    }
}

// ---------------------------------------------------------------------------
// y = gate * (attn * rsqrt(mean(attn^2)+eps)) * norm_w   (one WG per row)
// ---------------------------------------------------------------------------
__global__ __launch_bounds__(256) void rmsnorm_gate(const u16* __restrict__ attn,
                                                    const u16* __restrict__ gate,
                                                    const float* __restrict__ nw,
                                                    u16* __restrict__ y) {
    const int r = blockIdx.x, tid = threadIdx.x;
    const size_t base = (size_t)r * HID + tid * 8;
    const uint4 a = *(const uint4*)&attn[base];
    float x[8];
    x[0] = bf2f(a.x & 0xffff); x[1] = bf2f(a.x >> 16);
    x[2] = bf2f(a.y & 0xffff); x[3] = bf2f(a.y >> 16);
    x[4] = bf2f(a.z & 0xffff); x[5] = bf2f(a.z >> 16);
    x[6] = bf2f(a.w & 0xffff); x[7] = bf2f(a.w >> 16);
    float s = 0.f;
    #pragma unroll
    for (int i = 0; i < 8; i++) s += x[i] * x[i];
    #pragma unroll
    for (int off = 32; off > 0; off >>= 1) s += __shfl_down(s, off);
    __shared__ float red[4];
    if ((tid & 63) == 0) red[tid >> 6] = s;
    __syncthreads();
    const float tot = red[0] + red[1] + red[2] + red[3];
    const float sc = rsqrtf(tot * (1.f / 2048.f) + 1e-6f);
    const uint4 g = *(const uint4*)&gate[base];
    float gv[8];
    gv[0] = bf2f(g.x & 0xffff); gv[1] = bf2f(g.x >> 16);
    gv[2] = bf2f(g.y & 0xffff); gv[3] = bf2f(g.y >> 16);
    gv[4] = bf2f(g.z & 0xffff); gv[5] = bf2f(g.z >> 16);
    gv[6] = bf2f(g.w & 0xffff); gv[7] = bf2f(g.w >> 16);
    const float4 w0 = *(const float4*)&nw[tid * 8];
    const float4 w1 = *(const float4*)&nw[tid * 8 + 4];
    const float wv[8] = {w0.x, w0.y, w0.z, w0.w, w1.x, w1.y, w1.z, w1.w};
    u16 o[8];
    #pragma unroll
    for (int i = 0; i < 8; i++) o[i] = f2bf(gv[i] * x[i] * sc * wv[i]);
    uint4 ov;
    ov.x = (unsigned)o[0] | ((unsigned)o[1] << 16);
    ov.y = (unsigned)o[2] | ((unsigned)o[3] << 16);
    ov.z = (unsigned)o[4] | ((unsigned)o[5] << 16);
    ov.w = (unsigned)o[6] | ((unsigned)o[7] << 16);
    *(uint4*)&y[base] = ov;
}

// ---------------------------------------------------------------------------
extern "C" void kernel_launch(void* const* d_in, const int* in_sizes, int n_in,
                              void* d_out, int out_size, void* d_ws, size_t ws_size,
                              hipStream_t stream) {
    const float* hidden = (const float*)d_in[0];
    const float* slope  = (const float*)d_in[1];
    const float* w_qkv  = (const float*)d_in[2];
    const float* w_gate = (const float*)d_in[3];
    const float* w_out  = (const float*)d_in[4];
    const float* norm_w = (const float*)d_in[5];
    float* out = (float*)d_out;

    // 7 slots x 33,554,432 B = 234,881,024 B total
    char* w = (char*)d_ws;
    u16* qb   = (u16*)(w);                 // S0: q                 [QKV .. fused_pv]
    u16* kb   = (u16*)(w +  33554432);     // S1: k                 [QKV .. fused_pv]
    u16* kTs  = (u16*)(w +  67108864);     // S2: kTs               [transpose .. KVT]
    u16* hid_bf = (u16*)(w + 100663296);   // S3: hidden bf16       [cast .. QKV]
    u16* vT   = (u16*)(w + 134217728);     // S4: vT (via QKV)      [QKV .. fused_pv]
    u16* gate = (u16*)(w + 167772160);     // S5: gate (via QKV)    [QKV .. rms]
    u16* wqkv_bf  = (u16*)(w + 201326592); // S6: w_qkv bf16 25.17M [cast .. QKV]
    u16* wgate_bf = (u16*)(w + 201326592 + 25165824); // S6 tail 8.39M, contiguous
    // aliases (disjoint lifetimes):
    float* KVT  = (float*)hid_bf;          // S3: KV^T fp32         [KVT .. scan]
    u16*   ST   = kTs;                     // S2: S^T bf16 16.8M    [scan .. fused_pv]
    u16*   wout_bf = kb;                   // S1: w_out bf16        [cast .. OUT]
    u16*   attn = wqkv_bf;                 // S6: attn              [fused_pv .. rms]
    u16*   y    = kTs;                     // S2: y                 [rms .. OUT]

    static bool s_attr = false;
    if (!s_attr) {
        (void)hipFuncSetAttribute((const void*)gemm256<0>,
                                  hipFuncAttributeMaxDynamicSharedMemorySize, 131072);
        (void)hipFuncSetAttribute((const void*)gemm256<1>,
                                  hipFuncAttributeMaxDynamicSharedMemorySize, 131072);
        s_attr = true;
    }

    // fused casts: hidden | w_qkv | w_gate in one launch
    castk3<<<32768, 256, 0, stream>>>(hidden, hid_bf, w_qkv, wqkv_bf, w_gate, wgate_bf);

    // fused qkv+gate: B = [w_qkv ; w_gate] (8192 x 2048 contiguous)
    gemm256<0><<<dim3(1024), dim3(512), 131072, stream>>>(hid_bf, wqkv_bf, qb, vT, gate);
    transpose_k     <<<512,             256, 0, stream>>>(kb, kTs, slope);
    gemm_nt<M_KVT ><<<dim3(1, 1, 512),  256, 0, stream>>>(vT, kTs, KVT, slope, 0, nullptr, nullptr);
    scan_kv         <<<512,             256, 0, stream>>>(KVT, ST, slope);
    fused_pv        <<<dim3(2, 1, 512), 256, 0, stream>>>(qb, kb, ST, vT, attn, slope);
    castk<<< 4096, 256, 0, stream>>>(w_out, wout_bf);
    rmsnorm_gate    <<<8192,            256, 0, stream>>>(attn, gate, norm_w, y);
    gemm256<1><<<dim3(256), dim3(512), 131072, stream>>>(y, wout_bf, (void*)out, nullptr, nullptr);
}

// Round 16
// 441.625 us; speedup vs baseline: 1.0159x; 1.0016x over previous
//
#include <hip/hip_runtime.h>

// ---------------------------------------------------------------------------
// MiniMax-M1 Lightning Attention forward, MI355X / gfx950.
//   0. castk3: fp32->bf16 for hidden + w_qkv + w_gate in ONE launch
//   1. fused qkv+gate via 256x256 lockstep GEMM (R11 rotated-read schedule)
//      epilogue: q,k,gate row-major; v stored DIRECTLY transposed (vT)
//   2. transpose_k: kTs[d][m] = silu_k[m][d] * exp(-s*(255-m))
//   3. KVT_j = vT @ kTs^T  (fp32), DOUBLE-BUFFERED staging (vmcnt(4)/chunk)
//   4. scan: S_{j+1} = e^{-256 s} S_j + KV_j ; store S_j^T bf16  [512 WGs]
//   5+6 FUSED (fused_pv): inter (q@S^T, q_decay) + per-32-kv-chunk P in-reg
//      -> LDS round-trip -> acc += P@v.  BOTH loops double-buffered.
//   7. rmsnorm_gate: y = gate * rmsnorm(attn) * norm_w  (+ folds w_out cast)
//   8. out = y @ w_out^T via same 256 GEMM [fp32 -> d_out]
// Workspace: 7 slots x 33,554,432 B = 234,881,024 B peak.
// ---------------------------------------------------------------------------

typedef unsigned short u16;
typedef __bf16 bf16x8 __attribute__((ext_vector_type(8)));
typedef float f32x4 __attribute__((ext_vector_type(4)));

#define SEQ 4096
#define HID 2048

__device__ __forceinline__ u16 f2bf(float f) {
    union { float f; unsigned u; } v; v.f = f;
    unsigned r = v.u + 0x7fffu + ((v.u >> 16) & 1u);   // round-to-nearest-even
    return (u16)(r >> 16);
}
__device__ __forceinline__ float bf2f(u16 u) {
    union { unsigned u; float f; } v; v.u = ((unsigned)u) << 16; return v.f;
}

// async global->LDS, 16B per lane; lds dest must be wave-uniform base (+lane*16)
typedef __attribute__((address_space(1))) unsigned char gas_u8;
typedef __attribute__((address_space(3))) unsigned char las_u8;
__device__ __forceinline__ void gld16(const void* g, void* l) {
    __builtin_amdgcn_global_load_lds((gas_u8*)g, (las_u8*)l, 16, 0, 0);
}

// ---------------------------------------------------------------------------
// castk3: hidden|w_qkv|w_gate fp32->bf16 in one launch (4 elems/thread).
// ---------------------------------------------------------------------------
__global__ __launch_bounds__(256) void castk3(const float* __restrict__ a, u16* __restrict__ ao,
                                              const float* __restrict__ b, u16* __restrict__ bo,
                                              const float* __restrict__ c, u16* __restrict__ co) {
    const int bid = blockIdx.x;
    const float* src; u16* dst; size_t i;
    if (bid < 16384)      { src = a; dst = ao; i = (size_t)bid * 256 + threadIdx.x; }
    else if (bid < 28672) { src = b; dst = bo; i = (size_t)(bid - 16384) * 256 + threadIdx.x; }
    else                  { src = c; dst = co; i = (size_t)(bid - 28672) * 256 + threadIdx.x; }
    const float4 f = *(const float4*)&src[i * 4];
    uint2 o;
    o.x = (unsigned)f2bf(f.x) | ((unsigned)f2bf(f.y) << 16);
    o.y = (unsigned)f2bf(f.z) | ((unsigned)f2bf(f.w) << 16);
    *(uint2*)&dst[i * 4] = o;
}

// ---------------------------------------------------------------------------
// 256x256-tile lockstep pipelined NT GEMM (R11 rotated-read schedule).
// MODE 0: fused QKV+gate epilogue; MODE 1: f32 out.
// ---------------------------------------------------------------------------
template <int MODE>
__global__ __launch_bounds__(512, 2) void gemm256(const u16* __restrict__ A,
                                                  const u16* __restrict__ Bm,
                                                  void* __restrict__ Cv,
                                                  void* __restrict__ aux,
                                                  void* __restrict__ aux2) {
    constexpr int NTN = (MODE == 0) ? 32 : 8;     // tiles along N
    constexpr int NT  = 32;                       // K tiles (2048 / 64)
    extern __shared__ u16 smem[];                 // [2][A 16384 | B 16384]

    // XCD swizzle: 8 XCDs; per-XCD 4-row x 8-col rectangular supertiles
    const int bid = blockIdx.x;
    const int xcd = bid & 7, l = bid >> 3;
    int tm, tn;
    if constexpr (MODE == 0) {       // 32x32 tile grid, 128 WGs per XCD
        tm = xcd * 4 + (l & 3);
        tn = ((l >> 2) & 7) | ((l >> 5) << 3);
    } else {                         // 32x8 grid, 32 WGs per XCD (4x8 rect)
        const int wgid = xcd * 32 + l;
        tm = wgid / NTN; tn = wgid % NTN;
    }

    const int tid  = threadIdx.x;
    const int lane = tid & 63, wv = tid >> 6;
    const int quad = lane >> 4, cl = lane & 15;
    const int wm = (wv & 1) * 128, wn = (wv >> 1) * 64;

    const int srw  = tid >> 3;
    const int colo = ((tid & 7) ^ (srw & 7)) * 8;
    const u16* gA0 = A  + (size_t)(tm * 256 + srw) * HID + colo;
    const u16* gB0 = Bm + (size_t)(tn * 256 + srw) * HID + colo;

    const int x0 = ((quad       ^ (cl & 7)) * 8);
    const int x1 = (((4 + quad) ^ (cl & 7)) * 8);

    f32x4 acc[8][4];
    const f32x4 zero = {0.f, 0.f, 0.f, 0.f};
    #pragma unroll
    for (int a = 0; a < 8; a++)
        #pragma unroll
        for (int b = 0; b < 4; b++) acc[a][b] = zero;

    bf16x8 af[8], b0[4], b1[4];

    auto STG = [&](int kt, int mat, int hh) {   // stage one 128x64 half-tile
        const u16* g = (mat ? gB0 : gA0) + (size_t)(hh * 128) * HID + kt * 64;
        u16* lp = smem + (kt & 1) * 32768 + mat * 16384 + hh * 8192 + wv * 512;
        gld16(g, lp);
        gld16(g + (size_t)64 * HID, lp + 4096);
    };
    auto LDA = [&](int qm, int ab) {
        #pragma unroll
        for (int mi = 0; mi < 4; mi++) {
            const int rr = (wm + qm * 64 + mi * 16 + cl) * 64 + ab;
            af[mi * 2 + 0] = *(const bf16x8*)&smem[rr + x0];
            af[mi * 2 + 1] = *(const bf16x8*)&smem[rr + x1];
        }
    };
    auto LDB = [&](bf16x8* d, int qn, int bb2) {
        #pragma unroll
        for (int ni = 0; ni < 2; ni++) {
            const int rr = (wn + qn * 32 + ni * 16 + cl) * 64 + bb2;
            d[ni * 2 + 0] = *(const bf16x8*)&smem[rr + x0];
            d[ni * 2 + 1] = *(const bf16x8*)&smem[rr + x1];
        }
    };
    auto MM = [&](int qm, int qn, const bf16x8* bv) {
        #pragma unroll
        for (int mi = 0; mi < 4; mi++)
            #pragma unroll
            for (int ni = 0; ni < 2; ni++) {
                f32x4 c = acc[qm * 4 + mi][qn * 2 + ni];
                c = __builtin_amdgcn_mfma_f32_16x16x32_bf16(af[mi * 2 + 0], bv[ni * 2 + 0], c, 0, 0, 0);
                c = __builtin_amdgcn_mfma_f32_16x16x32_bf16(af[mi * 2 + 1], bv[ni * 2 + 1], c, 0, 0, 0);
                acc[qm * 4 + mi][qn * 2 + ni] = c;
            }
    };

    // prologue: issue stream per tile = B.lo, B.hi, A.lo, A.hi
    STG(0, 1, 0); STG(0, 1, 1); STG(0, 0, 0); STG(0, 0, 1);
    STG(1, 1, 0); STG(1, 1, 1); STG(1, 0, 0);
    asm volatile("s_waitcnt vmcnt(6)" ::: "memory");   // tile 0 resident
    __builtin_amdgcn_s_barrier();
    LDA(0, 0); LDB(b0, 0, 16384);      // ph0 operands (drain at ph0 lgkm(0))

    #pragma unroll 2
    for (int t = 0; t < NT; ++t) {
        const int ab  = (t & 1) * 32768;
        const int bb2 = ab + 16384;
        const int nab = ((t + 1) & 1) * 32768;
        // phase 0: MM(0,0)=A0*b0 (reads from prev ph3/prologue); read b1
        if (t + 1 < NT) STG(t + 1, 0, 1);
        __builtin_amdgcn_s_barrier();
        asm volatile("s_waitcnt lgkmcnt(0)" ::: "memory");
        __builtin_amdgcn_s_setprio(1); MM(0, 0, b0); __builtin_amdgcn_s_setprio(0);
        LDB(b1, 1, bb2);
        __builtin_amdgcn_s_barrier();
        // phase 1: MM(0,1)=A0*b1; read A1
        if (t + 2 < NT) STG(t + 2, 1, 0);
        __builtin_amdgcn_s_barrier();
        asm volatile("s_waitcnt lgkmcnt(0)" ::: "memory");
        __builtin_amdgcn_s_setprio(1); MM(0, 1, b1); __builtin_amdgcn_s_setprio(0);
        LDA(1, ab);
        __builtin_amdgcn_s_barrier();
        // phase 2: MM(1,1)=A1*b1
        if (t + 2 < NT) STG(t + 2, 1, 1);
        __builtin_amdgcn_s_barrier();
        asm volatile("s_waitcnt lgkmcnt(0)" ::: "memory");
        __builtin_amdgcn_s_setprio(1); MM(1, 1, b1); __builtin_amdgcn_s_setprio(0);
        __builtin_amdgcn_s_barrier();
        // phase 3: MM(1,0)=A1*b0; boundary vmcnt(6); post-MFMA next A0,b0
        if (t + 2 < NT) {
            STG(t + 2, 0, 0);
            asm volatile("s_waitcnt vmcnt(6)" ::: "memory");
        } else {
            asm volatile("s_waitcnt vmcnt(0)" ::: "memory");
        }
        __builtin_amdgcn_s_barrier();
        __builtin_amdgcn_s_setprio(1); MM(1, 0, b0); __builtin_amdgcn_s_setprio(0);
        if (t + 1 < NT) { LDA(0, nab); LDB(b0, 0, nab + 16384); }
        __builtin_amdgcn_s_barrier();
    }

    // epilogue
    if constexpr (MODE == 0) {
        const int grp = tn * 2 + (wn >> 7);
        const int which = grp >> 4, hd = grp & 15;
        const int n64 = wn & 64;
        if (which == 2) {
            const size_t bz = (size_t)((tm >> 4) * 256 + hd * 16 + (tm & 15));
            u16* tdst = (u16*)aux + bz * 32768;
            #pragma unroll
            for (int a = 0; a < 8; a++) {
                const int mm = wm + (a >> 2) * 64 + (a & 3) * 16 + quad * 4;
                #pragma unroll
                for (int b = 0; b < 4; b++) {
                    const int d = n64 + (b >> 1) * 32 + (b & 1) * 16 + cl;
                    u16 p[4];
                    #pragma unroll
                    for (int r = 0; r < 4; r++) {
                        const float x = acc[a][b][r];
                        p[r] = f2bf(x / (1.f + __expf(-x)));
                    }
                    uint2 pk;
                    pk.x = (unsigned)p[0] | ((unsigned)p[1] << 16);
                    pk.y = (unsigned)p[2] | ((unsigned)p[3] << 16);
                    *(uint2*)&tdst[(size_t)d * 256 + mm] = pk;
                }
            }
            return;
        }
        u16* dst = (which == 0) ? (u16*)Cv
                 : (which == 1) ? (u16*)Cv + (size_t)16777216   // k slot (S1)
                                : (u16*)aux2;                   // gate slot
        #pragma unroll
        for (int a = 0; a < 8; a++)
            #pragma unroll
            for (int b = 0; b < 4; b++)
                #pragma unroll
                for (int r = 0; r < 4; r++) {
                    const int m = tm * 256 + wm + (a >> 2) * 64 + (a & 3) * 16 + quad * 4 + r;
                    const int col = hd * 128 + n64 + (b >> 1) * 32 + (b & 1) * 16 + cl;
                    const float x = acc[a][b][r];
                    const float v = (which == 3) ? 1.f / (1.f + __expf(-x))
                                                 : x / (1.f + __expf(-x));
                    dst[(size_t)m * HID + col] = f2bf(v);
                }
        return;
    } else {
        float* C = (float*)Cv;
        #pragma unroll
        for (int a = 0; a < 8; a++)
            #pragma unroll
            for (int b = 0; b < 4; b++)
                #pragma unroll
                for (int r = 0; r < 4; r++) {
                    const int m = tm * 256 + wm + (a >> 2) * 64 + (a & 3) * 16 + quad * 4 + r;
                    const int n = tn * 256 + wn + (b >> 1) * 32 + (b & 1) * 16 + cl;
                    C[(size_t)m * HID + n] = acc[a][b][r];
                }
    }
}

// ---------------------------------------------------------------------------
// 128x128-tile NT GEMM for M_KVT, DOUBLE-BUFFERED (vmcnt(4) per chunk).
// ---------------------------------------------------------------------------
#define M_KVT   4

template <int MODE>
__global__ __launch_bounds__(256) void gemm_nt(const u16* __restrict__ A,
                                               const u16* __restrict__ Bm,
                                               void* __restrict__ Cv,
                                               const float* __restrict__ slope,
                                               int bz0,
                                               void* __restrict__ aux,
                                               void* __restrict__ aux2) {
    const int tid = threadIdx.x;
    const int bz  = blockIdx.z + bz0;

    __shared__ u16 smem[16384];           // 2 x (As 4096 + Bs 4096), 32 KB

    const int lane = tid & 63, wv = tid >> 6;
    const int wm = (wv & 1) * 64, wn = (wv >> 1) * 64;
    const int quad = lane >> 4, cl = lane & 15;
    const int lr = lane >> 2;
    const int lc = (lane & 3) * 8;

    f32x4 acc[4][4];
    const f32x4 zero = {0.f, 0.f, 0.f, 0.f};
    #pragma unroll
    for (int mi = 0; mi < 4; mi++)
        #pragma unroll
        for (int ni = 0; ni < 4; ni++) acc[mi][ni] = zero;

    // M_KVT: A = vT[bz], B = kTs[bz], both ld 256, kmax 256 (8 chunks)
    const u16* gA = A  + (size_t)bz * 32768 + (size_t)(wv * 32 + lr) * 256 + lc;
    const u16* gB = Bm + (size_t)bz * 32768 + (size_t)(wv * 32 + lr) * 256 + lc;

    auto stage = [&](int c, int buf) {    // 4 gld16
        u16* lA = smem + buf * 8192 + wv * 1024;
        u16* lB = lA + 4096;
        const int k0 = c * 32;
        gld16(gA + k0,                    lA);
        gld16(gA + k0 + (size_t)16 * 256, lA + 512);
        gld16(gB + k0,                    lB);
        gld16(gB + k0 + (size_t)16 * 256, lB + 512);
    };

    stage(0, 0);
    for (int c = 0; c < 8; ++c) {
        const int cb = c & 1;
        if (c + 1 < 8) {
            stage(c + 1, cb ^ 1);
            asm volatile("s_waitcnt vmcnt(4)" ::: "memory");   // chunk c landed
        } else {
            asm volatile("s_waitcnt vmcnt(0)" ::: "memory");
        }
        __builtin_amdgcn_s_barrier();
        const u16* As = smem + cb * 8192;
        const u16* Bs = As + 4096;
        const int ko = quad * 8;
        bf16x8 af[4], bfv[4];
        #pragma unroll
        for (int mi = 0; mi < 4; mi++) af[mi] = *(const bf16x8*)&As[(wm + mi * 16 + cl) * 32 + ko];
        #pragma unroll
        for (int ni = 0; ni < 4; ni++) bfv[ni] = *(const bf16x8*)&Bs[(wn + ni * 16 + cl) * 32 + ko];
        #pragma unroll
        for (int mi = 0; mi < 4; mi++)
            #pragma unroll
            for (int ni = 0; ni < 4; ni++)
                acc[mi][ni] = __builtin_amdgcn_mfma_f32_16x16x32_bf16(af[mi], bfv[ni], acc[mi][ni], 0, 0, 0);
        __builtin_amdgcn_s_barrier();   // WAR: all waves' reads of buf cb done
    }

    #pragma unroll
    for (int mi = 0; mi < 4; mi++)
        #pragma unroll
        for (int ni = 0; ni < 4; ni++)
            #pragma unroll
            for (int r = 0; r < 4; r++) {
                const int m = wm + mi * 16 + quad * 4 + r;
                const int n = wn + ni * 16 + cl;
                ((float*)Cv)[(size_t)bz * 16384 + m * 128 + n] = acc[mi][ni][r];
            }
}

// ---------------------------------------------------------------------------
// FUSED P+INTRA: grid (2,1,512) = (row-half tm, -, bz); 256 thr = 4 waves 2x2.
// BOTH loops double-buffered with counted vmcnt.
// ---------------------------------------------------------------------------
__global__ __launch_bounds__(256) void fused_pv(const u16* __restrict__ qb,
                                                const u16* __restrict__ kb,
                                                const u16* __restrict__ ST,
                                                const u16* __restrict__ vT,
                                                u16* __restrict__ attn,
                                                const float* __restrict__ slope) {
    __shared__ u16 smem[36864];   // q 16384 | k 2x4096 | P 4096 | Bs 2x4096
    u16* q_lds = smem;            // [4][128][32]
    u16* k_lds = smem + 16384;    // [2][32][128] row-XOR swizzled
    u16* P_lds = smem + 24576;    // [128][32]
    u16* Bs    = smem + 28672;    // [2][128][32]  (ST chunks / v chunks)

    const int tm = blockIdx.x;           // row half within the 256-block
    const int bz = blockIdx.z;
    const int bb = bz >> 8, hh = (bz >> 4) & 15, jb = bz & 15;
    const float s_ = slope[hh];

    const int tid  = threadIdx.x;
    const int lane = tid & 63, wv = tid >> 6;
    const int quad = lane >> 4, cl = lane & 15;
    const int wm = (wv & 1) * 64, wn = (wv >> 1) * 64;
    const int lr = lane >> 2, lc = (lane & 3) * 8;
    const int pcb = (wv >> 1) * 16;      // P kv-col base for this wave

    const size_t rowbase = (size_t)(bb * SEQ + jb * 256);

    // ---- stage q: 4 ks x 2 gld16 (gemm_nt A-tile pattern, linear) ----
    const u16* gq = qb + (rowbase + tm * 128 + wv * 32 + lr) * HID + hh * 128 + lc;
    u16* lq = q_lds + wv * 1024 + lr * 32 + lc;
    #pragma unroll
    for (int ks = 0; ks < 4; ks++) {
        gld16(gq + ks * 32,                 lq + ks * 4096);
        gld16(gq + ks * 32 + 16 * HID,      lq + ks * 4096 + 512);
    }

    f32x4 acc[4][4];
    const f32x4 zero = {0.f, 0.f, 0.f, 0.f};
    #pragma unroll
    for (int mi = 0; mi < 4; mi++)
        #pragma unroll
        for (int ni = 0; ni < 4; ni++) acc[mi][ni] = zero;

    // ---- inter: acc = q @ S^T  (double-buffered ST chunks) ----
    const u16* gS = ST + (size_t)bz * 16384 + (size_t)(wv * 32 + lr) * 128 + lc;
    auto stage_st = [&](int ks, int buf) {       // 2 gld16
        u16* lB = Bs + buf * 4096 + wv * 1024 + lr * 32 + lc;
        gld16(gS + ks * 32,            lB);
        gld16(gS + ks * 32 + 16 * 128, lB + 512);
    };
    stage_st(0, 0);
    #pragma unroll
    for (int ks = 0; ks < 4; ks++) {
        const int sb = ks & 1;
        if (ks + 1 < 4) {
            stage_st(ks + 1, sb ^ 1);
            asm volatile("s_waitcnt vmcnt(2)" ::: "memory");   // q + chunk ks landed
        } else {
            asm volatile("s_waitcnt vmcnt(0)" ::: "memory");
        }
        __builtin_amdgcn_s_barrier();
        bf16x8 af[4], bfv[4];
        #pragma unroll
        for (int mi = 0; mi < 4; mi++)
            af[mi] = *(const bf16x8*)&q_lds[ks * 4096 + (wm + mi * 16 + cl) * 32 + quad * 8];
        #pragma unroll
        for (int ni = 0; ni < 4; ni++)
            bfv[ni] = *(const bf16x8*)&Bs[sb * 4096 + (wn + ni * 16 + cl) * 32 + quad * 8];
        #pragma unroll
        for (int mi = 0; mi < 4; mi++)
            #pragma unroll
            for (int ni = 0; ni < 4; ni++)
                acc[mi][ni] = __builtin_amdgcn_mfma_f32_16x16x32_bf16(af[mi], bfv[ni], acc[mi][ni], 0, 0, 0);
        __builtin_amdgcn_s_barrier();   // WAR: buf sb reads done before restage
    }
    // q_decay scale
    #pragma unroll
    for (int mi = 0; mi < 4; mi++)
        #pragma unroll
        for (int r = 0; r < 4; r++) {
            const int m = tm * 128 + wm + mi * 16 + quad * 4 + r;
            const float qd = __expf(-s_ * (float)(m + 1));
            #pragma unroll
            for (int ni = 0; ni < 4; ni++) acc[mi][ni][r] *= qd;
        }

    // ---- intra: double-buffered chunk pipeline ----
    const int kmax = (tm == 0) ? 128 : 256;
    const int nc   = kmax >> 5;
    const u16* gV = vT + (size_t)bz * 32768 + (size_t)(wv * 32 + lr) * 256 + lc;
    const int krow = tid >> 4;                       // 0..15 per issue
    const int kcol = (((tid & 15) ^ (krow & 7)) * 8);
    const int kvr = pcb + cl;                        // lane's P kv-row (B-frag)

    auto stage_chunk = [&](int c, int buf) {         // 4 gld16
        u16* lk = k_lds + buf * 4096 + wv * 512 + lane * 8;
        u16* lv = Bs + buf * 4096 + wv * 1024 + lr * 32 + lc;
        const int kv0 = c * 32;
        gld16(kb + (rowbase + kv0 +      krow) * HID + hh * 128 + kcol, lk);
        gld16(kb + (rowbase + kv0 + 16 + krow) * HID + hh * 128 + kcol, lk + 2048);
        gld16(gV + kv0,            lv);
        gld16(gV + kv0 + 16 * 256, lv + 512);
    };

    stage_chunk(0, 0);
    for (int c = 0; c < nc; ++c) {
        const int cb = c & 1;
        if (c + 1 < nc) {
            stage_chunk(c + 1, cb ^ 1);
            asm volatile("s_waitcnt vmcnt(4)" ::: "memory");   // chunk c landed
        } else {
            asm volatile("s_waitcnt vmcnt(0)" ::: "memory");
        }
        __builtin_amdgcn_s_barrier();
        // P-GEMM: C[m(64 rows @wm)][kv(16 cols @pcb)] over d=128
        f32x4 acc2[4];
        #pragma unroll
        for (int mi = 0; mi < 4; mi++) acc2[mi] = zero;
        #pragma unroll
        for (int ds = 0; ds < 4; ds++) {
            bf16x8 bk = *(const bf16x8*)&k_lds[cb * 4096 + kvr * 128 + (((ds * 4 + quad) ^ (kvr & 7)) * 8)];
            #pragma unroll
            for (int mi = 0; mi < 4; mi++) {
                bf16x8 aq = *(const bf16x8*)&q_lds[ds * 4096 + (wm + mi * 16 + cl) * 32 + quad * 8];
                acc2[mi] = __builtin_amdgcn_mfma_f32_16x16x32_bf16(aq, bk, acc2[mi], 0, 0, 0);
            }
        }
        // mask + decay + bf16 -> P_lds[128][32]
        const int kv0 = c * 32;
        #pragma unroll
        for (int mi = 0; mi < 4; mi++)
            #pragma unroll
            for (int r = 0; r < 4; r++) {
                const int row = wm + mi * 16 + quad * 4 + r;
                const int mb  = tm * 128 + row;
                const int kv  = kv0 + pcb + cl;
                const int d   = mb - kv;
                const float x = acc2[mi][r];
                P_lds[row * 32 + pcb + cl] = f2bf(d >= 0 ? x * __expf(-s_ * (float)d) : 0.f);
            }
        asm volatile("s_waitcnt lgkmcnt(0)" ::: "memory");
        __builtin_amdgcn_s_barrier();
        // PV: acc += P @ vT^T
        bf16x8 afp[4], bfv[4];
        #pragma unroll
        for (int mi = 0; mi < 4; mi++)
            afp[mi] = *(const bf16x8*)&P_lds[(wm + mi * 16 + cl) * 32 + quad * 8];
        #pragma unroll
        for (int ni = 0; ni < 4; ni++)
            bfv[ni] = *(const bf16x8*)&Bs[cb * 4096 + (wn + ni * 16 + cl) * 32 + quad * 8];
        #pragma unroll
        for (int mi = 0; mi < 4; mi++)
            #pragma unroll
            for (int ni = 0; ni < 4; ni++)
                acc[mi][ni] = __builtin_amdgcn_mfma_f32_16x16x32_bf16(afp[mi], bfv[ni], acc[mi][ni], 0, 0, 0);
        __builtin_amdgcn_s_barrier();   // WAR: all waves' buf/P reads done
    }

    // ---- epilogue: attn write (verbatim M_INTRA) ----
    #pragma unroll
    for (int mi = 0; mi < 4; mi++)
        #pragma unroll
        for (int ni = 0; ni < 4; ni++)
            #pragma unroll
            for (int r = 0; r < 4; r++) {
                const int m = tm * 128 + wm + mi * 16 + quad * 4 + r;
                const int n = wn + ni * 16 + cl;
                attn[(rowbase + m) * HID + hh * 128 + n] = f2bf(acc[mi][ni][r]);
            }
}

// ---------------------------------------------------------------------------
// Per (b,h,block): kTs[d][m] = k[m][d] * exp(-s*(255-m))  (vectorized stores)
// ---------------------------------------------------------------------------
__global__ __launch_bounds__(256) void transpose_k(const u16* __restrict__ kb,
                                                   u16* __restrict__ kTs,
                                                   const float* __restrict__ slope) {
    __shared__ u16 t[128][137];   // pad 137: transposed-read lanes land 2-way max
    const int bz = blockIdx.x;
    const int bb = bz >> 8, hh = (bz >> 4) & 15, jb = bz & 15;
    const int tid = threadIdx.x;
    const float s_ = slope[hh];
    const u16* src = kb + ((size_t)(bb * SEQ + jb * 256)) * HID + hh * 128;
    u16* dst = kTs + (size_t)bz * 32768;

    for (int half = 0; half < 2; half++) {
        #pragma unroll
        for (int i = 0; i < 8; i++) {
            const int flat = tid + 256 * i;
            const int row = flat >> 4, c8 = (flat & 15) * 8;
            *(uint4*)&t[row][c8] = *(const uint4*)&src[(size_t)(half * 128 + row) * HID + c8];
        }
        __syncthreads();
        #pragma unroll
        for (int i = 0; i < 8; i++) {
            const int flat = tid + 256 * i;
            const int d = flat >> 4, mc = (flat & 15) * 8;
            u16 p[8];
            #pragma unroll
            for (int j = 0; j < 8; j++) {
                const int m = half * 128 + mc + j;
                p[j] = f2bf(bf2f(t[mc + j][d]) * __expf(-s_ * (float)(255 - m)));
            }
            uint4 pk;
            pk.x = (unsigned)p[0] | ((unsigned)p[1] << 16);
            pk.y = (unsigned)p[2] | ((unsigned)p[3] << 16);
            pk.z = (unsigned)p[4] | ((unsigned)p[5] << 16);
            pk.w = (unsigned)p[6] | ((unsigned)p[7] << 16);
            *(uint4*)&dst[(size_t)d * 256 + half * 128 + mc] = pk;
        }
        __syncthreads();
    }
}

// ---------------------------------------------------------------------------
// S_0 = 0; write S_j^T (bf16); S_{j+1} = e^{-256 s} S_j + KV_j
// ---------------------------------------------------------------------------
__global__ __launch_bounds__(256) void scan_kv(const float* __restrict__ KVT,
                                               u16* __restrict__ ST,
                                               const float* __restrict__ slope) {
    const int bh = blockIdx.x >> 4, ch = blockIdx.x & 15;
    const int off = ch * 1024 + threadIdx.x * 4;
    const float bd = __expf(-256.f * slope[bh & 15]);
    float4 st = {0.f, 0.f, 0.f, 0.f};
    for (int j = 0; j < 16; j++) {
        const size_t base = ((size_t)(bh * 16 + j)) * 16384 + off;
        uint2 o;
        o.x = (unsigned)f2bf(st.x) | ((unsigned)f2bf(st.y) << 16);
        o.y = (unsigned)f2bf(st.z) | ((unsigned)f2bf(st.w) << 16);
        *(uint2*)&ST[base] = o;
        const float4 kv = *(const float4*)&KVT[base];
        st.x = bd * st.x + kv.x;
        st.y = bd * st.y + kv.y;
        st.z = bd * st.z + kv.z;
        st.w = bd * st.w + kv.w;
    }
}

// ---------------------------------------------------------------------------
// y = gate * (attn * rsqrt(mean(attn^2)+eps)) * norm_w   (one WG per row)
// Also folds the w_out fp32->bf16 cast (2 elems/thread; 8192x512 = 2048^2).
// ---------------------------------------------------------------------------
__global__ __launch_bounds__(256) void rmsnorm_gate(const u16* __restrict__ attn,
                                                    const u16* __restrict__ gate,
                                                    const float* __restrict__ nw,
                                                    u16* __restrict__ y,
                                                    const float* __restrict__ wout,
                                                    u16* __restrict__ wout_bf) {
    const int r = blockIdx.x, tid = threadIdx.x;

    // folded w_out cast: block r covers elements [r*512, r*512+512)
    {
        const size_t wi = (size_t)r * 512 + tid * 2;
        const float2 wf = *(const float2*)&wout[wi];
        *(unsigned*)&wout_bf[wi] = (unsigned)f2bf(wf.x) | ((unsigned)f2bf(wf.y) << 16);
    }

    const size_t base = (size_t)r * HID + tid * 8;
    const uint4 a = *(const uint4*)&attn[base];
    float x[8];
    x[0] = bf2f(a.x & 0xffff); x[1] = bf2f(a.x >> 16);
    x[2] = bf2f(a.y & 0xffff); x[3] = bf2f(a.y >> 16);
    x[4] = bf2f(a.z & 0xffff); x[5] = bf2f(a.z >> 16);
    x[6] = bf2f(a.w & 0xffff); x[7] = bf2f(a.w >> 16);
    float s = 0.f;
    #pragma unroll
    for (int i = 0; i < 8; i++) s += x[i] * x[i];
    #pragma unroll
    for (int off = 32; off > 0; off >>= 1) s += __shfl_down(s, off);
    __shared__ float red[4];
    if ((tid & 63) == 0) red[tid >> 6] = s;
    __syncthreads();
    const float tot = red[0] + red[1] + red[2] + red[3];
    const float sc = rsqrtf(tot * (1.f / 2048.f) + 1e-6f);
    const uint4 g = *(const uint4*)&gate[base];
    float gv[8];
    gv[0] = bf2f(g.x & 0xffff); gv[1] = bf2f(g.x >> 16);
    gv[2] = bf2f(g.y & 0xffff); gv[3] = bf2f(g.y >> 16);
    gv[4] = bf2f(g.z & 0xffff); gv[5] = bf2f(g.z >> 16);
    gv[6] = bf2f(g.w & 0xffff); gv[7] = bf2f(g.w >> 16);
    const float4 w0 = *(const float4*)&nw[tid * 8];
    const float4 w1 = *(const float4*)&nw[tid * 8 + 4];
    const float wv[8] = {w0.x, w0.y, w0.z, w0.w, w1.x, w1.y, w1.z, w1.w};
    u16 o[8];
    #pragma unroll
    for (int i = 0; i < 8; i++) o[i] = f2bf(gv[i] * x[i] * sc * wv[i]);
    uint4 ov;
    ov.x = (unsigned)o[0] | ((unsigned)o[1] << 16);
    ov.y = (unsigned)o[2] | ((unsigned)o[3] << 16);
    ov.z = (unsigned)o[4] | ((unsigned)o[5] << 16);
    ov.w = (unsigned)o[6] | ((unsigned)o[7] << 16);
    *(uint4*)&y[base] = ov;
}

// ---------------------------------------------------------------------------
extern "C" void kernel_launch(void* const* d_in, const int* in_sizes, int n_in,
                              void* d_out, int out_size, void* d_ws, size_t ws_size,
                              hipStream_t stream) {
    const float* hidden = (const float*)d_in[0];
    const float* slope  = (const float*)d_in[1];
    const float* w_qkv  = (const float*)d_in[2];
    const float* w_gate = (const float*)d_in[3];
    const float* w_out  = (const float*)d_in[4];
    const float* norm_w = (const float*)d_in[5];
    float* out = (float*)d_out;

    // 7 slots x 33,554,432 B = 234,881,024 B total
    char* w = (char*)d_ws;
    u16* qb   = (u16*)(w);                 // S0: q                 [QKV .. fused_pv]
    u16* kb   = (u16*)(w +  33554432);     // S1: k                 [QKV .. fused_pv]
    u16* kTs  = (u16*)(w +  67108864);     // S2: kTs               [transpose .. KVT]
    u16* hid_bf = (u16*)(w + 100663296);   // S3: hidden bf16       [cast .. QKV]
    u16* vT   = (u16*)(w + 134217728);     // S4: vT (via QKV)      [QKV .. fused_pv]
    u16* gate = (u16*)(w + 167772160);     // S5: gate (via QKV)    [QKV .. rms]
    u16* wqkv_bf  = (u16*)(w + 201326592); // S6: w_qkv bf16 25.17M [cast .. QKV]
    u16* wgate_bf = (u16*)(w + 201326592 + 25165824); // S6 tail 8.39M, contiguous
    // aliases (disjoint lifetimes):
    float* KVT  = (float*)hid_bf;          // S3: KV^T fp32         [KVT .. scan]
    u16*   ST   = kTs;                     // S2: S^T bf16 16.8M    [scan .. fused_pv]
    u16*   wout_bf = kb;                   // S1: w_out bf16        [rms .. OUT]
    u16*   attn = wqkv_bf;                 // S6: attn              [fused_pv .. rms]
    u16*   y    = kTs;                     // S2: y                 [rms .. OUT]

    static bool s_attr = false;
    if (!s_attr) {
        (void)hipFuncSetAttribute((const void*)gemm256<0>,
                                  hipFuncAttributeMaxDynamicSharedMemorySize, 131072);
        (void)hipFuncSetAttribute((const void*)gemm256<1>,
                                  hipFuncAttributeMaxDynamicSharedMemorySize, 131072);
        s_attr = true;
    }

    // fused casts: hidden | w_qkv | w_gate in one launch
    castk3<<<32768, 256, 0, stream>>>(hidden, hid_bf, w_qkv, wqkv_bf, w_gate, wgate_bf);

    // fused qkv+gate: B = [w_qkv ; w_gate] (8192 x 2048 contiguous)
    gemm256<0><<<dim3(1024), dim3(512), 131072, stream>>>(hid_bf, wqkv_bf, qb, vT, gate);
    transpose_k     <<<512,             256, 0, stream>>>(kb, kTs, slope);
    gemm_nt<M_KVT ><<<dim3(1, 1, 512),  256, 0, stream>>>(vT, kTs, KVT, slope, 0, nullptr, nullptr);
    scan_kv         <<<512,             256, 0, stream>>>(KVT, ST, slope);
    fused_pv        <<<dim3(2, 1, 512), 256, 0, stream>>>(qb, kb, ST, vT, attn, slope);
    rmsnorm_gate    <<<8192,            256, 0, stream>>>(attn, gate, norm_w, y, w_out, wout_bf);
    gemm256<1><<<dim3(256), dim3(512), 131072, stream>>>(y, wout_bf, (void*)out, nullptr, nullptr);
}

// Round 18
// 430.589 us; speedup vs baseline: 1.0420x; 1.0256x over previous
//
#include <hip/hip_runtime.h>

// ---------------------------------------------------------------------------
// MiniMax-M1 Lightning Attention forward, MI355X / gfx950.
//   0. castk3: fp32->bf16 for hidden + w_qkv + w_gate in ONE launch
//   1. fused qkv+gate via 256x256 lockstep GEMM (R11 rotated-read schedule)
//      epilogue: q,k,gate row-major; v stored DIRECTLY transposed (vT)
//   2. kvt_fused: KVT_j = vT @ (silu_k*decay)^T -- transpose+decay folded
//      into the B-frag build (raw k staged with slot-XOR swizzle; no kTs
//      buffer, no transpose_k kernel).  Double-buffered (vmcnt(4)/chunk).
//      [R17 bug fix: B-stage LDS offset wv*512 (was wv*1024, corrupted k)]
//   3. scan: S_{j+1} = e^{-256 s} S_j + KV_j ; store S_j^T bf16  [512 WGs]
//   4+5 FUSED (fused_pv): inter (q@S^T, q_decay) + per-32-kv-chunk P in-reg
//      -> LDS round-trip -> acc += P@v.  BOTH loops double-buffered.
//   6. rmsnorm_gate: y = gate * rmsnorm(attn) * norm_w  (+ folds w_out cast)
//   7. out = y @ w_out^T via same 256 GEMM [fp32 -> d_out]
// Workspace: 7 slots x 33,554,432 B = 234,881,024 B peak.
// ---------------------------------------------------------------------------

typedef unsigned short u16;
typedef __bf16 bf16x8 __attribute__((ext_vector_type(8)));
typedef float f32x4 __attribute__((ext_vector_type(4)));

#define SEQ 4096
#define HID 2048

__device__ __forceinline__ u16 f2bf(float f) {
    union { float f; unsigned u; } v; v.f = f;
    unsigned r = v.u + 0x7fffu + ((v.u >> 16) & 1u);   // round-to-nearest-even
    return (u16)(r >> 16);
}
__device__ __forceinline__ float bf2f(u16 u) {
    union { unsigned u; float f; } v; v.u = ((unsigned)u) << 16; return v.f;
}

// async global->LDS, 16B per lane; lds dest must be wave-uniform base (+lane*16)
typedef __attribute__((address_space(1))) unsigned char gas_u8;
typedef __attribute__((address_space(3))) unsigned char las_u8;
__device__ __forceinline__ void gld16(const void* g, void* l) {
    __builtin_amdgcn_global_load_lds((gas_u8*)g, (las_u8*)l, 16, 0, 0);
}

// ---------------------------------------------------------------------------
// castk3: hidden|w_qkv|w_gate fp32->bf16 in one launch (4 elems/thread).
// ---------------------------------------------------------------------------
__global__ __launch_bounds__(256) void castk3(const float* __restrict__ a, u16* __restrict__ ao,
                                              const float* __restrict__ b, u16* __restrict__ bo,
                                              const float* __restrict__ c, u16* __restrict__ co) {
    const int bid = blockIdx.x;
    const float* src; u16* dst; size_t i;
    if (bid < 16384)      { src = a; dst = ao; i = (size_t)bid * 256 + threadIdx.x; }
    else if (bid < 28672) { src = b; dst = bo; i = (size_t)(bid - 16384) * 256 + threadIdx.x; }
    else                  { src = c; dst = co; i = (size_t)(bid - 28672) * 256 + threadIdx.x; }
    const float4 f = *(const float4*)&src[i * 4];
    uint2 o;
    o.x = (unsigned)f2bf(f.x) | ((unsigned)f2bf(f.y) << 16);
    o.y = (unsigned)f2bf(f.z) | ((unsigned)f2bf(f.w) << 16);
    *(uint2*)&dst[i * 4] = o;
}

// ---------------------------------------------------------------------------
// 256x256-tile lockstep pipelined NT GEMM (R11 rotated-read schedule).
// MODE 0: fused QKV+gate epilogue; MODE 1: f32 out.
// ---------------------------------------------------------------------------
template <int MODE>
__global__ __launch_bounds__(512, 2) void gemm256(const u16* __restrict__ A,
                                                  const u16* __restrict__ Bm,
                                                  void* __restrict__ Cv,
                                                  void* __restrict__ aux,
                                                  void* __restrict__ aux2) {
    constexpr int NTN = (MODE == 0) ? 32 : 8;     // tiles along N
    constexpr int NT  = 32;                       // K tiles (2048 / 64)
    extern __shared__ u16 smem[];                 // [2][A 16384 | B 16384]

    // XCD swizzle: 8 XCDs; per-XCD 4-row x 8-col rectangular supertiles
    const int bid = blockIdx.x;
    const int xcd = bid & 7, l = bid >> 3;
    int tm, tn;
    if constexpr (MODE == 0) {       // 32x32 tile grid, 128 WGs per XCD
        tm = xcd * 4 + (l & 3);
        tn = ((l >> 2) & 7) | ((l >> 5) << 3);
    } else {                         // 32x8 grid, 32 WGs per XCD (4x8 rect)
        const int wgid = xcd * 32 + l;
        tm = wgid / NTN; tn = wgid % NTN;
    }

    const int tid  = threadIdx.x;
    const int lane = tid & 63, wv = tid >> 6;
    const int quad = lane >> 4, cl = lane & 15;
    const int wm = (wv & 1) * 128, wn = (wv >> 1) * 64;

    const int srw  = tid >> 3;
    const int colo = ((tid & 7) ^ (srw & 7)) * 8;
    const u16* gA0 = A  + (size_t)(tm * 256 + srw) * HID + colo;
    const u16* gB0 = Bm + (size_t)(tn * 256 + srw) * HID + colo;

    const int x0 = ((quad       ^ (cl & 7)) * 8);
    const int x1 = (((4 + quad) ^ (cl & 7)) * 8);

    f32x4 acc[8][4];
    const f32x4 zero = {0.f, 0.f, 0.f, 0.f};
    #pragma unroll
    for (int a = 0; a < 8; a++)
        #pragma unroll
        for (int b = 0; b < 4; b++) acc[a][b] = zero;

    bf16x8 af[8], b0[4], b1[4];

    auto STG = [&](int kt, int mat, int hh) {   // stage one 128x64 half-tile
        const u16* g = (mat ? gB0 : gA0) + (size_t)(hh * 128) * HID + kt * 64;
        u16* lp = smem + (kt & 1) * 32768 + mat * 16384 + hh * 8192 + wv * 512;
        gld16(g, lp);
        gld16(g + (size_t)64 * HID, lp + 4096);
    };
    auto LDA = [&](int qm, int ab) {
        #pragma unroll
        for (int mi = 0; mi < 4; mi++) {
            const int rr = (wm + qm * 64 + mi * 16 + cl) * 64 + ab;
            af[mi * 2 + 0] = *(const bf16x8*)&smem[rr + x0];
            af[mi * 2 + 1] = *(const bf16x8*)&smem[rr + x1];
        }
    };
    auto LDB = [&](bf16x8* d, int qn, int bb2) {
        #pragma unroll
        for (int ni = 0; ni < 2; ni++) {
            const int rr = (wn + qn * 32 + ni * 16 + cl) * 64 + bb2;
            d[ni * 2 + 0] = *(const bf16x8*)&smem[rr + x0];
            d[ni * 2 + 1] = *(const bf16x8*)&smem[rr + x1];
        }
    };
    auto MM = [&](int qm, int qn, const bf16x8* bv) {
        #pragma unroll
        for (int mi = 0; mi < 4; mi++)
            #pragma unroll
            for (int ni = 0; ni < 2; ni++) {
                f32x4 c = acc[qm * 4 + mi][qn * 2 + ni];
                c = __builtin_amdgcn_mfma_f32_16x16x32_bf16(af[mi * 2 + 0], bv[ni * 2 + 0], c, 0, 0, 0);
                c = __builtin_amdgcn_mfma_f32_16x16x32_bf16(af[mi * 2 + 1], bv[ni * 2 + 1], c, 0, 0, 0);
                acc[qm * 4 + mi][qn * 2 + ni] = c;
            }
    };

    // prologue: issue stream per tile = B.lo, B.hi, A.lo, A.hi
    STG(0, 1, 0); STG(0, 1, 1); STG(0, 0, 0); STG(0, 0, 1);
    STG(1, 1, 0); STG(1, 1, 1); STG(1, 0, 0);
    asm volatile("s_waitcnt vmcnt(6)" ::: "memory");   // tile 0 resident
    __builtin_amdgcn_s_barrier();
    LDA(0, 0); LDB(b0, 0, 16384);      // ph0 operands (drain at ph0 lgkm(0))

    #pragma unroll 2
    for (int t = 0; t < NT; ++t) {
        const int ab  = (t & 1) * 32768;
        const int bb2 = ab + 16384;
        const int nab = ((t + 1) & 1) * 32768;
        // phase 0: MM(0,0)=A0*b0 (reads from prev ph3/prologue); read b1
        if (t + 1 < NT) STG(t + 1, 0, 1);
        __builtin_amdgcn_s_barrier();
        asm volatile("s_waitcnt lgkmcnt(0)" ::: "memory");
        __builtin_amdgcn_s_setprio(1); MM(0, 0, b0); __builtin_amdgcn_s_setprio(0);
        LDB(b1, 1, bb2);
        __builtin_amdgcn_s_barrier();
        // phase 1: MM(0,1)=A0*b1; read A1
        if (t + 2 < NT) STG(t + 2, 1, 0);
        __builtin_amdgcn_s_barrier();
        asm volatile("s_waitcnt lgkmcnt(0)" ::: "memory");
        __builtin_amdgcn_s_setprio(1); MM(0, 1, b1); __builtin_amdgcn_s_setprio(0);
        LDA(1, ab);
        __builtin_amdgcn_s_barrier();
        // phase 2: MM(1,1)=A1*b1
        if (t + 2 < NT) STG(t + 2, 1, 1);
        __builtin_amdgcn_s_barrier();
        asm volatile("s_waitcnt lgkmcnt(0)" ::: "memory");
        __builtin_amdgcn_s_setprio(1); MM(1, 1, b1); __builtin_amdgcn_s_setprio(0);
        __builtin_amdgcn_s_barrier();
        // phase 3: MM(1,0)=A1*b0; boundary vmcnt(6); post-MFMA next A0,b0
        if (t + 2 < NT) {
            STG(t + 2, 0, 0);
            asm volatile("s_waitcnt vmcnt(6)" ::: "memory");
        } else {
            asm volatile("s_waitcnt vmcnt(0)" ::: "memory");
        }
        __builtin_amdgcn_s_barrier();
        __builtin_amdgcn_s_setprio(1); MM(1, 0, b0); __builtin_amdgcn_s_setprio(0);
        if (t + 1 < NT) { LDA(0, nab); LDB(b0, 0, nab + 16384); }
        __builtin_amdgcn_s_barrier();
    }

    // epilogue
    if constexpr (MODE == 0) {
        const int grp = tn * 2 + (wn >> 7);
        const int which = grp >> 4, hd = grp & 15;
        const int n64 = wn & 64;
        if (which == 2) {
            const size_t bz = (size_t)((tm >> 4) * 256 + hd * 16 + (tm & 15));
            u16* tdst = (u16*)aux + bz * 32768;
            #pragma unroll
            for (int a = 0; a < 8; a++) {
                const int mm = wm + (a >> 2) * 64 + (a & 3) * 16 + quad * 4;
                #pragma unroll
                for (int b = 0; b < 4; b++) {
                    const int d = n64 + (b >> 1) * 32 + (b & 1) * 16 + cl;
                    u16 p[4];
                    #pragma unroll
                    for (int r = 0; r < 4; r++) {
                        const float x = acc[a][b][r];
                        p[r] = f2bf(x / (1.f + __expf(-x)));
                    }
                    uint2 pk;
                    pk.x = (unsigned)p[0] | ((unsigned)p[1] << 16);
                    pk.y = (unsigned)p[2] | ((unsigned)p[3] << 16);
                    *(uint2*)&tdst[(size_t)d * 256 + mm] = pk;
                }
            }
            return;
        }
        u16* dst = (which == 0) ? (u16*)Cv
                 : (which == 1) ? (u16*)Cv + (size_t)16777216   // k slot (S1)
                                : (u16*)aux2;                   // gate slot
        #pragma unroll
        for (int a = 0; a < 8; a++)
            #pragma unroll
            for (int b = 0; b < 4; b++)
                #pragma unroll
                for (int r = 0; r < 4; r++) {
                    const int m = tm * 256 + wm + (a >> 2) * 64 + (a & 3) * 16 + quad * 4 + r;
                    const int col = hd * 128 + n64 + (b >> 1) * 32 + (b & 1) * 16 + cl;
                    const float x = acc[a][b][r];
                    const float v = (which == 3) ? 1.f / (1.f + __expf(-x))
                                                 : x / (1.f + __expf(-x));
                    dst[(size_t)m * HID + col] = f2bf(v);
                }
        return;
    } else {
        float* C = (float*)Cv;
        #pragma unroll
        for (int a = 0; a < 8; a++)
            #pragma unroll
            for (int b = 0; b < 4; b++)
                #pragma unroll
                for (int r = 0; r < 4; r++) {
                    const int m = tm * 256 + wm + (a >> 2) * 64 + (a & 3) * 16 + quad * 4 + r;
                    const int n = tn * 256 + wn + (b >> 1) * 32 + (b & 1) * 16 + cl;
                    C[(size_t)m * HID + n] = acc[a][b][r];
                }
    }
}

// ---------------------------------------------------------------------------
// kvt_fused: KVT_j[e][d] = sum_m vT[e][m] * silu_k[m][d] * exp(-s*(255-m)).
// A = vT[bz] ([128 e][256 m], staged [128][32] chunks as before).
// B = raw k rows staged [32 m][128 d] with slot-XOR swizzle (phys 8-u16 slot
// p at row m holds logical slot p^(m&15); source pre-swizzled).  B-frags are
// built by 32 scalar swizzled ds_reads + decay multiply at frag build (decay
// chain: 1 expf + 7 muls by e^s, shared across the 4 ni frags).
// Double-buffered: 4 gld16/chunk, vmcnt(4).  Replaces transpose_k + old KVT.
// ---------------------------------------------------------------------------
__global__ __launch_bounds__(256) void kvt_fused(const u16* __restrict__ vT,
                                                 const u16* __restrict__ kb,
                                                 float* __restrict__ KVT,
                                                 const float* __restrict__ slope) {
    __shared__ u16 smem[16384];           // A dbuf 2x4096 | Braw dbuf 2x4096

    const int tid = threadIdx.x;
    const int bz  = blockIdx.x;
    const int bb = bz >> 8, hh = (bz >> 4) & 15, jb = bz & 15;
    const float s_ = slope[hh];
    const float es = __expf(s_);
    const size_t rowbase = (size_t)(bb * SEQ + jb * 256);

    const int lane = tid & 63, wv = tid >> 6;
    const int wm = (wv & 1) * 64, wn = (wv >> 1) * 64;
    const int quad = lane >> 4, cl = lane & 15;
    const int lr = lane >> 2;
    const int lc = (lane & 3) * 8;
    const int ko = quad * 8;

    f32x4 acc[4][4];
    const f32x4 zero = {0.f, 0.f, 0.f, 0.f};
    #pragma unroll
    for (int mi = 0; mi < 4; mi++)
        #pragma unroll
        for (int ni = 0; ni < 4; ni++) acc[mi][ni] = zero;

    // A: vT rows (e), contraction m; per-wave 32 rows, [row][32 m] layout
    const u16* gA = vT + (size_t)bz * 32768 + (size_t)(wv * 32 + lr) * 256 + lc;
    // B: raw k rows, source pre-swizzled so linear LDS holds slot-XOR layout
    const u16* gK = kb + (rowbase + (tid >> 4)) * HID + hh * 128
                       + (((tid & 15) ^ (tid >> 4)) * 8);

    auto stage = [&](int c, int buf) {    // 4 gld16 per chunk
        u16* lA = smem + buf * 4096 + wv * 1024;
        gld16(gA + c * 32,                    lA);
        gld16(gA + c * 32 + (size_t)16 * 256, lA + 512);
        u16* lB = smem + 8192 + buf * 4096 + wv * 512 + lane * 8;   // FIX: wv*512
        gld16(gK + (size_t)(c * 32) * HID,      lB);
        gld16(gK + (size_t)(c * 32 + 16) * HID, lB + 2048);
    };

    stage(0, 0);
    for (int c = 0; c < 8; ++c) {
        const int cb = c & 1;
        if (c + 1 < 8) {
            stage(c + 1, cb ^ 1);
            asm volatile("s_waitcnt vmcnt(4)" ::: "memory");   // chunk c landed
        } else {
            asm volatile("s_waitcnt vmcnt(0)" ::: "memory");
        }
        __builtin_amdgcn_s_barrier();
        const u16* As   = smem + cb * 4096;
        const u16* braw = smem + 8192 + cb * 4096;
        // decay factors for this thread's m-slice (shared across ni)
        const int kv0 = c * 32;
        const float dec0 = __expf(-s_ * (float)(255 - (kv0 + ko)));
        bf16x8 af[4], bfv[4];
        #pragma unroll
        for (int mi = 0; mi < 4; mi++)
            af[mi] = *(const bf16x8*)&As[(wm + mi * 16 + cl) * 32 + ko];
        #pragma unroll
        for (int ni = 0; ni < 4; ni++) {
            const int d   = wn + ni * 16 + cl;
            const int dhi = d >> 3, dlo = d & 7;
            float dec = dec0;
            union { u16 u[8]; bf16x8 v; } cvt;
            #pragma unroll
            for (int j = 0; j < 8; j++) {
                const int ml = ko + j;
                const u16 raw = braw[ml * 128 + ((dhi ^ (ml & 15)) * 8) + dlo];
                cvt.u[j] = f2bf(bf2f(raw) * dec);
                dec *= es;
            }
            bfv[ni] = cvt.v;
        }
        #pragma unroll
        for (int mi = 0; mi < 4; mi++)
            #pragma unroll
            for (int ni = 0; ni < 4; ni++)
                acc[mi][ni] = __builtin_amdgcn_mfma_f32_16x16x32_bf16(af[mi], bfv[ni], acc[mi][ni], 0, 0, 0);
        __builtin_amdgcn_s_barrier();   // WAR: all waves' reads of buf cb done
    }

    #pragma unroll
    for (int mi = 0; mi < 4; mi++)
        #pragma unroll
        for (int ni = 0; ni < 4; ni++)
            #pragma unroll
            for (int r = 0; r < 4; r++) {
                const int m = wm + mi * 16 + quad * 4 + r;
                const int n = wn + ni * 16 + cl;
                KVT[(size_t)bz * 16384 + m * 128 + n] = acc[mi][ni][r];
            }
}

// ---------------------------------------------------------------------------
// FUSED P+INTRA: grid (2,1,512) = (row-half tm, -, bz); 256 thr = 4 waves 2x2.
// BOTH loops double-buffered with counted vmcnt.
// ---------------------------------------------------------------------------
__global__ __launch_bounds__(256) void fused_pv(const u16* __restrict__ qb,
                                                const u16* __restrict__ kb,
                                                const u16* __restrict__ ST,
                                                const u16* __restrict__ vT,
                                                u16* __restrict__ attn,
                                                const float* __restrict__ slope) {
    __shared__ u16 smem[36864];   // q 16384 | k 2x4096 | P 4096 | Bs 2x4096
    u16* q_lds = smem;            // [4][128][32]
    u16* k_lds = smem + 16384;    // [2][32][128] row-XOR swizzled
    u16* P_lds = smem + 24576;    // [128][32]
    u16* Bs    = smem + 28672;    // [2][128][32]  (ST chunks / v chunks)

    const int tm = blockIdx.x;           // row half within the 256-block
    const int bz = blockIdx.z;
    const int bb = bz >> 8, hh = (bz >> 4) & 15, jb = bz & 15;
    const float s_ = slope[hh];

    const int tid  = threadIdx.x;
    const int lane = tid & 63, wv = tid >> 6;
    const int quad = lane >> 4, cl = lane & 15;
    const int wm = (wv & 1) * 64, wn = (wv >> 1) * 64;
    const int lr = lane >> 2, lc = (lane & 3) * 8;
    const int pcb = (wv >> 1) * 16;      // P kv-col base for this wave

    const size_t rowbase = (size_t)(bb * SEQ + jb * 256);

    // ---- stage q: 4 ks x 2 gld16 (gemm_nt A-tile pattern, linear) ----
    const u16* gq = qb + (rowbase + tm * 128 + wv * 32 + lr) * HID + hh * 128 + lc;
    u16* lq = q_lds + wv * 1024 + lr * 32 + lc;
    #pragma unroll
    for (int ks = 0; ks < 4; ks++) {
        gld16(gq + ks * 32,                 lq + ks * 4096);
        gld16(gq + ks * 32 + 16 * HID,      lq + ks * 4096 + 512);
    }

    f32x4 acc[4][4];
    const f32x4 zero = {0.f, 0.f, 0.f, 0.f};
    #pragma unroll
    for (int mi = 0; mi < 4; mi++)
        #pragma unroll
        for (int ni = 0; ni < 4; ni++) acc[mi][ni] = zero;

    // ---- inter: acc = q @ S^T  (double-buffered ST chunks) ----
    const u16* gS = ST + (size_t)bz * 16384 + (size_t)(wv * 32 + lr) * 128 + lc;
    auto stage_st = [&](int ks, int buf) {       // 2 gld16
        u16* lB = Bs + buf * 4096 + wv * 1024 + lr * 32 + lc;
        gld16(gS + ks * 32,            lB);
        gld16(gS + ks * 32 + 16 * 128, lB + 512);
    };
    stage_st(0, 0);
    #pragma unroll
    for (int ks = 0; ks < 4; ks++) {
        const int sb = ks & 1;
        if (ks + 1 < 4) {
            stage_st(ks + 1, sb ^ 1);
            asm volatile("s_waitcnt vmcnt(2)" ::: "memory");   // q + chunk ks landed
        } else {
            asm volatile("s_waitcnt vmcnt(0)" ::: "memory");
        }
        __builtin_amdgcn_s_barrier();
        bf16x8 af[4], bfv[4];
        #pragma unroll
        for (int mi = 0; mi < 4; mi++)
            af[mi] = *(const bf16x8*)&q_lds[ks * 4096 + (wm + mi * 16 + cl) * 32 + quad * 8];
        #pragma unroll
        for (int ni = 0; ni < 4; ni++)
            bfv[ni] = *(const bf16x8*)&Bs[sb * 4096 + (wn + ni * 16 + cl) * 32 + quad * 8];
        #pragma unroll
        for (int mi = 0; mi < 4; mi++)
            #pragma unroll
            for (int ni = 0; ni < 4; ni++)
                acc[mi][ni] = __builtin_amdgcn_mfma_f32_16x16x32_bf16(af[mi], bfv[ni], acc[mi][ni], 0, 0, 0);
        __builtin_amdgcn_s_barrier();   // WAR: buf sb reads done before restage
    }
    // q_decay scale
    #pragma unroll
    for (int mi = 0; mi < 4; mi++)
        #pragma unroll
        for (int r = 0; r < 4; r++) {
            const int m = tm * 128 + wm + mi * 16 + quad * 4 + r;
            const float qd = __expf(-s_ * (float)(m + 1));
            #pragma unroll
            for (int ni = 0; ni < 4; ni++) acc[mi][ni][r] *= qd;
        }

    // ---- intra: double-buffered chunk pipeline ----
    const int kmax = (tm == 0) ? 128 : 256;
    const int nc   = kmax >> 5;
    const u16* gV = vT + (size_t)bz * 32768 + (size_t)(wv * 32 + lr) * 256 + lc;
    const int krow = tid >> 4;                       // 0..15 per issue
    const int kcol = (((tid & 15) ^ (krow & 7)) * 8);
    const int kvr = pcb + cl;                        // lane's P kv-row (B-frag)

    auto stage_chunk = [&](int c, int buf) {         // 4 gld16
        u16* lk = k_lds + buf * 4096 + wv * 512 + lane * 8;
        u16* lv = Bs + buf * 4096 + wv * 1024 + lr * 32 + lc;
        const int kv0 = c * 32;
        gld16(kb + (rowbase + kv0 +      krow) * HID + hh * 128 + kcol, lk);
        gld16(kb + (rowbase + kv0 + 16 + krow) * HID + hh * 128 + kcol, lk + 2048);
        gld16(gV + kv0,            lv);
        gld16(gV + kv0 + 16 * 256, lv + 512);
    };

    stage_chunk(0, 0);
    for (int c = 0; c < nc; ++c) {
        const int cb = c & 1;
        if (c + 1 < nc) {
            stage_chunk(c + 1, cb ^ 1);
            asm volatile("s_waitcnt vmcnt(4)" ::: "memory");   // chunk c landed
        } else {
            asm volatile("s_waitcnt vmcnt(0)" ::: "memory");
        }
        __builtin_amdgcn_s_barrier();
        // P-GEMM: C[m(64 rows @wm)][kv(16 cols @pcb)] over d=128
        f32x4 acc2[4];
        #pragma unroll
        for (int mi = 0; mi < 4; mi++) acc2[mi] = zero;
        #pragma unroll
        for (int ds = 0; ds < 4; ds++) {
            bf16x8 bk = *(const bf16x8*)&k_lds[cb * 4096 + kvr * 128 + (((ds * 4 + quad) ^ (kvr & 7)) * 8)];
            #pragma unroll
            for (int mi = 0; mi < 4; mi++) {
                bf16x8 aq = *(const bf16x8*)&q_lds[ds * 4096 + (wm + mi * 16 + cl) * 32 + quad * 8];
                acc2[mi] = __builtin_amdgcn_mfma_f32_16x16x32_bf16(aq, bk, acc2[mi], 0, 0, 0);
            }
        }
        // mask + decay + bf16 -> P_lds[128][32]
        const int kv0 = c * 32;
        #pragma unroll
        for (int mi = 0; mi < 4; mi++)
            #pragma unroll
            for (int r = 0; r < 4; r++) {
                const int row = wm + mi * 16 + quad * 4 + r;
                const int mb  = tm * 128 + row;
                const int kv  = kv0 + pcb + cl;
                const int d   = mb - kv;
                const float x = acc2[mi][r];
                P_lds[row * 32 + pcb + cl] = f2bf(d >= 0 ? x * __expf(-s_ * (float)d) : 0.f);
            }
        asm volatile("s_waitcnt lgkmcnt(0)" ::: "memory");
        __builtin_amdgcn_s_barrier();
        // PV: acc += P @ vT^T
        bf16x8 afp[4], bfv[4];
        #pragma unroll
        for (int mi = 0; mi < 4; mi++)
            afp[mi] = *(const bf16x8*)&P_lds[(wm + mi * 16 + cl) * 32 + quad * 8];
        #pragma unroll
        for (int ni = 0; ni < 4; ni++)
            bfv[ni] = *(const bf16x8*)&Bs[cb * 4096 + (wn + ni * 16 + cl) * 32 + quad * 8];
        #pragma unroll
        for (int mi = 0; mi < 4; mi++)
            #pragma unroll
            for (int ni = 0; ni < 4; ni++)
                acc[mi][ni] = __builtin_amdgcn_mfma_f32_16x16x32_bf16(afp[mi], bfv[ni], acc[mi][ni], 0, 0, 0);
        __builtin_amdgcn_s_barrier();   // WAR: all waves' buf/P reads done
    }

    // ---- epilogue: attn write (verbatim M_INTRA) ----
    #pragma unroll
    for (int mi = 0; mi < 4; mi++)
        #pragma unroll
        for (int ni = 0; ni < 4; ni++)
            #pragma unroll
            for (int r = 0; r < 4; r++) {
                const int m = tm * 128 + wm + mi * 16 + quad * 4 + r;
                const int n = wn + ni * 16 + cl;
                attn[(rowbase + m) * HID + hh * 128 + n] = f2bf(acc[mi][ni][r]);
            }
}

// ---------------------------------------------------------------------------
// S_0 = 0; write S_j^T (bf16); S_{j+1} = e^{-256 s} S_j + KV_j
// ---------------------------------------------------------------------------
__global__ __launch_bounds__(256) void scan_kv(const float* __restrict__ KVT,
                                               u16* __restrict__ ST,
                                               const float* __restrict__ slope) {
    const int bh = blockIdx.x >> 4, ch = blockIdx.x & 15;
    const int off = ch * 1024 + threadIdx.x * 4;
    const float bd = __expf(-256.f * slope[bh & 15]);
    float4 st = {0.f, 0.f, 0.f, 0.f};
    for (int j = 0; j < 16; j++) {
        const size_t base = ((size_t)(bh * 16 + j)) * 16384 + off;
        uint2 o;
        o.x = (unsigned)f2bf(st.x) | ((unsigned)f2bf(st.y) << 16);
        o.y = (unsigned)f2bf(st.z) | ((unsigned)f2bf(st.w) << 16);
        *(uint2*)&ST[base] = o;
        const float4 kv = *(const float4*)&KVT[base];
        st.x = bd * st.x + kv.x;
        st.y = bd * st.y + kv.y;
        st.z = bd * st.z + kv.z;
        st.w = bd * st.w + kv.w;
    }
}

// ---------------------------------------------------------------------------
// y = gate * (attn * rsqrt(mean(attn^2)+eps)) * norm_w   (one WG per row)
// Also folds the w_out fp32->bf16 cast (2 elems/thread; 8192x512 = 2048^2).
// ---------------------------------------------------------------------------
__global__ __launch_bounds__(256) void rmsnorm_gate(const u16* __restrict__ attn,
                                                    const u16* __restrict__ gate,
                                                    const float* __restrict__ nw,
                                                    u16* __restrict__ y,
                                                    const float* __restrict__ wout,
                                                    u16* __restrict__ wout_bf) {
    const int r = blockIdx.x, tid = threadIdx.x;

    // folded w_out cast: block r covers elements [r*512, r*512+512)
    {
        const size_t wi = (size_t)r * 512 + tid * 2;
        const float2 wf = *(const float2*)&wout[wi];
        *(unsigned*)&wout_bf[wi] = (unsigned)f2bf(wf.x) | ((unsigned)f2bf(wf.y) << 16);
    }

    const size_t base = (size_t)r * HID + tid * 8;
    const uint4 a = *(const uint4*)&attn[base];
    float x[8];
    x[0] = bf2f(a.x & 0xffff); x[1] = bf2f(a.x >> 16);
    x[2] = bf2f(a.y & 0xffff); x[3] = bf2f(a.y >> 16);
    x[4] = bf2f(a.z & 0xffff); x[5] = bf2f(a.z >> 16);
    x[6] = bf2f(a.w & 0xffff); x[7] = bf2f(a.w >> 16);
    float s = 0.f;
    #pragma unroll
    for (int i = 0; i < 8; i++) s += x[i] * x[i];
    #pragma unroll
    for (int off = 32; off > 0; off >>= 1) s += __shfl_down(s, off);
    __shared__ float red[4];
    if ((tid & 63) == 0) red[tid >> 6] = s;
    __syncthreads();
    const float tot = red[0] + red[1] + red[2] + red[3];
    const float sc = rsqrtf(tot * (1.f / 2048.f) + 1e-6f);
    const uint4 g = *(const uint4*)&gate[base];
    float gv[8];
    gv[0] = bf2f(g.x & 0xffff); gv[1] = bf2f(g.x >> 16);
    gv[2] = bf2f(g.y & 0xffff); gv[3] = bf2f(g.y >> 16);
    gv[4] = bf2f(g.z & 0xffff); gv[5] = bf2f(g.z >> 16);
    gv[6] = bf2f(g.w & 0xffff); gv[7] = bf2f(g.w >> 16);
    const float4 w0 = *(const float4*)&nw[tid * 8];
    const float4 w1 = *(const float4*)&nw[tid * 8 + 4];
    const float wv[8] = {w0.x, w0.y, w0.z, w0.w, w1.x, w1.y, w1.z, w1.w};
    u16 o[8];
    #pragma unroll
    for (int i = 0; i < 8; i++) o[i] = f2bf(gv[i] * x[i] * sc * wv[i]);
    uint4 ov;
    ov.x = (unsigned)o[0] | ((unsigned)o[1] << 16);
    ov.y = (unsigned)o[2] | ((unsigned)o[3] << 16);
    ov.z = (unsigned)o[4] | ((unsigned)o[5] << 16);
    ov.w = (unsigned)o[6] | ((unsigned)o[7] << 16);
    *(uint4*)&y[base] = ov;
}

// ---------------------------------------------------------------------------
extern "C" void kernel_launch(void* const* d_in, const int* in_sizes, int n_in,
                              void* d_out, int out_size, void* d_ws, size_t ws_size,
                              hipStream_t stream) {
    const float* hidden = (const float*)d_in[0];
    const float* slope  = (const float*)d_in[1];
    const float* w_qkv  = (const float*)d_in[2];
    const float* w_gate = (const float*)d_in[3];
    const float* w_out  = (const float*)d_in[4];
    const float* norm_w = (const float*)d_in[5];
    float* out = (float*)d_out;

    // 7 slots x 33,554,432 B = 234,881,024 B total
    char* w = (char*)d_ws;
    u16* qb   = (u16*)(w);                 // S0: q                 [QKV .. fused_pv]
    u16* kb   = (u16*)(w +  33554432);     // S1: k                 [QKV .. fused_pv]
    u16* kTs  = (u16*)(w +  67108864);     // S2: (ST / y slot)
    u16* hid_bf = (u16*)(w + 100663296);   // S3: hidden bf16       [cast .. QKV]
    u16* vT   = (u16*)(w + 134217728);     // S4: vT (via QKV)      [QKV .. fused_pv]
    u16* gate = (u16*)(w + 167772160);     // S5: gate (via QKV)    [QKV .. rms]
    u16* wqkv_bf  = (u16*)(w + 201326592); // S6: w_qkv bf16 25.17M [cast .. QKV]
    u16* wgate_bf = (u16*)(w + 201326592 + 25165824); // S6 tail 8.39M, contiguous
    // aliases (disjoint lifetimes):
    float* KVT  = (float*)hid_bf;          // S3: KV^T fp32         [kvt .. scan]
    u16*   ST   = kTs;                     // S2: S^T bf16 16.8M    [scan .. fused_pv]
    u16*   wout_bf = kb;                   // S1: w_out bf16        [rms .. OUT]
    u16*   attn = wqkv_bf;                 // S6: attn              [fused_pv .. rms]
    u16*   y    = kTs;                     // S2: y                 [rms .. OUT]

    static bool s_attr = false;
    if (!s_attr) {
        (void)hipFuncSetAttribute((const void*)gemm256<0>,
                                  hipFuncAttributeMaxDynamicSharedMemorySize, 131072);
        (void)hipFuncSetAttribute((const void*)gemm256<1>,
                                  hipFuncAttributeMaxDynamicSharedMemorySize, 131072);
        s_attr = true;
    }

    // fused casts: hidden | w_qkv | w_gate in one launch
    castk3<<<32768, 256, 0, stream>>>(hidden, hid_bf, w_qkv, wqkv_bf, w_gate, wgate_bf);

    // fused qkv+gate: B = [w_qkv ; w_gate] (8192 x 2048 contiguous)
    gemm256<0><<<dim3(1024), dim3(512), 131072, stream>>>(hid_bf, wqkv_bf, qb, vT, gate);
    kvt_fused       <<<512,             256, 0, stream>>>(vT, kb, KVT, slope);
    scan_kv         <<<512,             256, 0, stream>>>(KVT, ST, slope);
    fused_pv        <<<dim3(2, 1, 512), 256, 0, stream>>>(qb, kb, ST, vT, attn, slope);
    rmsnorm_gate    <<<8192,            256, 0, stream>>>(attn, gate, norm_w, y, w_out, wout_bf);
    gemm256<1><<<dim3(256), dim3(512), 131072, stream>>>(y, wout_bf, (void*)out, nullptr, nullptr);
}

// Round 19
// 430.168 us; speedup vs baseline: 1.0430x; 1.0010x over previous
//
#include <hip/hip_runtime.h>

// ---------------------------------------------------------------------------
// MiniMax-M1 Lightning Attention forward, MI355X / gfx950.
//   0. castk3: fp32->bf16 for hidden + w_qkv + w_gate in ONE launch
//   1. fused qkv+gate via 256x256 lockstep GEMM (R11 rotated-read schedule)
//      epilogue: q,k,gate row-major; v stored DIRECTLY transposed (vT)
//   2. kvt_fused: KVT_j = vT @ (silu_k*decay)^T -- transpose+decay folded
//      into the B-frag build.  Double-buffered (vmcnt(4)/chunk).
//   3. scan: S_{j+1} = e^{-256 s} S_j + KV_j ; ALL 16 KV loads prefetched
//      to registers (independent) so only the accumulate is serial.
//   4+5 FUSED (fused_pv): inter (q@S^T, q_decay) + per-32-kv-chunk P in-reg
//      -> LDS round-trip -> acc += P@v.  BOTH loops double-buffered.
//   6. rmsnorm_gate: y = gate * rmsnorm(attn) * norm_w  (+ folds w_out cast)
//   7. out = y @ w_out^T via same 256 GEMM [fp32 -> d_out]
// Workspace: 7 slots x 33,554,432 B = 234,881,024 B peak.
// ---------------------------------------------------------------------------

typedef unsigned short u16;
typedef __bf16 bf16x8 __attribute__((ext_vector_type(8)));
typedef float f32x4 __attribute__((ext_vector_type(4)));

#define SEQ 4096
#define HID 2048

__device__ __forceinline__ u16 f2bf(float f) {
    union { float f; unsigned u; } v; v.f = f;
    unsigned r = v.u + 0x7fffu + ((v.u >> 16) & 1u);   // round-to-nearest-even
    return (u16)(r >> 16);
}
__device__ __forceinline__ float bf2f(u16 u) {
    union { unsigned u; float f; } v; v.u = ((unsigned)u) << 16; return v.f;
}

// async global->LDS, 16B per lane; lds dest must be wave-uniform base (+lane*16)
typedef __attribute__((address_space(1))) unsigned char gas_u8;
typedef __attribute__((address_space(3))) unsigned char las_u8;
__device__ __forceinline__ void gld16(const void* g, void* l) {
    __builtin_amdgcn_global_load_lds((gas_u8*)g, (las_u8*)l, 16, 0, 0);
}

// ---------------------------------------------------------------------------
// castk3: hidden|w_qkv|w_gate fp32->bf16 in one launch (4 elems/thread).
// ---------------------------------------------------------------------------
__global__ __launch_bounds__(256) void castk3(const float* __restrict__ a, u16* __restrict__ ao,
                                              const float* __restrict__ b, u16* __restrict__ bo,
                                              const float* __restrict__ c, u16* __restrict__ co) {
    const int bid = blockIdx.x;
    const float* src; u16* dst; size_t i;
    if (bid < 16384)      { src = a; dst = ao; i = (size_t)bid * 256 + threadIdx.x; }
    else if (bid < 28672) { src = b; dst = bo; i = (size_t)(bid - 16384) * 256 + threadIdx.x; }
    else                  { src = c; dst = co; i = (size_t)(bid - 28672) * 256 + threadIdx.x; }
    const float4 f = *(const float4*)&src[i * 4];
    uint2 o;
    o.x = (unsigned)f2bf(f.x) | ((unsigned)f2bf(f.y) << 16);
    o.y = (unsigned)f2bf(f.z) | ((unsigned)f2bf(f.w) << 16);
    *(uint2*)&dst[i * 4] = o;
}

// ---------------------------------------------------------------------------
// 256x256-tile lockstep pipelined NT GEMM (R11 rotated-read schedule).
// MODE 0: fused QKV+gate epilogue; MODE 1: f32 out.
// ---------------------------------------------------------------------------
template <int MODE>
__global__ __launch_bounds__(512, 2) void gemm256(const u16* __restrict__ A,
                                                  const u16* __restrict__ Bm,
                                                  void* __restrict__ Cv,
                                                  void* __restrict__ aux,
                                                  void* __restrict__ aux2) {
    constexpr int NTN = (MODE == 0) ? 32 : 8;     // tiles along N
    constexpr int NT  = 32;                       // K tiles (2048 / 64)
    extern __shared__ u16 smem[];                 // [2][A 16384 | B 16384]

    // XCD swizzle: 8 XCDs; per-XCD 4-row x 8-col rectangular supertiles
    const int bid = blockIdx.x;
    const int xcd = bid & 7, l = bid >> 3;
    int tm, tn;
    if constexpr (MODE == 0) {       // 32x32 tile grid, 128 WGs per XCD
        tm = xcd * 4 + (l & 3);
        tn = ((l >> 2) & 7) | ((l >> 5) << 3);
    } else {                         // 32x8 grid, 32 WGs per XCD (4x8 rect)
        const int wgid = xcd * 32 + l;
        tm = wgid / NTN; tn = wgid % NTN;
    }

    const int tid  = threadIdx.x;
    const int lane = tid & 63, wv = tid >> 6;
    const int quad = lane >> 4, cl = lane & 15;
    const int wm = (wv & 1) * 128, wn = (wv >> 1) * 64;

    const int srw  = tid >> 3;
    const int colo = ((tid & 7) ^ (srw & 7)) * 8;
    const u16* gA0 = A  + (size_t)(tm * 256 + srw) * HID + colo;
    const u16* gB0 = Bm + (size_t)(tn * 256 + srw) * HID + colo;

    const int x0 = ((quad       ^ (cl & 7)) * 8);
    const int x1 = (((4 + quad) ^ (cl & 7)) * 8);

    f32x4 acc[8][4];
    const f32x4 zero = {0.f, 0.f, 0.f, 0.f};
    #pragma unroll
    for (int a = 0; a < 8; a++)
        #pragma unroll
        for (int b = 0; b < 4; b++) acc[a][b] = zero;

    bf16x8 af[8], b0[4], b1[4];

    auto STG = [&](int kt, int mat, int hh) {   // stage one 128x64 half-tile
        const u16* g = (mat ? gB0 : gA0) + (size_t)(hh * 128) * HID + kt * 64;
        u16* lp = smem + (kt & 1) * 32768 + mat * 16384 + hh * 8192 + wv * 512;
        gld16(g, lp);
        gld16(g + (size_t)64 * HID, lp + 4096);
    };
    auto LDA = [&](int qm, int ab) {
        #pragma unroll
        for (int mi = 0; mi < 4; mi++) {
            const int rr = (wm + qm * 64 + mi * 16 + cl) * 64 + ab;
            af[mi * 2 + 0] = *(const bf16x8*)&smem[rr + x0];
            af[mi * 2 + 1] = *(const bf16x8*)&smem[rr + x1];
        }
    };
    auto LDB = [&](bf16x8* d, int qn, int bb2) {
        #pragma unroll
        for (int ni = 0; ni < 2; ni++) {
            const int rr = (wn + qn * 32 + ni * 16 + cl) * 64 + bb2;
            d[ni * 2 + 0] = *(const bf16x8*)&smem[rr + x0];
            d[ni * 2 + 1] = *(const bf16x8*)&smem[rr + x1];
        }
    };
    auto MM = [&](int qm, int qn, const bf16x8* bv) {
        #pragma unroll
        for (int mi = 0; mi < 4; mi++)
            #pragma unroll
            for (int ni = 0; ni < 2; ni++) {
                f32x4 c = acc[qm * 4 + mi][qn * 2 + ni];
                c = __builtin_amdgcn_mfma_f32_16x16x32_bf16(af[mi * 2 + 0], bv[ni * 2 + 0], c, 0, 0, 0);
                c = __builtin_amdgcn_mfma_f32_16x16x32_bf16(af[mi * 2 + 1], bv[ni * 2 + 1], c, 0, 0, 0);
                acc[qm * 4 + mi][qn * 2 + ni] = c;
            }
    };

    // prologue: issue stream per tile = B.lo, B.hi, A.lo, A.hi
    STG(0, 1, 0); STG(0, 1, 1); STG(0, 0, 0); STG(0, 0, 1);
    STG(1, 1, 0); STG(1, 1, 1); STG(1, 0, 0);
    asm volatile("s_waitcnt vmcnt(6)" ::: "memory");   // tile 0 resident
    __builtin_amdgcn_s_barrier();
    LDA(0, 0); LDB(b0, 0, 16384);      // ph0 operands (drain at ph0 lgkm(0))

    #pragma unroll 2
    for (int t = 0; t < NT; ++t) {
        const int ab  = (t & 1) * 32768;
        const int bb2 = ab + 16384;
        const int nab = ((t + 1) & 1) * 32768;
        // phase 0: MM(0,0)=A0*b0 (reads from prev ph3/prologue); read b1
        if (t + 1 < NT) STG(t + 1, 0, 1);
        __builtin_amdgcn_s_barrier();
        asm volatile("s_waitcnt lgkmcnt(0)" ::: "memory");
        __builtin_amdgcn_s_setprio(1); MM(0, 0, b0); __builtin_amdgcn_s_setprio(0);
        LDB(b1, 1, bb2);
        __builtin_amdgcn_s_barrier();
        // phase 1: MM(0,1)=A0*b1; read A1
        if (t + 2 < NT) STG(t + 2, 1, 0);
        __builtin_amdgcn_s_barrier();
        asm volatile("s_waitcnt lgkmcnt(0)" ::: "memory");
        __builtin_amdgcn_s_setprio(1); MM(0, 1, b1); __builtin_amdgcn_s_setprio(0);
        LDA(1, ab);
        __builtin_amdgcn_s_barrier();
        // phase 2: MM(1,1)=A1*b1
        if (t + 2 < NT) STG(t + 2, 1, 1);
        __builtin_amdgcn_s_barrier();
        asm volatile("s_waitcnt lgkmcnt(0)" ::: "memory");
        __builtin_amdgcn_s_setprio(1); MM(1, 1, b1); __builtin_amdgcn_s_setprio(0);
        __builtin_amdgcn_s_barrier();
        // phase 3: MM(1,0)=A1*b0; boundary vmcnt(6); post-MFMA next A0,b0
        if (t + 2 < NT) {
            STG(t + 2, 0, 0);
            asm volatile("s_waitcnt vmcnt(6)" ::: "memory");
        } else {
            asm volatile("s_waitcnt vmcnt(0)" ::: "memory");
        }
        __builtin_amdgcn_s_barrier();
        __builtin_amdgcn_s_setprio(1); MM(1, 0, b0); __builtin_amdgcn_s_setprio(0);
        if (t + 1 < NT) { LDA(0, nab); LDB(b0, 0, nab + 16384); }
        __builtin_amdgcn_s_barrier();
    }

    // epilogue
    if constexpr (MODE == 0) {
        const int grp = tn * 2 + (wn >> 7);
        const int which = grp >> 4, hd = grp & 15;
        const int n64 = wn & 64;
        if (which == 2) {
            const size_t bz = (size_t)((tm >> 4) * 256 + hd * 16 + (tm & 15));
            u16* tdst = (u16*)aux + bz * 32768;
            #pragma unroll
            for (int a = 0; a < 8; a++) {
                const int mm = wm + (a >> 2) * 64 + (a & 3) * 16 + quad * 4;
                #pragma unroll
                for (int b = 0; b < 4; b++) {
                    const int d = n64 + (b >> 1) * 32 + (b & 1) * 16 + cl;
                    u16 p[4];
                    #pragma unroll
                    for (int r = 0; r < 4; r++) {
                        const float x = acc[a][b][r];
                        p[r] = f2bf(x / (1.f + __expf(-x)));
                    }
                    uint2 pk;
                    pk.x = (unsigned)p[0] | ((unsigned)p[1] << 16);
                    pk.y = (unsigned)p[2] | ((unsigned)p[3] << 16);
                    *(uint2*)&tdst[(size_t)d * 256 + mm] = pk;
                }
            }
            return;
        }
        u16* dst = (which == 0) ? (u16*)Cv
                 : (which == 1) ? (u16*)Cv + (size_t)16777216   // k slot (S1)
                                : (u16*)aux2;                   // gate slot
        #pragma unroll
        for (int a = 0; a < 8; a++)
            #pragma unroll
            for (int b = 0; b < 4; b++)
                #pragma unroll
                for (int r = 0; r < 4; r++) {
                    const int m = tm * 256 + wm + (a >> 2) * 64 + (a & 3) * 16 + quad * 4 + r;
                    const int col = hd * 128 + n64 + (b >> 1) * 32 + (b & 1) * 16 + cl;
                    const float x = acc[a][b][r];
                    const float v = (which == 3) ? 1.f / (1.f + __expf(-x))
                                                 : x / (1.f + __expf(-x));
                    dst[(size_t)m * HID + col] = f2bf(v);
                }
        return;
    } else {
        float* C = (float*)Cv;
        #pragma unroll
        for (int a = 0; a < 8; a++)
            #pragma unroll
            for (int b = 0; b < 4; b++)
                #pragma unroll
                for (int r = 0; r < 4; r++) {
                    const int m = tm * 256 + wm + (a >> 2) * 64 + (a & 3) * 16 + quad * 4 + r;
                    const int n = tn * 256 + wn + (b >> 1) * 32 + (b & 1) * 16 + cl;
                    C[(size_t)m * HID + n] = acc[a][b][r];
                }
    }
}

// ---------------------------------------------------------------------------
// kvt_fused: KVT_j[e][d] = sum_m vT[e][m] * silu_k[m][d] * exp(-s*(255-m)).
// ---------------------------------------------------------------------------
__global__ __launch_bounds__(256) void kvt_fused(const u16* __restrict__ vT,
                                                 const u16* __restrict__ kb,
                                                 float* __restrict__ KVT,
                                                 const float* __restrict__ slope) {
    __shared__ u16 smem[16384];           // A dbuf 2x4096 | Braw dbuf 2x4096

    const int tid = threadIdx.x;
    const int bz  = blockIdx.x;
    const int bb = bz >> 8, hh = (bz >> 4) & 15, jb = bz & 15;
    const float s_ = slope[hh];
    const float es = __expf(s_);
    const size_t rowbase = (size_t)(bb * SEQ + jb * 256);

    const int lane = tid & 63, wv = tid >> 6;
    const int wm = (wv & 1) * 64, wn = (wv >> 1) * 64;
    const int quad = lane >> 4, cl = lane & 15;
    const int lr = lane >> 2;
    const int lc = (lane & 3) * 8;
    const int ko = quad * 8;

    f32x4 acc[4][4];
    const f32x4 zero = {0.f, 0.f, 0.f, 0.f};
    #pragma unroll
    for (int mi = 0; mi < 4; mi++)
        #pragma unroll
        for (int ni = 0; ni < 4; ni++) acc[mi][ni] = zero;

    // A: vT rows (e), contraction m; per-wave 32 rows, [row][32 m] layout
    const u16* gA = vT + (size_t)bz * 32768 + (size_t)(wv * 32 + lr) * 256 + lc;
    // B: raw k rows, source pre-swizzled so linear LDS holds slot-XOR layout
    const u16* gK = kb + (rowbase + (tid >> 4)) * HID + hh * 128
                       + (((tid & 15) ^ (tid >> 4)) * 8);

    auto stage = [&](int c, int buf) {    // 4 gld16 per chunk
        u16* lA = smem + buf * 4096 + wv * 1024;
        gld16(gA + c * 32,                    lA);
        gld16(gA + c * 32 + (size_t)16 * 256, lA + 512);
        u16* lB = smem + 8192 + buf * 4096 + wv * 512 + lane * 8;
        gld16(gK + (size_t)(c * 32) * HID,      lB);
        gld16(gK + (size_t)(c * 32 + 16) * HID, lB + 2048);
    };

    stage(0, 0);
    for (int c = 0; c < 8; ++c) {
        const int cb = c & 1;
        if (c + 1 < 8) {
            stage(c + 1, cb ^ 1);
            asm volatile("s_waitcnt vmcnt(4)" ::: "memory");   // chunk c landed
        } else {
            asm volatile("s_waitcnt vmcnt(0)" ::: "memory");
        }
        __builtin_amdgcn_s_barrier();
        const u16* As   = smem + cb * 4096;
        const u16* braw = smem + 8192 + cb * 4096;
        // decay factors for this thread's m-slice (shared across ni)
        const int kv0 = c * 32;
        const float dec0 = __expf(-s_ * (float)(255 - (kv0 + ko)));
        bf16x8 af[4], bfv[4];
        #pragma unroll
        for (int mi = 0; mi < 4; mi++)
            af[mi] = *(const bf16x8*)&As[(wm + mi * 16 + cl) * 32 + ko];
        #pragma unroll
        for (int ni = 0; ni < 4; ni++) {
            const int d   = wn + ni * 16 + cl;
            const int dhi = d >> 3, dlo = d & 7;
            float dec = dec0;
            union { u16 u[8]; bf16x8 v; } cvt;
            #pragma unroll
            for (int j = 0; j < 8; j++) {
                const int ml = ko + j;
                const u16 raw = braw[ml * 128 + ((dhi ^ (ml & 15)) * 8) + dlo];
                cvt.u[j] = f2bf(bf2f(raw) * dec);
                dec *= es;
            }
            bfv[ni] = cvt.v;
        }
        #pragma unroll
        for (int mi = 0; mi < 4; mi++)
            #pragma unroll
            for (int ni = 0; ni < 4; ni++)
                acc[mi][ni] = __builtin_amdgcn_mfma_f32_16x16x32_bf16(af[mi], bfv[ni], acc[mi][ni], 0, 0, 0);
        __builtin_amdgcn_s_barrier();   // WAR: all waves' reads of buf cb done
    }

    #pragma unroll
    for (int mi = 0; mi < 4; mi++)
        #pragma unroll
        for (int ni = 0; ni < 4; ni++)
            #pragma unroll
            for (int r = 0; r < 4; r++) {
                const int m = wm + mi * 16 + quad * 4 + r;
                const int n = wn + ni * 16 + cl;
                KVT[(size_t)bz * 16384 + m * 128 + n] = acc[mi][ni][r];
            }
}

// ---------------------------------------------------------------------------
// FUSED P+INTRA: grid (2,1,512) = (row-half tm, -, bz); 256 thr = 4 waves 2x2.
// BOTH loops double-buffered with counted vmcnt.
// ---------------------------------------------------------------------------
__global__ __launch_bounds__(256) void fused_pv(const u16* __restrict__ qb,
                                                const u16* __restrict__ kb,
                                                const u16* __restrict__ ST,
                                                const u16* __restrict__ vT,
                                                u16* __restrict__ attn,
                                                const float* __restrict__ slope) {
    __shared__ u16 smem[36864];   // q 16384 | k 2x4096 | P 4096 | Bs 2x4096
    u16* q_lds = smem;            // [4][128][32]
    u16* k_lds = smem + 16384;    // [2][32][128] row-XOR swizzled
    u16* P_lds = smem + 24576;    // [128][32]
    u16* Bs    = smem + 28672;    // [2][128][32]  (ST chunks / v chunks)

    const int tm = blockIdx.x;           // row half within the 256-block
    const int bz = blockIdx.z;
    const int bb = bz >> 8, hh = (bz >> 4) & 15, jb = bz & 15;
    const float s_ = slope[hh];

    const int tid  = threadIdx.x;
    const int lane = tid & 63, wv = tid >> 6;
    const int quad = lane >> 4, cl = lane & 15;
    const int wm = (wv & 1) * 64, wn = (wv >> 1) * 64;
    const int lr = lane >> 2, lc = (lane & 3) * 8;
    const int pcb = (wv >> 1) * 16;      // P kv-col base for this wave

    const size_t rowbase = (size_t)(bb * SEQ + jb * 256);

    // ---- stage q: 4 ks x 2 gld16 (gemm_nt A-tile pattern, linear) ----
    const u16* gq = qb + (rowbase + tm * 128 + wv * 32 + lr) * HID + hh * 128 + lc;
    u16* lq = q_lds + wv * 1024 + lr * 32 + lc;
    #pragma unroll
    for (int ks = 0; ks < 4; ks++) {
        gld16(gq + ks * 32,                 lq + ks * 4096);
        gld16(gq + ks * 32 + 16 * HID,      lq + ks * 4096 + 512);
    }

    f32x4 acc[4][4];
    const f32x4 zero = {0.f, 0.f, 0.f, 0.f};
    #pragma unroll
    for (int mi = 0; mi < 4; mi++)
        #pragma unroll
        for (int ni = 0; ni < 4; ni++) acc[mi][ni] = zero;

    // ---- inter: acc = q @ S^T  (double-buffered ST chunks) ----
    const u16* gS = ST + (size_t)bz * 16384 + (size_t)(wv * 32 + lr) * 128 + lc;
    auto stage_st = [&](int ks, int buf) {       // 2 gld16
        u16* lB = Bs + buf * 4096 + wv * 1024 + lr * 32 + lc;
        gld16(gS + ks * 32,            lB);
        gld16(gS + ks * 32 + 16 * 128, lB + 512);
    };
    stage_st(0, 0);
    #pragma unroll
    for (int ks = 0; ks < 4; ks++) {
        const int sb = ks & 1;
        if (ks + 1 < 4) {
            stage_st(ks + 1, sb ^ 1);
            asm volatile("s_waitcnt vmcnt(2)" ::: "memory");   // q + chunk ks landed
        } else {
            asm volatile("s_waitcnt vmcnt(0)" ::: "memory");
        }
        __builtin_amdgcn_s_barrier();
        bf16x8 af[4], bfv[4];
        #pragma unroll
        for (int mi = 0; mi < 4; mi++)
            af[mi] = *(const bf16x8*)&q_lds[ks * 4096 + (wm + mi * 16 + cl) * 32 + quad * 8];
        #pragma unroll
        for (int ni = 0; ni < 4; ni++)
            bfv[ni] = *(const bf16x8*)&Bs[sb * 4096 + (wn + ni * 16 + cl) * 32 + quad * 8];
        #pragma unroll
        for (int mi = 0; mi < 4; mi++)
            #pragma unroll
            for (int ni = 0; ni < 4; ni++)
                acc[mi][ni] = __builtin_amdgcn_mfma_f32_16x16x32_bf16(af[mi], bfv[ni], acc[mi][ni], 0, 0, 0);
        __builtin_amdgcn_s_barrier();   // WAR: buf sb reads done before restage
    }
    // q_decay scale
    #pragma unroll
    for (int mi = 0; mi < 4; mi++)
        #pragma unroll
        for (int r = 0; r < 4; r++) {
            const int m = tm * 128 + wm + mi * 16 + quad * 4 + r;
            const float qd = __expf(-s_ * (float)(m + 1));
            #pragma unroll
            for (int ni = 0; ni < 4; ni++) acc[mi][ni][r] *= qd;
        }

    // ---- intra: double-buffered chunk pipeline ----
    const int kmax = (tm == 0) ? 128 : 256;
    const int nc   = kmax >> 5;
    const u16* gV = vT + (size_t)bz * 32768 + (size_t)(wv * 32 + lr) * 256 + lc;
    const int krow = tid >> 4;                       // 0..15 per issue
    const int kcol = (((tid & 15) ^ (krow & 7)) * 8);
    const int kvr = pcb + cl;                        // lane's P kv-row (B-frag)

    auto stage_chunk = [&](int c, int buf) {         // 4 gld16
        u16* lk = k_lds + buf * 4096 + wv * 512 + lane * 8;
        u16* lv = Bs + buf * 4096 + wv * 1024 + lr * 32 + lc;
        const int kv0 = c * 32;
        gld16(kb + (rowbase + kv0 +      krow) * HID + hh * 128 + kcol, lk);
        gld16(kb + (rowbase + kv0 + 16 + krow) * HID + hh * 128 + kcol, lk + 2048);
        gld16(gV + kv0,            lv);
        gld16(gV + kv0 + 16 * 256, lv + 512);
    };

    stage_chunk(0, 0);
    for (int c = 0; c < nc; ++c) {
        const int cb = c & 1;
        if (c + 1 < nc) {
            stage_chunk(c + 1, cb ^ 1);
            asm volatile("s_waitcnt vmcnt(4)" ::: "memory");   // chunk c landed
        } else {
            asm volatile("s_waitcnt vmcnt(0)" ::: "memory");
        }
        __builtin_amdgcn_s_barrier();
        // P-GEMM: C[m(64 rows @wm)][kv(16 cols @pcb)] over d=128
        f32x4 acc2[4];
        #pragma unroll
        for (int mi = 0; mi < 4; mi++) acc2[mi] = zero;
        #pragma unroll
        for (int ds = 0; ds < 4; ds++) {
            bf16x8 bk = *(const bf16x8*)&k_lds[cb * 4096 + kvr * 128 + (((ds * 4 + quad) ^ (kvr & 7)) * 8)];
            #pragma unroll
            for (int mi = 0; mi < 4; mi++) {
                bf16x8 aq = *(const bf16x8*)&q_lds[ds * 4096 + (wm + mi * 16 + cl) * 32 + quad * 8];
                acc2[mi] = __builtin_amdgcn_mfma_f32_16x16x32_bf16(aq, bk, acc2[mi], 0, 0, 0);
            }
        }
        // mask + decay + bf16 -> P_lds[128][32]
        const int kv0 = c * 32;
        #pragma unroll
        for (int mi = 0; mi < 4; mi++)
            #pragma unroll
            for (int r = 0; r < 4; r++) {
                const int row = wm + mi * 16 + quad * 4 + r;
                const int mb  = tm * 128 + row;
                const int kv  = kv0 + pcb + cl;
                const int d   = mb - kv;
                const float x = acc2[mi][r];
                P_lds[row * 32 + pcb + cl] = f2bf(d >= 0 ? x * __expf(-s_ * (float)d) : 0.f);
            }
        asm volatile("s_waitcnt lgkmcnt(0)" ::: "memory");
        __builtin_amdgcn_s_barrier();
        // PV: acc += P @ vT^T
        bf16x8 afp[4], bfv[4];
        #pragma unroll
        for (int mi = 0; mi < 4; mi++)
            afp[mi] = *(const bf16x8*)&P_lds[(wm + mi * 16 + cl) * 32 + quad * 8];
        #pragma unroll
        for (int ni = 0; ni < 4; ni++)
            bfv[ni] = *(const bf16x8*)&Bs[cb * 4096 + (wn + ni * 16 + cl) * 32 + quad * 8];
        #pragma unroll
        for (int mi = 0; mi < 4; mi++)
            #pragma unroll
            for (int ni = 0; ni < 4; ni++)
                acc[mi][ni] = __builtin_amdgcn_mfma_f32_16x16x32_bf16(afp[mi], bfv[ni], acc[mi][ni], 0, 0, 0);
        __builtin_amdgcn_s_barrier();   // WAR: all waves' buf/P reads done
    }

    // ---- epilogue: attn write (verbatim M_INTRA) ----
    #pragma unroll
    for (int mi = 0; mi < 4; mi++)
        #pragma unroll
        for (int ni = 0; ni < 4; ni++)
            #pragma unroll
            for (int r = 0; r < 4; r++) {
                const int m = tm * 128 + wm + mi * 16 + quad * 4 + r;
                const int n = wn + ni * 16 + cl;
                attn[(rowbase + m) * HID + hh * 128 + n] = f2bf(acc[mi][ni][r]);
            }
}

// ---------------------------------------------------------------------------
// S_0 = 0; write S_j^T (bf16); S_{j+1} = e^{-256 s} S_j + KV_j.
// ALL 16 KV_j loads are independent -> prefetch to registers up front so
// only the accumulate chain is serial (removes ~15x exposed load latency).
// ---------------------------------------------------------------------------
__global__ __launch_bounds__(256) void scan_kv(const float* __restrict__ KVT,
                                               u16* __restrict__ ST,
                                               const float* __restrict__ slope) {
    const int bh = blockIdx.x >> 4, ch = blockIdx.x & 15;
    const int off = ch * 1024 + threadIdx.x * 4;
    const float bd = __expf(-256.f * slope[bh & 15]);
    float4 kv[16];
    #pragma unroll
    for (int j = 0; j < 16; j++)
        kv[j] = *(const float4*)&KVT[((size_t)(bh * 16 + j)) * 16384 + off];
    float4 st = {0.f, 0.f, 0.f, 0.f};
    #pragma unroll
    for (int j = 0; j < 16; j++) {
        const size_t base = ((size_t)(bh * 16 + j)) * 16384 + off;
        uint2 o;
        o.x = (unsigned)f2bf(st.x) | ((unsigned)f2bf(st.y) << 16);
        o.y = (unsigned)f2bf(st.z) | ((unsigned)f2bf(st.w) << 16);
        *(uint2*)&ST[base] = o;
        st.x = bd * st.x + kv[j].x;
        st.y = bd * st.y + kv[j].y;
        st.z = bd * st.z + kv[j].z;
        st.w = bd * st.w + kv[j].w;
    }
}

// ---------------------------------------------------------------------------
// y = gate * (attn * rsqrt(mean(attn^2)+eps)) * norm_w   (one WG per row)
// Also folds the w_out fp32->bf16 cast (2 elems/thread; 8192x512 = 2048^2).
// ---------------------------------------------------------------------------
__global__ __launch_bounds__(256) void rmsnorm_gate(const u16* __restrict__ attn,
                                                    const u16* __restrict__ gate,
                                                    const float* __restrict__ nw,
                                                    u16* __restrict__ y,
                                                    const float* __restrict__ wout,
                                                    u16* __restrict__ wout_bf) {
    const int r = blockIdx.x, tid = threadIdx.x;

    // folded w_out cast: block r covers elements [r*512, r*512+512)
    {
        const size_t wi = (size_t)r * 512 + tid * 2;
        const float2 wf = *(const float2*)&wout[wi];
        *(unsigned*)&wout_bf[wi] = (unsigned)f2bf(wf.x) | ((unsigned)f2bf(wf.y) << 16);
    }

    const size_t base = (size_t)r * HID + tid * 8;
    const uint4 a = *(const uint4*)&attn[base];
    float x[8];
    x[0] = bf2f(a.x & 0xffff); x[1] = bf2f(a.x >> 16);
    x[2] = bf2f(a.y & 0xffff); x[3] = bf2f(a.y >> 16);
    x[4] = bf2f(a.z & 0xffff); x[5] = bf2f(a.z >> 16);
    x[6] = bf2f(a.w & 0xffff); x[7] = bf2f(a.w >> 16);
    float s = 0.f;
    #pragma unroll
    for (int i = 0; i < 8; i++) s += x[i] * x[i];
    #pragma unroll
    for (int off = 32; off > 0; off >>= 1) s += __shfl_down(s, off);
    __shared__ float red[4];
    if ((tid & 63) == 0) red[tid >> 6] = s;
    __syncthreads();
    const float tot = red[0] + red[1] + red[2] + red[3];
    const float sc = rsqrtf(tot * (1.f / 2048.f) + 1e-6f);
    const uint4 g = *(const uint4*)&gate[base];
    float gv[8];
    gv[0] = bf2f(g.x & 0xffff); gv[1] = bf2f(g.x >> 16);
    gv[2] = bf2f(g.y & 0xffff); gv[3] = bf2f(g.y >> 16);
    gv[4] = bf2f(g.z & 0xffff); gv[5] = bf2f(g.z >> 16);
    gv[6] = bf2f(g.w & 0xffff); gv[7] = bf2f(g.w >> 16);
    const float4 w0 = *(const float4*)&nw[tid * 8];
    const float4 w1 = *(const float4*)&nw[tid * 8 + 4];
    const float wv[8] = {w0.x, w0.y, w0.z, w0.w, w1.x, w1.y, w1.z, w1.w};
    u16 o[8];
    #pragma unroll
    for (int i = 0; i < 8; i++) o[i] = f2bf(gv[i] * x[i] * sc * wv[i]);
    uint4 ov;
    ov.x = (unsigned)o[0] | ((unsigned)o[1] << 16);
    ov.y = (unsigned)o[2] | ((unsigned)o[3] << 16);
    ov.z = (unsigned)o[4] | ((unsigned)o[5] << 16);
    ov.w = (unsigned)o[6] | ((unsigned)o[7] << 16);
    *(uint4*)&y[base] = ov;
}

// ---------------------------------------------------------------------------
extern "C" void kernel_launch(void* const* d_in, const int* in_sizes, int n_in,
                              void* d_out, int out_size, void* d_ws, size_t ws_size,
                              hipStream_t stream) {
    const float* hidden = (const float*)d_in[0];
    const float* slope  = (const float*)d_in[1];
    const float* w_qkv  = (const float*)d_in[2];
    const float* w_gate = (const float*)d_in[3];
    const float* w_out  = (const float*)d_in[4];
    const float* norm_w = (const float*)d_in[5];
    float* out = (float*)d_out;

    // 7 slots x 33,554,432 B = 234,881,024 B total
    char* w = (char*)d_ws;
    u16* qb   = (u16*)(w);                 // S0: q                 [QKV .. fused_pv]
    u16* kb   = (u16*)(w +  33554432);     // S1: k                 [QKV .. fused_pv]
    u16* kTs  = (u16*)(w +  67108864);     // S2: (ST / y slot)
    u16* hid_bf = (u16*)(w + 100663296);   // S3: hidden bf16       [cast .. QKV]
    u16* vT   = (u16*)(w + 134217728);     // S4: vT (via QKV)      [QKV .. fused_pv]
    u16* gate = (u16*)(w + 167772160);     // S5: gate (via QKV)    [QKV .. rms]
    u16* wqkv_bf  = (u16*)(w + 201326592); // S6: w_qkv bf16 25.17M [cast .. QKV]
    u16* wgate_bf = (u16*)(w + 201326592 + 25165824); // S6 tail 8.39M, contiguous
    // aliases (disjoint lifetimes):
    float* KVT  = (float*)hid_bf;          // S3: KV^T fp32         [kvt .. scan]
    u16*   ST   = kTs;                     // S2: S^T bf16 16.8M    [scan .. fused_pv]
    u16*   wout_bf = kb;                   // S1: w_out bf16        [rms .. OUT]
    u16*   attn = wqkv_bf;                 // S6: attn              [fused_pv .. rms]
    u16*   y    = kTs;                     // S2: y                 [rms .. OUT]

    static bool s_attr = false;
    if (!s_attr) {
        (void)hipFuncSetAttribute((const void*)gemm256<0>,
                                  hipFuncAttributeMaxDynamicSharedMemorySize, 131072);
        (void)hipFuncSetAttribute((const void*)gemm256<1>,
                                  hipFuncAttributeMaxDynamicSharedMemorySize, 131072);
        s_attr = true;
    }

    // fused casts: hidden | w_qkv | w_gate in one launch
    castk3<<<32768, 256, 0, stream>>>(hidden, hid_bf, w_qkv, wqkv_bf, w_gate, wgate_bf);

    // fused qkv+gate: B = [w_qkv ; w_gate] (8192 x 2048 contiguous)
    gemm256<0><<<dim3(1024), dim3(512), 131072, stream>>>(hid_bf, wqkv_bf, qb, vT, gate);
    kvt_fused       <<<512,             256, 0, stream>>>(vT, kb, KVT, slope);
    scan_kv         <<<512,             256, 0, stream>>>(KVT, ST, slope);
    fused_pv        <<<dim3(2, 1, 512), 256, 0, stream>>>(qb, kb, ST, vT, attn, slope);
    rmsnorm_gate    <<<8192,            256, 0, stream>>>(attn, gate, norm_w, y, w_out, wout_bf);
    gemm256<1><<<dim3(256), dim3(512), 131072, stream>>>(y, wout_bf, (void*)out, nullptr, nullptr);
}

// Round 20
// 429.915 us; speedup vs baseline: 1.0436x; 1.0006x over previous
//
#include <hip/hip_runtime.h>

// ---------------------------------------------------------------------------
// MiniMax-M1 Lightning Attention forward, MI355X / gfx950.
//   0. castk3: fp32->bf16 for hidden + w_qkv + w_gate in ONE launch
//   1. fused qkv+gate via 256x256 lockstep GEMM (R11 rotated-read schedule)
//      epilogue: q,k,gate row-major; v stored DIRECTLY transposed (vT)
//   2. kvt_fused: KVT_j = vT @ (silu_k*decay)^T -- transpose+decay folded
//      into the B-frag build.  Double-buffered (vmcnt(4)/chunk).
//   3. scan: S_{j+1} = e^{-256 s} S_j + KV_j ; 16 KV loads prefetched.
//   4+5 FUSED (fused_pv): inter (q@S^T, q_decay) + per-32-kv-chunk P in-reg
//      -> LDS round-trip -> acc += P@v.  BOTH loops double-buffered.
//      jb==0 blocks skip the inter pass entirely (S_0 = 0).
//   6. rmsnorm_gate: y = gate * rmsnorm(attn) * norm_w  (+ folds w_out cast)
//   7. out = y @ w_out^T via same 256 GEMM [fp32 -> d_out]
// Workspace: 7 slots x 33,554,432 B = 234,881,024 B peak.
// ---------------------------------------------------------------------------

typedef unsigned short u16;
typedef __bf16 bf16x8 __attribute__((ext_vector_type(8)));
typedef float f32x4 __attribute__((ext_vector_type(4)));

#define SEQ 4096
#define HID 2048

__device__ __forceinline__ u16 f2bf(float f) {
    union { float f; unsigned u; } v; v.f = f;
    unsigned r = v.u + 0x7fffu + ((v.u >> 16) & 1u);   // round-to-nearest-even
    return (u16)(r >> 16);
}
__device__ __forceinline__ float bf2f(u16 u) {
    union { unsigned u; float f; } v; v.u = ((unsigned)u) << 16; return v.f;
}

// async global->LDS, 16B per lane; lds dest must be wave-uniform base (+lane*16)
typedef __attribute__((address_space(1))) unsigned char gas_u8;
typedef __attribute__((address_space(3))) unsigned char las_u8;
__device__ __forceinline__ void gld16(const void* g, void* l) {
    __builtin_amdgcn_global_load_lds((gas_u8*)g, (las_u8*)l, 16, 0, 0);
}

// ---------------------------------------------------------------------------
// castk3: hidden|w_qkv|w_gate fp32->bf16 in one launch (4 elems/thread).
// ---------------------------------------------------------------------------
__global__ __launch_bounds__(256) void castk3(const float* __restrict__ a, u16* __restrict__ ao,
                                              const float* __restrict__ b, u16* __restrict__ bo,
                                              const float* __restrict__ c, u16* __restrict__ co) {
    const int bid = blockIdx.x;
    const float* src; u16* dst; size_t i;
    if (bid < 16384)      { src = a; dst = ao; i = (size_t)bid * 256 + threadIdx.x; }
    else if (bid < 28672) { src = b; dst = bo; i = (size_t)(bid - 16384) * 256 + threadIdx.x; }
    else                  { src = c; dst = co; i = (size_t)(bid - 28672) * 256 + threadIdx.x; }
    const float4 f = *(const float4*)&src[i * 4];
    uint2 o;
    o.x = (unsigned)f2bf(f.x) | ((unsigned)f2bf(f.y) << 16);
    o.y = (unsigned)f2bf(f.z) | ((unsigned)f2bf(f.w) << 16);
    *(uint2*)&dst[i * 4] = o;
}

// ---------------------------------------------------------------------------
// 256x256-tile lockstep pipelined NT GEMM (R11 rotated-read schedule).
// MODE 0: fused QKV+gate epilogue; MODE 1: f32 out.
// ---------------------------------------------------------------------------
template <int MODE>
__global__ __launch_bounds__(512, 2) void gemm256(const u16* __restrict__ A,
                                                  const u16* __restrict__ Bm,
                                                  void* __restrict__ Cv,
                                                  void* __restrict__ aux,
                                                  void* __restrict__ aux2) {
    constexpr int NTN = (MODE == 0) ? 32 : 8;     // tiles along N
    constexpr int NT  = 32;                       // K tiles (2048 / 64)
    extern __shared__ u16 smem[];                 // [2][A 16384 | B 16384]

    // XCD swizzle: 8 XCDs; per-XCD 4-row x 8-col rectangular supertiles
    const int bid = blockIdx.x;
    const int xcd = bid & 7, l = bid >> 3;
    int tm, tn;
    if constexpr (MODE == 0) {       // 32x32 tile grid, 128 WGs per XCD
        tm = xcd * 4 + (l & 3);
        tn = ((l >> 2) & 7) | ((l >> 5) << 3);
    } else {                         // 32x8 grid, 32 WGs per XCD (4x8 rect)
        const int wgid = xcd * 32 + l;
        tm = wgid / NTN; tn = wgid % NTN;
    }

    const int tid  = threadIdx.x;
    const int lane = tid & 63, wv = tid >> 6;
    const int quad = lane >> 4, cl = lane & 15;
    const int wm = (wv & 1) * 128, wn = (wv >> 1) * 64;

    const int srw  = tid >> 3;
    const int colo = ((tid & 7) ^ (srw & 7)) * 8;
    const u16* gA0 = A  + (size_t)(tm * 256 + srw) * HID + colo;
    const u16* gB0 = Bm + (size_t)(tn * 256 + srw) * HID + colo;

    const int x0 = ((quad       ^ (cl & 7)) * 8);
    const int x1 = (((4 + quad) ^ (cl & 7)) * 8);

    f32x4 acc[8][4];
    const f32x4 zero = {0.f, 0.f, 0.f, 0.f};
    #pragma unroll
    for (int a = 0; a < 8; a++)
        #pragma unroll
        for (int b = 0; b < 4; b++) acc[a][b] = zero;

    bf16x8 af[8], b0[4], b1[4];

    auto STG = [&](int kt, int mat, int hh) {   // stage one 128x64 half-tile
        const u16* g = (mat ? gB0 : gA0) + (size_t)(hh * 128) * HID + kt * 64;
        u16* lp = smem + (kt & 1) * 32768 + mat * 16384 + hh * 8192 + wv * 512;
        gld16(g, lp);
        gld16(g + (size_t)64 * HID, lp + 4096);
    };
    auto LDA = [&](int qm, int ab) {
        #pragma unroll
        for (int mi = 0; mi < 4; mi++) {
            const int rr = (wm + qm * 64 + mi * 16 + cl) * 64 + ab;
            af[mi * 2 + 0] = *(const bf16x8*)&smem[rr + x0];
            af[mi * 2 + 1] = *(const bf16x8*)&smem[rr + x1];
        }
    };
    auto LDB = [&](bf16x8* d, int qn, int bb2) {
        #pragma unroll
        for (int ni = 0; ni < 2; ni++) {
            const int rr = (wn + qn * 32 + ni * 16 + cl) * 64 + bb2;
            d[ni * 2 + 0] = *(const bf16x8*)&smem[rr + x0];
            d[ni * 2 + 1] = *(const bf16x8*)&smem[rr + x1];
        }
    };
    auto MM = [&](int qm, int qn, const bf16x8* bv) {
        #pragma unroll
        for (int mi = 0; mi < 4; mi++)
            #pragma unroll
            for (int ni = 0; ni < 2; ni++) {
                f32x4 c = acc[qm * 4 + mi][qn * 2 + ni];
                c = __builtin_amdgcn_mfma_f32_16x16x32_bf16(af[mi * 2 + 0], bv[ni * 2 + 0], c, 0, 0, 0);
                c = __builtin_amdgcn_mfma_f32_16x16x32_bf16(af[mi * 2 + 1], bv[ni * 2 + 1], c, 0, 0, 0);
                acc[qm * 4 + mi][qn * 2 + ni] = c;
            }
    };

    // prologue: issue stream per tile = B.lo, B.hi, A.lo, A.hi
    STG(0, 1, 0); STG(0, 1, 1); STG(0, 0, 0); STG(0, 0, 1);
    STG(1, 1, 0); STG(1, 1, 1); STG(1, 0, 0);
    asm volatile("s_waitcnt vmcnt(6)" ::: "memory");   // tile 0 resident
    __builtin_amdgcn_s_barrier();
    LDA(0, 0); LDB(b0, 0, 16384);      // ph0 operands (drain at ph0 lgkm(0))

    #pragma unroll 2
    for (int t = 0; t < NT; ++t) {
        const int ab  = (t & 1) * 32768;
        const int bb2 = ab + 16384;
        const int nab = ((t + 1) & 1) * 32768;
        // phase 0: MM(0,0)=A0*b0 (reads from prev ph3/prologue); read b1
        if (t + 1 < NT) STG(t + 1, 0, 1);
        __builtin_amdgcn_s_barrier();
        asm volatile("s_waitcnt lgkmcnt(0)" ::: "memory");
        __builtin_amdgcn_s_setprio(1); MM(0, 0, b0); __builtin_amdgcn_s_setprio(0);
        LDB(b1, 1, bb2);
        __builtin_amdgcn_s_barrier();
        // phase 1: MM(0,1)=A0*b1; read A1
        if (t + 2 < NT) STG(t + 2, 1, 0);
        __builtin_amdgcn_s_barrier();
        asm volatile("s_waitcnt lgkmcnt(0)" ::: "memory");
        __builtin_amdgcn_s_setprio(1); MM(0, 1, b1); __builtin_amdgcn_s_setprio(0);
        LDA(1, ab);
        __builtin_amdgcn_s_barrier();
        // phase 2: MM(1,1)=A1*b1
        if (t + 2 < NT) STG(t + 2, 1, 1);
        __builtin_amdgcn_s_barrier();
        asm volatile("s_waitcnt lgkmcnt(0)" ::: "memory");
        __builtin_amdgcn_s_setprio(1); MM(1, 1, b1); __builtin_amdgcn_s_setprio(0);
        __builtin_amdgcn_s_barrier();
        // phase 3: MM(1,0)=A1*b0; boundary vmcnt(6); post-MFMA next A0,b0
        if (t + 2 < NT) {
            STG(t + 2, 0, 0);
            asm volatile("s_waitcnt vmcnt(6)" ::: "memory");
        } else {
            asm volatile("s_waitcnt vmcnt(0)" ::: "memory");
        }
        __builtin_amdgcn_s_barrier();
        __builtin_amdgcn_s_setprio(1); MM(1, 0, b0); __builtin_amdgcn_s_setprio(0);
        if (t + 1 < NT) { LDA(0, nab); LDB(b0, 0, nab + 16384); }
        __builtin_amdgcn_s_barrier();
    }

    // epilogue
    if constexpr (MODE == 0) {
        const int grp = tn * 2 + (wn >> 7);
        const int which = grp >> 4, hd = grp & 15;
        const int n64 = wn & 64;
        if (which == 2) {
            const size_t bz = (size_t)((tm >> 4) * 256 + hd * 16 + (tm & 15));
            u16* tdst = (u16*)aux + bz * 32768;
            #pragma unroll
            for (int a = 0; a < 8; a++) {
                const int mm = wm + (a >> 2) * 64 + (a & 3) * 16 + quad * 4;
                #pragma unroll
                for (int b = 0; b < 4; b++) {
                    const int d = n64 + (b >> 1) * 32 + (b & 1) * 16 + cl;
                    u16 p[4];
                    #pragma unroll
                    for (int r = 0; r < 4; r++) {
                        const float x = acc[a][b][r];
                        p[r] = f2bf(x / (1.f + __expf(-x)));
                    }
                    uint2 pk;
                    pk.x = (unsigned)p[0] | ((unsigned)p[1] << 16);
                    pk.y = (unsigned)p[2] | ((unsigned)p[3] << 16);
                    *(uint2*)&tdst[(size_t)d * 256 + mm] = pk;
                }
            }
            return;
        }
        u16* dst = (which == 0) ? (u16*)Cv
                 : (which == 1) ? (u16*)Cv + (size_t)16777216   // k slot (S1)
                                : (u16*)aux2;                   // gate slot
        #pragma unroll
        for (int a = 0; a < 8; a++)
            #pragma unroll
            for (int b = 0; b < 4; b++)
                #pragma unroll
                for (int r = 0; r < 4; r++) {
                    const int m = tm * 256 + wm + (a >> 2) * 64 + (a & 3) * 16 + quad * 4 + r;
                    const int col = hd * 128 + n64 + (b >> 1) * 32 + (b & 1) * 16 + cl;
                    const float x = acc[a][b][r];
                    const float v = (which == 3) ? 1.f / (1.f + __expf(-x))
                                                 : x / (1.f + __expf(-x));
                    dst[(size_t)m * HID + col] = f2bf(v);
                }
        return;
    } else {
        float* C = (float*)Cv;
        #pragma unroll
        for (int a = 0; a < 8; a++)
            #pragma unroll
            for (int b = 0; b < 4; b++)
                #pragma unroll
                for (int r = 0; r < 4; r++) {
                    const int m = tm * 256 + wm + (a >> 2) * 64 + (a & 3) * 16 + quad * 4 + r;
                    const int n = tn * 256 + wn + (b >> 1) * 32 + (b & 1) * 16 + cl;
                    C[(size_t)m * HID + n] = acc[a][b][r];
                }
    }
}

// ---------------------------------------------------------------------------
// kvt_fused: KVT_j[e][d] = sum_m vT[e][m] * silu_k[m][d] * exp(-s*(255-m)).
// ---------------------------------------------------------------------------
__global__ __launch_bounds__(256) void kvt_fused(const u16* __restrict__ vT,
                                                 const u16* __restrict__ kb,
                                                 float* __restrict__ KVT,
                                                 const float* __restrict__ slope) {
    __shared__ u16 smem[16384];           // A dbuf 2x4096 | Braw dbuf 2x4096

    const int tid = threadIdx.x;
    const int bz  = blockIdx.x;
    const int bb = bz >> 8, hh = (bz >> 4) & 15, jb = bz & 15;
    const float s_ = slope[hh];
    const float es = __expf(s_);
    const size_t rowbase = (size_t)(bb * SEQ + jb * 256);

    const int lane = tid & 63, wv = tid >> 6;
    const int wm = (wv & 1) * 64, wn = (wv >> 1) * 64;
    const int quad = lane >> 4, cl = lane & 15;
    const int lr = lane >> 2;
    const int lc = (lane & 3) * 8;
    const int ko = quad * 8;

    f32x4 acc[4][4];
    const f32x4 zero = {0.f, 0.f, 0.f, 0.f};
    #pragma unroll
    for (int mi = 0; mi < 4; mi++)
        #pragma unroll
        for (int ni = 0; ni < 4; ni++) acc[mi][ni] = zero;

    // A: vT rows (e), contraction m; per-wave 32 rows, [row][32 m] layout
    const u16* gA = vT + (size_t)bz * 32768 + (size_t)(wv * 32 + lr) * 256 + lc;
    // B: raw k rows, source pre-swizzled so linear LDS holds slot-XOR layout
    const u16* gK = kb + (rowbase + (tid >> 4)) * HID + hh * 128
                       + (((tid & 15) ^ (tid >> 4)) * 8);

    auto stage = [&](int c, int buf) {    // 4 gld16 per chunk
        u16* lA = smem + buf * 4096 + wv * 1024;
        gld16(gA + c * 32,                    lA);
        gld16(gA + c * 32 + (size_t)16 * 256, lA + 512);
        u16* lB = smem + 8192 + buf * 4096 + wv * 512 + lane * 8;
        gld16(gK + (size_t)(c * 32) * HID,      lB);
        gld16(gK + (size_t)(c * 32 + 16) * HID, lB + 2048);
    };

    stage(0, 0);
    for (int c = 0; c < 8; ++c) {
        const int cb = c & 1;
        if (c + 1 < 8) {
            stage(c + 1, cb ^ 1);
            asm volatile("s_waitcnt vmcnt(4)" ::: "memory");   // chunk c landed
        } else {
            asm volatile("s_waitcnt vmcnt(0)" ::: "memory");
        }
        __builtin_amdgcn_s_barrier();
        const u16* As   = smem + cb * 4096;
        const u16* braw = smem + 8192 + cb * 4096;
        // decay factors for this thread's m-slice (shared across ni)
        const int kv0 = c * 32;
        const float dec0 = __expf(-s_ * (float)(255 - (kv0 + ko)));
        bf16x8 af[4], bfv[4];
        #pragma unroll
        for (int mi = 0; mi < 4; mi++)
            af[mi] = *(const bf16x8*)&As[(wm + mi * 16 + cl) * 32 + ko];
        #pragma unroll
        for (int ni = 0; ni < 4; ni++) {
            const int d   = wn + ni * 16 + cl;
            const int dhi = d >> 3, dlo = d & 7;
            float dec = dec0;
            union { u16 u[8]; bf16x8 v; } cvt;
            #pragma unroll
            for (int j = 0; j < 8; j++) {
                const int ml = ko + j;
                const u16 raw = braw[ml * 128 + ((dhi ^ (ml & 15)) * 8) + dlo];
                cvt.u[j] = f2bf(bf2f(raw) * dec);
                dec *= es;
            }
            bfv[ni] = cvt.v;
        }
        #pragma unroll
        for (int mi = 0; mi < 4; mi++)
            #pragma unroll
            for (int ni = 0; ni < 4; ni++)
                acc[mi][ni] = __builtin_amdgcn_mfma_f32_16x16x32_bf16(af[mi], bfv[ni], acc[mi][ni], 0, 0, 0);
        __builtin_amdgcn_s_barrier();   // WAR: all waves' reads of buf cb done
    }

    #pragma unroll
    for (int mi = 0; mi < 4; mi++)
        #pragma unroll
        for (int ni = 0; ni < 4; ni++)
            #pragma unroll
            for (int r = 0; r < 4; r++) {
                const int m = wm + mi * 16 + quad * 4 + r;
                const int n = wn + ni * 16 + cl;
                KVT[(size_t)bz * 16384 + m * 128 + n] = acc[mi][ni][r];
            }
}

// ---------------------------------------------------------------------------
// FUSED P+INTRA: grid (2,1,512) = (row-half tm, -, bz); 256 thr = 4 waves 2x2.
// BOTH loops double-buffered with counted vmcnt.  jb==0: skip inter (S_0=0).
// ---------------------------------------------------------------------------
__global__ __launch_bounds__(256) void fused_pv(const u16* __restrict__ qb,
                                                const u16* __restrict__ kb,
                                                const u16* __restrict__ ST,
                                                const u16* __restrict__ vT,
                                                u16* __restrict__ attn,
                                                const float* __restrict__ slope) {
    __shared__ u16 smem[36864];   // q 16384 | k 2x4096 | P 4096 | Bs 2x4096
    u16* q_lds = smem;            // [4][128][32]
    u16* k_lds = smem + 16384;    // [2][32][128] row-XOR swizzled
    u16* P_lds = smem + 24576;    // [128][32]
    u16* Bs    = smem + 28672;    // [2][128][32]  (ST chunks / v chunks)

    const int tm = blockIdx.x;           // row half within the 256-block
    const int bz = blockIdx.z;
    const int bb = bz >> 8, hh = (bz >> 4) & 15, jb = bz & 15;
    const float s_ = slope[hh];

    const int tid  = threadIdx.x;
    const int lane = tid & 63, wv = tid >> 6;
    const int quad = lane >> 4, cl = lane & 15;
    const int wm = (wv & 1) * 64, wn = (wv >> 1) * 64;
    const int lr = lane >> 2, lc = (lane & 3) * 8;
    const int pcb = (wv >> 1) * 16;      // P kv-col base for this wave

    const size_t rowbase = (size_t)(bb * SEQ + jb * 256);

    // ---- stage q: 4 ks x 2 gld16 (gemm_nt A-tile pattern, linear) ----
    const u16* gq = qb + (rowbase + tm * 128 + wv * 32 + lr) * HID + hh * 128 + lc;
    u16* lq = q_lds + wv * 1024 + lr * 32 + lc;
    #pragma unroll
    for (int ks = 0; ks < 4; ks++) {
        gld16(gq + ks * 32,                 lq + ks * 4096);
        gld16(gq + ks * 32 + 16 * HID,      lq + ks * 4096 + 512);
    }

    f32x4 acc[4][4];
    const f32x4 zero = {0.f, 0.f, 0.f, 0.f};
    #pragma unroll
    for (int mi = 0; mi < 4; mi++)
        #pragma unroll
        for (int ni = 0; ni < 4; ni++) acc[mi][ni] = zero;

    if (jb != 0) {
        // ---- inter: acc = q @ S^T  (double-buffered ST chunks) ----
        const u16* gS = ST + (size_t)bz * 16384 + (size_t)(wv * 32 + lr) * 128 + lc;
        auto stage_st = [&](int ks, int buf) {       // 2 gld16
            u16* lB = Bs + buf * 4096 + wv * 1024 + lr * 32 + lc;
            gld16(gS + ks * 32,            lB);
            gld16(gS + ks * 32 + 16 * 128, lB + 512);
        };
        stage_st(0, 0);
        #pragma unroll
        for (int ks = 0; ks < 4; ks++) {
            const int sb = ks & 1;
            if (ks + 1 < 4) {
                stage_st(ks + 1, sb ^ 1);
                asm volatile("s_waitcnt vmcnt(2)" ::: "memory");   // q + chunk ks landed
            } else {
                asm volatile("s_waitcnt vmcnt(0)" ::: "memory");
            }
            __builtin_amdgcn_s_barrier();
            bf16x8 af[4], bfv[4];
            #pragma unroll
            for (int mi = 0; mi < 4; mi++)
                af[mi] = *(const bf16x8*)&q_lds[ks * 4096 + (wm + mi * 16 + cl) * 32 + quad * 8];
            #pragma unroll
            for (int ni = 0; ni < 4; ni++)
                bfv[ni] = *(const bf16x8*)&Bs[sb * 4096 + (wn + ni * 16 + cl) * 32 + quad * 8];
            #pragma unroll
            for (int mi = 0; mi < 4; mi++)
                #pragma unroll
                for (int ni = 0; ni < 4; ni++)
                    acc[mi][ni] = __builtin_amdgcn_mfma_f32_16x16x32_bf16(af[mi], bfv[ni], acc[mi][ni], 0, 0, 0);
            __builtin_amdgcn_s_barrier();   // WAR: buf sb reads done before restage
        }
        // q_decay scale
        #pragma unroll
        for (int mi = 0; mi < 4; mi++)
            #pragma unroll
            for (int r = 0; r < 4; r++) {
                const int m = tm * 128 + wm + mi * 16 + quad * 4 + r;
                const float qd = __expf(-s_ * (float)(m + 1));
                #pragma unroll
                for (int ni = 0; ni < 4; ni++) acc[mi][ni][r] *= qd;
            }
    }

    // ---- intra: double-buffered chunk pipeline ----
    const int kmax = (tm == 0) ? 128 : 256;
    const int nc   = kmax >> 5;
    const u16* gV = vT + (size_t)bz * 32768 + (size_t)(wv * 32 + lr) * 256 + lc;
    const int krow = tid >> 4;                       // 0..15 per issue
    const int kcol = (((tid & 15) ^ (krow & 7)) * 8);
    const int kvr = pcb + cl;                        // lane's P kv-row (B-frag)

    auto stage_chunk = [&](int c, int buf) {         // 4 gld16
        u16* lk = k_lds + buf * 4096 + wv * 512 + lane * 8;
        u16* lv = Bs + buf * 4096 + wv * 1024 + lr * 32 + lc;
        const int kv0 = c * 32;
        gld16(kb + (rowbase + kv0 +      krow) * HID + hh * 128 + kcol, lk);
        gld16(kb + (rowbase + kv0 + 16 + krow) * HID + hh * 128 + kcol, lk + 2048);
        gld16(gV + kv0,            lv);
        gld16(gV + kv0 + 16 * 256, lv + 512);
    };

    stage_chunk(0, 0);
    for (int c = 0; c < nc; ++c) {
        const int cb = c & 1;
        if (c + 1 < nc) {
            stage_chunk(c + 1, cb ^ 1);
            asm volatile("s_waitcnt vmcnt(4)" ::: "memory");   // chunk c landed
        } else {
            asm volatile("s_waitcnt vmcnt(0)" ::: "memory");
        }
        __builtin_amdgcn_s_barrier();
        // P-GEMM: C[m(64 rows @wm)][kv(16 cols @pcb)] over d=128
        f32x4 acc2[4];
        #pragma unroll
        for (int mi = 0; mi < 4; mi++) acc2[mi] = zero;
        #pragma unroll
        for (int ds = 0; ds < 4; ds++) {
            bf16x8 bk = *(const bf16x8*)&k_lds[cb * 4096 + kvr * 128 + (((ds * 4 + quad) ^ (kvr & 7)) * 8)];
            #pragma unroll
            for (int mi = 0; mi < 4; mi++) {
                bf16x8 aq = *(const bf16x8*)&q_lds[ds * 4096 + (wm + mi * 16 + cl) * 32 + quad * 8];
                acc2[mi] = __builtin_amdgcn_mfma_f32_16x16x32_bf16(aq, bk, acc2[mi], 0, 0, 0);
            }
        }
        // mask + decay + bf16 -> P_lds[128][32]
        const int kv0 = c * 32;
        #pragma unroll
        for (int mi = 0; mi < 4; mi++)
            #pragma unroll
            for (int r = 0; r < 4; r++) {
                const int row = wm + mi * 16 + quad * 4 + r;
                const int mb  = tm * 128 + row;
                const int kv  = kv0 + pcb + cl;
                const int d   = mb - kv;
                const float x = acc2[mi][r];
                P_lds[row * 32 + pcb + cl] = f2bf(d >= 0 ? x * __expf(-s_ * (float)d) : 0.f);
            }
        asm volatile("s_waitcnt lgkmcnt(0)" ::: "memory");
        __builtin_amdgcn_s_barrier();
        // PV: acc += P @ vT^T
        bf16x8 afp[4], bfv[4];
        #pragma unroll
        for (int mi = 0; mi < 4; mi++)
            afp[mi] = *(const bf16x8*)&P_lds[(wm + mi * 16 + cl) * 32 + quad * 8];
        #pragma unroll
        for (int ni = 0; ni < 4; ni++)
            bfv[ni] = *(const bf16x8*)&Bs[cb * 4096 + (wn + ni * 16 + cl) * 32 + quad * 8];
        #pragma unroll
        for (int mi = 0; mi < 4; mi++)
            #pragma unroll
            for (int ni = 0; ni < 4; ni++)
                acc[mi][ni] = __builtin_amdgcn_mfma_f32_16x16x32_bf16(afp[mi], bfv[ni], acc[mi][ni], 0, 0, 0);
        __builtin_amdgcn_s_barrier();   // WAR: all waves' buf/P reads done
    }

    // ---- epilogue: attn write (verbatim M_INTRA) ----
    #pragma unroll
    for (int mi = 0; mi < 4; mi++)
        #pragma unroll
        for (int ni = 0; ni < 4; ni++)
            #pragma unroll
            for (int r = 0; r < 4; r++) {
                const int m = tm * 128 + wm + mi * 16 + quad * 4 + r;
                const int n = wn + ni * 16 + cl;
                attn[(rowbase + m) * HID + hh * 128 + n] = f2bf(acc[mi][ni][r]);
            }
}

// ---------------------------------------------------------------------------
// S_0 = 0; write S_j^T (bf16); S_{j+1} = e^{-256 s} S_j + KV_j.
// ---------------------------------------------------------------------------
__global__ __launch_bounds__(256) void scan_kv(const float* __restrict__ KVT,
                                               u16* __restrict__ ST,
                                               const float* __restrict__ slope) {
    const int bh = blockIdx.x >> 4, ch = blockIdx.x & 15;
    const int off = ch * 1024 + threadIdx.x * 4;
    const float bd = __expf(-256.f * slope[bh & 15]);
    float4 kv[16];
    #pragma unroll
    for (int j = 0; j < 16; j++)
        kv[j] = *(const float4*)&KVT[((size_t)(bh * 16 + j)) * 16384 + off];
    float4 st = {0.f, 0.f, 0.f, 0.f};
    #pragma unroll
    for (int j = 0; j < 16; j++) {
        const size_t base = ((size_t)(bh * 16 + j)) * 16384 + off;
        uint2 o;
        o.x = (unsigned)f2bf(st.x) | ((unsigned)f2bf(st.y) << 16);
        o.y = (unsigned)f2bf(st.z) | ((unsigned)f2bf(st.w) << 16);
        *(uint2*)&ST[base] = o;
        st.x = bd * st.x + kv[j].x;
        st.y = bd * st.y + kv[j].y;
        st.z = bd * st.z + kv[j].z;
        st.w = bd * st.w + kv[j].w;
    }
}

// ---------------------------------------------------------------------------
// y = gate * (attn * rsqrt(mean(attn^2)+eps)) * norm_w   (one WG per row)
// Also folds the w_out fp32->bf16 cast (2 elems/thread; 8192x512 = 2048^2).
// ---------------------------------------------------------------------------
__global__ __launch_bounds__(256) void rmsnorm_gate(const u16* __restrict__ attn,
                                                    const u16* __restrict__ gate,
                                                    const float* __restrict__ nw,
                                                    u16* __restrict__ y,
                                                    const float* __restrict__ wout,
                                                    u16* __restrict__ wout_bf) {
    const int r = blockIdx.x, tid = threadIdx.x;

    // folded w_out cast: block r covers elements [r*512, r*512+512)
    {
        const size_t wi = (size_t)r * 512 + tid * 2;
        const float2 wf = *(const float2*)&wout[wi];
        *(unsigned*)&wout_bf[wi] = (unsigned)f2bf(wf.x) | ((unsigned)f2bf(wf.y) << 16);
    }

    const size_t base = (size_t)r * HID + tid * 8;
    const uint4 a = *(const uint4*)&attn[base];
    float x[8];
    x[0] = bf2f(a.x & 0xffff); x[1] = bf2f(a.x >> 16);
    x[2] = bf2f(a.y & 0xffff); x[3] = bf2f(a.y >> 16);
    x[4] = bf2f(a.z & 0xffff); x[5] = bf2f(a.z >> 16);
    x[6] = bf2f(a.w & 0xffff); x[7] = bf2f(a.w >> 16);
    float s = 0.f;
    #pragma unroll
    for (int i = 0; i < 8; i++) s += x[i] * x[i];
    #pragma unroll
    for (int off = 32; off > 0; off >>= 1) s += __shfl_down(s, off);
    __shared__ float red[4];
    if ((tid & 63) == 0) red[tid >> 6] = s;
    __syncthreads();
    const float tot = red[0] + red[1] + red[2] + red[3];
    const float sc = rsqrtf(tot * (1.f / 2048.f) + 1e-6f);
    const uint4 g = *(const uint4*)&gate[base];
    float gv[8];
    gv[0] = bf2f(g.x & 0xffff); gv[1] = bf2f(g.x >> 16);
    gv[2] = bf2f(g.y & 0xffff); gv[3] = bf2f(g.y >> 16);
    gv[4] = bf2f(g.z & 0xffff); gv[5] = bf2f(g.z >> 16);
    gv[6] = bf2f(g.w & 0xffff); gv[7] = bf2f(g.w >> 16);
    const float4 w0 = *(const float4*)&nw[tid * 8];
    const float4 w1 = *(const float4*)&nw[tid * 8 + 4];
    const float wv[8] = {w0.x, w0.y, w0.z, w0.w, w1.x, w1.y, w1.z, w1.w};
    u16 o[8];
    #pragma unroll
    for (int i = 0; i < 8; i++) o[i] = f2bf(gv[i] * x[i] * sc * wv[i]);
    uint4 ov;
    ov.x = (unsigned)o[0] | ((unsigned)o[1] << 16);
    ov.y = (unsigned)o[2] | ((unsigned)o[3] << 16);
    ov.z = (unsigned)o[4] | ((unsigned)o[5] << 16);
    ov.w = (unsigned)o[6] | ((unsigned)o[7] << 16);
    *(uint4*)&y[base] = ov;
}

// ---------------------------------------------------------------------------
extern "C" void kernel_launch(void* const* d_in, const int* in_sizes, int n_in,
                              void* d_out, int out_size, void* d_ws, size_t ws_size,
                              hipStream_t stream) {
    const float* hidden = (const float*)d_in[0];
    const float* slope  = (const float*)d_in[1];
    const float* w_qkv  = (const float*)d_in[2];
    const float* w_gate = (const float*)d_in[3];
    const float* w_out  = (const float*)d_in[4];
    const float* norm_w = (const float*)d_in[5];
    float* out = (float*)d_out;

    // 7 slots x 33,554,432 B = 234,881,024 B total
    char* w = (char*)d_ws;
    u16* qb   = (u16*)(w);                 // S0: q                 [QKV .. fused_pv]
    u16* kb   = (u16*)(w +  33554432);     // S1: k                 [QKV .. fused_pv]
    u16* kTs  = (u16*)(w +  67108864);     // S2: (ST / y slot)
    u16* hid_bf = (u16*)(w + 100663296);   // S3: hidden bf16       [cast .. QKV]
    u16* vT   = (u16*)(w + 134217728);     // S4: vT (via QKV)      [QKV .. fused_pv]
    u16* gate = (u16*)(w + 167772160);     // S5: gate (via QKV)    [QKV .. rms]
    u16* wqkv_bf  = (u16*)(w + 201326592); // S6: w_qkv bf16 25.17M [cast .. QKV]
    u16* wgate_bf = (u16*)(w + 201326592 + 25165824); // S6 tail 8.39M, contiguous
    // aliases (disjoint lifetimes):
    float* KVT  = (float*)hid_bf;          // S3: KV^T fp32         [kvt .. scan]
    u16*   ST   = kTs;                     // S2: S^T bf16 16.8M    [scan .. fused_pv]
    u16*   wout_bf = kb;                   // S1: w_out bf16        [rms .. OUT]
    u16*   attn = wqkv_bf;                 // S6: attn              [fused_pv .. rms]
    u16*   y    = kTs;                     // S2: y                 [rms .. OUT]

    static bool s_attr = false;
    if (!s_attr) {
        (void)hipFuncSetAttribute((const void*)gemm256<0>,
                                  hipFuncAttributeMaxDynamicSharedMemorySize, 131072);
        (void)hipFuncSetAttribute((const void*)gemm256<1>,
                                  hipFuncAttributeMaxDynamicSharedMemorySize, 131072);
        s_attr = true;
    }

    // fused casts: hidden | w_qkv | w_gate in one launch
    castk3<<<32768, 256, 0, stream>>>(hidden, hid_bf, w_qkv, wqkv_bf, w_gate, wgate_bf);

    // fused qkv+gate: B = [w_qkv ; w_gate] (8192 x 2048 contiguous)
    gemm256<0><<<dim3(1024), dim3(512), 131072, stream>>>(hid_bf, wqkv_bf, qb, vT, gate);
    kvt_fused       <<<512,             256, 0, stream>>>(vT, kb, KVT, slope);
    scan_kv         <<<512,             256, 0, stream>>>(KVT, ST, slope);
    fused_pv        <<<dim3(2, 1, 512), 256, 0, stream>>>(qb, kb, ST, vT, attn, slope);
    rmsnorm_gate    <<<8192,            256, 0, stream>>>(attn, gate, norm_w, y, w_out, wout_bf);
    gemm256<1><<<dim3(256), dim3(512), 131072, stream>>>(y, wout_bf, (void*)out, nullptr, nullptr);
}

// Round 21
// 428.491 us; speedup vs baseline: 1.0471x; 1.0033x over previous
//
#include <hip/hip_runtime.h>

// ---------------------------------------------------------------------------
// MiniMax-M1 Lightning Attention forward, MI355X / gfx950.
//   0. castk3: fp32->bf16 for hidden + w_qkv + w_gate in ONE launch
//   1. fused qkv+gate via 256x256 lockstep GEMM (R11 rotated-read schedule,
//      COMPILER-SCHEDULED lgkm waits: no explicit lgkmcnt(0) before MFMA --
//      data deps force fine-grained lgkmcnt(N) per m97)
//   2. kvt_fused: KVT_j = vT @ (silu_k*decay)^T (transpose+decay folded)
//   3. scan: S_{j+1} = e^{-256 s} S_j + KV_j ; 16 KV loads prefetched.
//   4+5 FUSED (fused_pv): inter (q@S^T, q_decay) + per-32-kv-chunk P in-reg
//      -> LDS round-trip -> acc += P@v.  BOTH loops double-buffered.
//      jb==0 blocks skip the inter pass entirely (S_0 = 0).
//   6. rmsnorm_gate: y = gate * rmsnorm(attn) * norm_w  (+ folds w_out cast)
//   7. out = y @ w_out^T via same 256 GEMM [fp32 -> d_out]
// Workspace: 7 slots x 33,554,432 B = 234,881,024 B peak.
// ---------------------------------------------------------------------------

typedef unsigned short u16;
typedef __bf16 bf16x8 __attribute__((ext_vector_type(8)));
typedef float f32x4 __attribute__((ext_vector_type(4)));

#define SEQ 4096
#define HID 2048

__device__ __forceinline__ u16 f2bf(float f) {
    union { float f; unsigned u; } v; v.f = f;
    unsigned r = v.u + 0x7fffu + ((v.u >> 16) & 1u);   // round-to-nearest-even
    return (u16)(r >> 16);
}
__device__ __forceinline__ float bf2f(u16 u) {
    union { unsigned u; float f; } v; v.u = ((unsigned)u) << 16; return v.f;
}

// async global->LDS, 16B per lane; lds dest must be wave-uniform base (+lane*16)
typedef __attribute__((address_space(1))) unsigned char gas_u8;
typedef __attribute__((address_space(3))) unsigned char las_u8;
__device__ __forceinline__ void gld16(const void* g, void* l) {
    __builtin_amdgcn_global_load_lds((gas_u8*)g, (las_u8*)l, 16, 0, 0);
}

// ---------------------------------------------------------------------------
// castk3: hidden|w_qkv|w_gate fp32->bf16 in one launch (4 elems/thread).
// ---------------------------------------------------------------------------
__global__ __launch_bounds__(256) void castk3(const float* __restrict__ a, u16* __restrict__ ao,
                                              const float* __restrict__ b, u16* __restrict__ bo,
                                              const float* __restrict__ c, u16* __restrict__ co) {
    const int bid = blockIdx.x;
    const float* src; u16* dst; size_t i;
    if (bid < 16384)      { src = a; dst = ao; i = (size_t)bid * 256 + threadIdx.x; }
    else if (bid < 28672) { src = b; dst = bo; i = (size_t)(bid - 16384) * 256 + threadIdx.x; }
    else                  { src = c; dst = co; i = (size_t)(bid - 28672) * 256 + threadIdx.x; }
    const float4 f = *(const float4*)&src[i * 4];
    uint2 o;
    o.x = (unsigned)f2bf(f.x) | ((unsigned)f2bf(f.y) << 16);
    o.y = (unsigned)f2bf(f.z) | ((unsigned)f2bf(f.w) << 16);
    *(uint2*)&dst[i * 4] = o;
}

// ---------------------------------------------------------------------------
// 256x256-tile lockstep pipelined NT GEMM (R11 rotated-read schedule).
// ds_read->MFMA waits are COMPILER-INSERTED (fine-grained lgkmcnt, m97):
// no explicit lgkmcnt(0) in the K-loop.  vmcnt asm kept for staging
// residency (compiler cannot track global_load_lds -> LDS).
// MODE 0: fused QKV+gate epilogue; MODE 1: f32 out.
// ---------------------------------------------------------------------------
template <int MODE>
__global__ __launch_bounds__(512, 2) void gemm256(const u16* __restrict__ A,
                                                  const u16* __restrict__ Bm,
                                                  void* __restrict__ Cv,
                                                  void* __restrict__ aux,
                                                  void* __restrict__ aux2) {
    constexpr int NTN = (MODE == 0) ? 32 : 8;     // tiles along N
    constexpr int NT  = 32;                       // K tiles (2048 / 64)
    extern __shared__ u16 smem[];                 // [2][A 16384 | B 16384]

    // XCD swizzle: 8 XCDs; per-XCD 4-row x 8-col rectangular supertiles
    const int bid = blockIdx.x;
    const int xcd = bid & 7, l = bid >> 3;
    int tm, tn;
    if constexpr (MODE == 0) {       // 32x32 tile grid, 128 WGs per XCD
        tm = xcd * 4 + (l & 3);
        tn = ((l >> 2) & 7) | ((l >> 5) << 3);
    } else {                         // 32x8 grid, 32 WGs per XCD (4x8 rect)
        const int wgid = xcd * 32 + l;
        tm = wgid / NTN; tn = wgid % NTN;
    }

    const int tid  = threadIdx.x;
    const int lane = tid & 63, wv = tid >> 6;
    const int quad = lane >> 4, cl = lane & 15;
    const int wm = (wv & 1) * 128, wn = (wv >> 1) * 64;

    const int srw  = tid >> 3;
    const int colo = ((tid & 7) ^ (srw & 7)) * 8;
    const u16* gA0 = A  + (size_t)(tm * 256 + srw) * HID + colo;
    const u16* gB0 = Bm + (size_t)(tn * 256 + srw) * HID + colo;

    const int x0 = ((quad       ^ (cl & 7)) * 8);
    const int x1 = (((4 + quad) ^ (cl & 7)) * 8);

    f32x4 acc[8][4];
    const f32x4 zero = {0.f, 0.f, 0.f, 0.f};
    #pragma unroll
    for (int a = 0; a < 8; a++)
        #pragma unroll
        for (int b = 0; b < 4; b++) acc[a][b] = zero;

    bf16x8 af[8], b0[4], b1[4];

    auto STG = [&](int kt, int mat, int hh) {   // stage one 128x64 half-tile
        const u16* g = (mat ? gB0 : gA0) + (size_t)(hh * 128) * HID + kt * 64;
        u16* lp = smem + (kt & 1) * 32768 + mat * 16384 + hh * 8192 + wv * 512;
        gld16(g, lp);
        gld16(g + (size_t)64 * HID, lp + 4096);
    };
    auto LDA = [&](int qm, int ab) {
        #pragma unroll
        for (int mi = 0; mi < 4; mi++) {
            const int rr = (wm + qm * 64 + mi * 16 + cl) * 64 + ab;
            af[mi * 2 + 0] = *(const bf16x8*)&smem[rr + x0];
            af[mi * 2 + 1] = *(const bf16x8*)&smem[rr + x1];
        }
    };
    auto LDB = [&](bf16x8* d, int qn, int bb2) {
        #pragma unroll
        for (int ni = 0; ni < 2; ni++) {
            const int rr = (wn + qn * 32 + ni * 16 + cl) * 64 + bb2;
            d[ni * 2 + 0] = *(const bf16x8*)&smem[rr + x0];
            d[ni * 2 + 1] = *(const bf16x8*)&smem[rr + x1];
        }
    };
    auto MM = [&](int qm, int qn, const bf16x8* bv) {
        #pragma unroll
        for (int mi = 0; mi < 4; mi++)
            #pragma unroll
            for (int ni = 0; ni < 2; ni++) {
                f32x4 c = acc[qm * 4 + mi][qn * 2 + ni];
                c = __builtin_amdgcn_mfma_f32_16x16x32_bf16(af[mi * 2 + 0], bv[ni * 2 + 0], c, 0, 0, 0);
                c = __builtin_amdgcn_mfma_f32_16x16x32_bf16(af[mi * 2 + 1], bv[ni * 2 + 1], c, 0, 0, 0);
                acc[qm * 4 + mi][qn * 2 + ni] = c;
            }
    };

    // prologue: issue stream per tile = B.lo, B.hi, A.lo, A.hi
    STG(0, 1, 0); STG(0, 1, 1); STG(0, 0, 0); STG(0, 0, 1);
    STG(1, 1, 0); STG(1, 1, 1); STG(1, 0, 0);
    asm volatile("s_waitcnt vmcnt(6)" ::: "memory");   // tile 0 resident
    __builtin_amdgcn_s_barrier();
    LDA(0, 0); LDB(b0, 0, 16384);      // ph0 operands (compiler-drained at use)

    #pragma unroll 2
    for (int t = 0; t < NT; ++t) {
        const int ab  = (t & 1) * 32768;
        const int bb2 = ab + 16384;
        const int nab = ((t + 1) & 1) * 32768;
        // phase 0: MM(0,0)=A0*b0 (reads from prev ph3/prologue); read b1
        if (t + 1 < NT) STG(t + 1, 0, 1);
        __builtin_amdgcn_s_barrier();
        __builtin_amdgcn_s_setprio(1); MM(0, 0, b0); __builtin_amdgcn_s_setprio(0);
        LDB(b1, 1, bb2);
        __builtin_amdgcn_s_barrier();
        // phase 1: MM(0,1)=A0*b1; read A1
        if (t + 2 < NT) STG(t + 2, 1, 0);
        __builtin_amdgcn_s_barrier();
        __builtin_amdgcn_s_setprio(1); MM(0, 1, b1); __builtin_amdgcn_s_setprio(0);
        LDA(1, ab);
        __builtin_amdgcn_s_barrier();
        // phase 2: MM(1,1)=A1*b1
        if (t + 2 < NT) STG(t + 2, 1, 1);
        __builtin_amdgcn_s_barrier();
        __builtin_amdgcn_s_setprio(1); MM(1, 1, b1); __builtin_amdgcn_s_setprio(0);
        __builtin_amdgcn_s_barrier();
        // phase 3: MM(1,0)=A1*b0; boundary vmcnt(6); post-MFMA next A0,b0
        if (t + 2 < NT) {
            STG(t + 2, 0, 0);
            asm volatile("s_waitcnt vmcnt(6)" ::: "memory");
        } else {
            asm volatile("s_waitcnt vmcnt(0)" ::: "memory");
        }
        __builtin_amdgcn_s_barrier();
        __builtin_amdgcn_s_setprio(1); MM(1, 0, b0); __builtin_amdgcn_s_setprio(0);
        if (t + 1 < NT) { LDA(0, nab); LDB(b0, 0, nab + 16384); }
        __builtin_amdgcn_s_barrier();
    }

    // epilogue
    if constexpr (MODE == 0) {
        const int grp = tn * 2 + (wn >> 7);
        const int which = grp >> 4, hd = grp & 15;
        const int n64 = wn & 64;
        if (which == 2) {
            const size_t bz = (size_t)((tm >> 4) * 256 + hd * 16 + (tm & 15));
            u16* tdst = (u16*)aux + bz * 32768;
            #pragma unroll
            for (int a = 0; a < 8; a++) {
                const int mm = wm + (a >> 2) * 64 + (a & 3) * 16 + quad * 4;
                #pragma unroll
                for (int b = 0; b < 4; b++) {
                    const int d = n64 + (b >> 1) * 32 + (b & 1) * 16 + cl;
                    u16 p[4];
                    #pragma unroll
                    for (int r = 0; r < 4; r++) {
                        const float x = acc[a][b][r];
                        p[r] = f2bf(x / (1.f + __expf(-x)));
                    }
                    uint2 pk;
                    pk.x = (unsigned)p[0] | ((unsigned)p[1] << 16);
                    pk.y = (unsigned)p[2] | ((unsigned)p[3] << 16);
                    *(uint2*)&tdst[(size_t)d * 256 + mm] = pk;
                }
            }
            return;
        }
        u16* dst = (which == 0) ? (u16*)Cv
                 : (which == 1) ? (u16*)Cv + (size_t)16777216   // k slot (S1)
                                : (u16*)aux2;                   // gate slot
        #pragma unroll
        for (int a = 0; a < 8; a++)
            #pragma unroll
            for (int b = 0; b < 4; b++)
                #pragma unroll
                for (int r = 0; r < 4; r++) {
                    const int m = tm * 256 + wm + (a >> 2) * 64 + (a & 3) * 16 + quad * 4 + r;
                    const int col = hd * 128 + n64 + (b >> 1) * 32 + (b & 1) * 16 + cl;
                    const float x = acc[a][b][r];
                    const float v = (which == 3) ? 1.f / (1.f + __expf(-x))
                                                 : x / (1.f + __expf(-x));
                    dst[(size_t)m * HID + col] = f2bf(v);
                }
        return;
    } else {
        float* C = (float*)Cv;
        #pragma unroll
        for (int a = 0; a < 8; a++)
            #pragma unroll
            for (int b = 0; b < 4; b++)
                #pragma unroll
                for (int r = 0; r < 4; r++) {
                    const int m = tm * 256 + wm + (a >> 2) * 64 + (a & 3) * 16 + quad * 4 + r;
                    const int n = tn * 256 + wn + (b >> 1) * 32 + (b & 1) * 16 + cl;
                    C[(size_t)m * HID + n] = acc[a][b][r];
                }
    }
}

// ---------------------------------------------------------------------------
// kvt_fused: KVT_j[e][d] = sum_m vT[e][m] * silu_k[m][d] * exp(-s*(255-m)).
// ---------------------------------------------------------------------------
__global__ __launch_bounds__(256) void kvt_fused(const u16* __restrict__ vT,
                                                 const u16* __restrict__ kb,
                                                 float* __restrict__ KVT,
                                                 const float* __restrict__ slope) {
    __shared__ u16 smem[16384];           // A dbuf 2x4096 | Braw dbuf 2x4096

    const int tid = threadIdx.x;
    const int bz  = blockIdx.x;
    const int bb = bz >> 8, hh = (bz >> 4) & 15, jb = bz & 15;
    const float s_ = slope[hh];
    const float es = __expf(s_);
    const size_t rowbase = (size_t)(bb * SEQ + jb * 256);

    const int lane = tid & 63, wv = tid >> 6;
    const int wm = (wv & 1) * 64, wn = (wv >> 1) * 64;
    const int quad = lane >> 4, cl = lane & 15;
    const int lr = lane >> 2;
    const int lc = (lane & 3) * 8;
    const int ko = quad * 8;

    f32x4 acc[4][4];
    const f32x4 zero = {0.f, 0.f, 0.f, 0.f};
    #pragma unroll
    for (int mi = 0; mi < 4; mi++)
        #pragma unroll
        for (int ni = 0; ni < 4; ni++) acc[mi][ni] = zero;

    // A: vT rows (e), contraction m; per-wave 32 rows, [row][32 m] layout
    const u16* gA = vT + (size_t)bz * 32768 + (size_t)(wv * 32 + lr) * 256 + lc;
    // B: raw k rows, source pre-swizzled so linear LDS holds slot-XOR layout
    const u16* gK = kb + (rowbase + (tid >> 4)) * HID + hh * 128
                       + (((tid & 15) ^ (tid >> 4)) * 8);

    auto stage = [&](int c, int buf) {    // 4 gld16 per chunk
        u16* lA = smem + buf * 4096 + wv * 1024;
        gld16(gA + c * 32,                    lA);
        gld16(gA + c * 32 + (size_t)16 * 256, lA + 512);
        u16* lB = smem + 8192 + buf * 4096 + wv * 512 + lane * 8;
        gld16(gK + (size_t)(c * 32) * HID,      lB);
        gld16(gK + (size_t)(c * 32 + 16) * HID, lB + 2048);
    };

    stage(0, 0);
    for (int c = 0; c < 8; ++c) {
        const int cb = c & 1;
        if (c + 1 < 8) {
            stage(c + 1, cb ^ 1);
            asm volatile("s_waitcnt vmcnt(4)" ::: "memory");   // chunk c landed
        } else {
            asm volatile("s_waitcnt vmcnt(0)" ::: "memory");
        }
        __builtin_amdgcn_s_barrier();
        const u16* As   = smem + cb * 4096;
        const u16* braw = smem + 8192 + cb * 4096;
        // decay factors for this thread's m-slice (shared across ni)
        const int kv0 = c * 32;
        const float dec0 = __expf(-s_ * (float)(255 - (kv0 + ko)));
        bf16x8 af[4], bfv[4];
        #pragma unroll
        for (int mi = 0; mi < 4; mi++)
            af[mi] = *(const bf16x8*)&As[(wm + mi * 16 + cl) * 32 + ko];
        #pragma unroll
        for (int ni = 0; ni < 4; ni++) {
            const int d   = wn + ni * 16 + cl;
            const int dhi = d >> 3, dlo = d & 7;
            float dec = dec0;
            union { u16 u[8]; bf16x8 v; } cvt;
            #pragma unroll
            for (int j = 0; j < 8; j++) {
                const int ml = ko + j;
                const u16 raw = braw[ml * 128 + ((dhi ^ (ml & 15)) * 8) + dlo];
                cvt.u[j] = f2bf(bf2f(raw) * dec);
                dec *= es;
            }
            bfv[ni] = cvt.v;
        }
        #pragma unroll
        for (int mi = 0; mi < 4; mi++)
            #pragma unroll
            for (int ni = 0; ni < 4; ni++)
                acc[mi][ni] = __builtin_amdgcn_mfma_f32_16x16x32_bf16(af[mi], bfv[ni], acc[mi][ni], 0, 0, 0);
        __builtin_amdgcn_s_barrier();   // WAR: all waves' reads of buf cb done
    }

    #pragma unroll
    for (int mi = 0; mi < 4; mi++)
        #pragma unroll
        for (int ni = 0; ni < 4; ni++)
            #pragma unroll
            for (int r = 0; r < 4; r++) {
                const int m = wm + mi * 16 + quad * 4 + r;
                const int n = wn + ni * 16 + cl;
                KVT[(size_t)bz * 16384 + m * 128 + n] = acc[mi][ni][r];
            }
}

// ---------------------------------------------------------------------------
// FUSED P+INTRA: grid (2,1,512) = (row-half tm, -, bz); 256 thr = 4 waves 2x2.
// BOTH loops double-buffered with counted vmcnt.  jb==0: skip inter (S_0=0).
// ---------------------------------------------------------------------------
__global__ __launch_bounds__(256) void fused_pv(const u16* __restrict__ qb,
                                                const u16* __restrict__ kb,
                                                const u16* __restrict__ ST,
                                                const u16* __restrict__ vT,
                                                u16* __restrict__ attn,
                                                const float* __restrict__ slope) {
    __shared__ u16 smem[36864];   // q 16384 | k 2x4096 | P 4096 | Bs 2x4096
    u16* q_lds = smem;            // [4][128][32]
    u16* k_lds = smem + 16384;    // [2][32][128] row-XOR swizzled
    u16* P_lds = smem + 24576;    // [128][32]
    u16* Bs    = smem + 28672;    // [2][128][32]  (ST chunks / v chunks)

    const int tm = blockIdx.x;           // row half within the 256-block
    const int bz = blockIdx.z;
    const int bb = bz >> 8, hh = (bz >> 4) & 15, jb = bz & 15;
    const float s_ = slope[hh];

    const int tid  = threadIdx.x;
    const int lane = tid & 63, wv = tid >> 6;
    const int quad = lane >> 4, cl = lane & 15;
    const int wm = (wv & 1) * 64, wn = (wv >> 1) * 64;
    const int lr = lane >> 2, lc = (lane & 3) * 8;
    const int pcb = (wv >> 1) * 16;      // P kv-col base for this wave

    const size_t rowbase = (size_t)(bb * SEQ + jb * 256);

    // ---- stage q: 4 ks x 2 gld16 (gemm_nt A-tile pattern, linear) ----
    const u16* gq = qb + (rowbase + tm * 128 + wv * 32 + lr) * HID + hh * 128 + lc;
    u16* lq = q_lds + wv * 1024 + lr * 32 + lc;
    #pragma unroll
    for (int ks = 0; ks < 4; ks++) {
        gld16(gq + ks * 32,                 lq + ks * 4096);
        gld16(gq + ks * 32 + 16 * HID,      lq + ks * 4096 + 512);
    }

    f32x4 acc[4][4];
    const f32x4 zero = {0.f, 0.f, 0.f, 0.f};
    #pragma unroll
    for (int mi = 0; mi < 4; mi++)
        #pragma unroll
        for (int ni = 0; ni < 4; ni++) acc[mi][ni] = zero;

    if (jb != 0) {
        // ---- inter: acc = q @ S^T  (double-buffered ST chunks) ----
        const u16* gS = ST + (size_t)bz * 16384 + (size_t)(wv * 32 + lr) * 128 + lc;
        auto stage_st = [&](int ks, int buf) {       // 2 gld16
            u16* lB = Bs + buf * 4096 + wv * 1024 + lr * 32 + lc;
            gld16(gS + ks * 32,            lB);
            gld16(gS + ks * 32 + 16 * 128, lB + 512);
        };
        stage_st(0, 0);
        #pragma unroll
        for (int ks = 0; ks < 4; ks++) {
            const int sb = ks & 1;
            if (ks + 1 < 4) {
                stage_st(ks + 1, sb ^ 1);
                asm volatile("s_waitcnt vmcnt(2)" ::: "memory");   // q + chunk ks landed
            } else {
                asm volatile("s_waitcnt vmcnt(0)" ::: "memory");
            }
            __builtin_amdgcn_s_barrier();
            bf16x8 af[4], bfv[4];
            #pragma unroll
            for (int mi = 0; mi < 4; mi++)
                af[mi] = *(const bf16x8*)&q_lds[ks * 4096 + (wm + mi * 16 + cl) * 32 + quad * 8];
            #pragma unroll
            for (int ni = 0; ni < 4; ni++)
                bfv[ni] = *(const bf16x8*)&Bs[sb * 4096 + (wn + ni * 16 + cl) * 32 + quad * 8];
            #pragma unroll
            for (int mi = 0; mi < 4; mi++)
                #pragma unroll
                for (int ni = 0; ni < 4; ni++)
                    acc[mi][ni] = __builtin_amdgcn_mfma_f32_16x16x32_bf16(af[mi], bfv[ni], acc[mi][ni], 0, 0, 0);
            __builtin_amdgcn_s_barrier();   // WAR: buf sb reads done before restage
        }
        // q_decay scale
        #pragma unroll
        for (int mi = 0; mi < 4; mi++)
            #pragma unroll
            for (int r = 0; r < 4; r++) {
                const int m = tm * 128 + wm + mi * 16 + quad * 4 + r;
                const float qd = __expf(-s_ * (float)(m + 1));
                #pragma unroll
                for (int ni = 0; ni < 4; ni++) acc[mi][ni][r] *= qd;
            }
    }

    // ---- intra: double-buffered chunk pipeline ----
    const int kmax = (tm == 0) ? 128 : 256;
    const int nc   = kmax >> 5;
    const u16* gV = vT + (size_t)bz * 32768 + (size_t)(wv * 32 + lr) * 256 + lc;
    const int krow = tid >> 4;                       // 0..15 per issue
    const int kcol = (((tid & 15) ^ (krow & 7)) * 8);
    const int kvr = pcb + cl;                        // lane's P kv-row (B-frag)

    auto stage_chunk = [&](int c, int buf) {         // 4 gld16
        u16* lk = k_lds + buf * 4096 + wv * 512 + lane * 8;
        u16* lv = Bs + buf * 4096 + wv * 1024 + lr * 32 + lc;
        const int kv0 = c * 32;
        gld16(kb + (rowbase + kv0 +      krow) * HID + hh * 128 + kcol, lk);
        gld16(kb + (rowbase + kv0 + 16 + krow) * HID + hh * 128 + kcol, lk + 2048);
        gld16(gV + kv0,            lv);
        gld16(gV + kv0 + 16 * 256, lv + 512);
    };

    stage_chunk(0, 0);
    for (int c = 0; c < nc; ++c) {
        const int cb = c & 1;
        if (c + 1 < nc) {
            stage_chunk(c + 1, cb ^ 1);
            asm volatile("s_waitcnt vmcnt(4)" ::: "memory");   // chunk c landed
        } else {
            asm volatile("s_waitcnt vmcnt(0)" ::: "memory");
        }
        __builtin_amdgcn_s_barrier();
        // P-GEMM: C[m(64 rows @wm)][kv(16 cols @pcb)] over d=128
        f32x4 acc2[4];
        #pragma unroll
        for (int mi = 0; mi < 4; mi++) acc2[mi] = zero;
        #pragma unroll
        for (int ds = 0; ds < 4; ds++) {
            bf16x8 bk = *(const bf16x8*)&k_lds[cb * 4096 + kvr * 128 + (((ds * 4 + quad) ^ (kvr & 7)) * 8)];
            #pragma unroll
            for (int mi = 0; mi < 4; mi++) {
                bf16x8 aq = *(const bf16x8*)&q_lds[ds * 4096 + (wm + mi * 16 + cl) * 32 + quad * 8];
                acc2[mi] = __builtin_amdgcn_mfma_f32_16x16x32_bf16(aq, bk, acc2[mi], 0, 0, 0);
            }
        }
        // mask + decay + bf16 -> P_lds[128][32]
        const int kv0 = c * 32;
        #pragma unroll
        for (int mi = 0; mi < 4; mi++)
            #pragma unroll
            for (int r = 0; r < 4; r++) {
                const int row = wm + mi * 16 + quad * 4 + r;
                const int mb  = tm * 128 + row;
                const int kv  = kv0 + pcb + cl;
                const int d   = mb - kv;
                const float x = acc2[mi][r];
                P_lds[row * 32 + pcb + cl] = f2bf(d >= 0 ? x * __expf(-s_ * (float)d) : 0.f);
            }
        asm volatile("s_waitcnt lgkmcnt(0)" ::: "memory");
        __builtin_amdgcn_s_barrier();
        // PV: acc += P @ vT^T
        bf16x8 afp[4], bfv[4];
        #pragma unroll
        for (int mi = 0; mi < 4; mi++)
            afp[mi] = *(const bf16x8*)&P_lds[(wm + mi * 16 + cl) * 32 + quad * 8];
        #pragma unroll
        for (int ni = 0; ni < 4; ni++)
            bfv[ni] = *(const bf16x8*)&Bs[cb * 4096 + (wn + ni * 16 + cl) * 32 + quad * 8];
        #pragma unroll
        for (int mi = 0; mi < 4; mi++)
            #pragma unroll
            for (int ni = 0; ni < 4; ni++)
                acc[mi][ni] = __builtin_amdgcn_mfma_f32_16x16x32_bf16(afp[mi], bfv[ni], acc[mi][ni], 0, 0, 0);
        __builtin_amdgcn_s_barrier();   // WAR: all waves' buf/P reads done
    }

    // ---- epilogue: attn write (verbatim M_INTRA) ----
    #pragma unroll
    for (int mi = 0; mi < 4; mi++)
        #pragma unroll
        for (int ni = 0; ni < 4; ni++)
            #pragma unroll
            for (int r = 0; r < 4; r++) {
                const int m = tm * 128 + wm + mi * 16 + quad * 4 + r;
                const int n = wn + ni * 16 + cl;
                attn[(rowbase + m) * HID + hh * 128 + n] = f2bf(acc[mi][ni][r]);
            }
}

// ---------------------------------------------------------------------------
// S_0 = 0; write S_j^T (bf16); S_{j+1} = e^{-256 s} S_j + KV_j.
// ---------------------------------------------------------------------------
__global__ __launch_bounds__(256) void scan_kv(const float* __restrict__ KVT,
                                               u16* __restrict__ ST,
                                               const float* __restrict__ slope) {
    const int bh = blockIdx.x >> 4, ch = blockIdx.x & 15;
    const int off = ch * 1024 + threadIdx.x * 4;
    const float bd = __expf(-256.f * slope[bh & 15]);
    float4 kv[16];
    #pragma unroll
    for (int j = 0; j < 16; j++)
        kv[j] = *(const float4*)&KVT[((size_t)(bh * 16 + j)) * 16384 + off];
    float4 st = {0.f, 0.f, 0.f, 0.f};
    #pragma unroll
    for (int j = 0; j < 16; j++) {
        const size_t base = ((size_t)(bh * 16 + j)) * 16384 + off;
        uint2 o;
        o.x = (unsigned)f2bf(st.x) | ((unsigned)f2bf(st.y) << 16);
        o.y = (unsigned)f2bf(st.z) | ((unsigned)f2bf(st.w) << 16);
        *(uint2*)&ST[base] = o;
        st.x = bd * st.x + kv[j].x;
        st.y = bd * st.y + kv[j].y;
        st.z = bd * st.z + kv[j].z;
        st.w = bd * st.w + kv[j].w;
    }
}

// ---------------------------------------------------------------------------
// y = gate * (attn * rsqrt(mean(attn^2)+eps)) * norm_w   (one WG per row)
// Also folds the w_out fp32->bf16 cast (2 elems/thread; 8192x512 = 2048^2).
// ---------------------------------------------------------------------------
__global__ __launch_bounds__(256) void rmsnorm_gate(const u16* __restrict__ attn,
                                                    const u16* __restrict__ gate,
                                                    const float* __restrict__ nw,
                                                    u16* __restrict__ y,
                                                    const float* __restrict__ wout,
                                                    u16* __restrict__ wout_bf) {
    const int r = blockIdx.x, tid = threadIdx.x;

    // folded w_out cast: block r covers elements [r*512, r*512+512)
    {
        const size_t wi = (size_t)r * 512 + tid * 2;
        const float2 wf = *(const float2*)&wout[wi];
        *(unsigned*)&wout_bf[wi] = (unsigned)f2bf(wf.x) | ((unsigned)f2bf(wf.y) << 16);
    }

    const size_t base = (size_t)r * HID + tid * 8;
    const uint4 a = *(const uint4*)&attn[base];
    float x[8];
    x[0] = bf2f(a.x & 0xffff); x[1] = bf2f(a.x >> 16);
    x[2] = bf2f(a.y & 0xffff); x[3] = bf2f(a.y >> 16);
    x[4] = bf2f(a.z & 0xffff); x[5] = bf2f(a.z >> 16);
    x[6] = bf2f(a.w & 0xffff); x[7] = bf2f(a.w >> 16);
    float s = 0.f;
    #pragma unroll
    for (int i = 0; i < 8; i++) s += x[i] * x[i];
    #pragma unroll
    for (int off = 32; off > 0; off >>= 1) s += __shfl_down(s, off);
    __shared__ float red[4];
    if ((tid & 63) == 0) red[tid >> 6] = s;
    __syncthreads();
    const float tot = red[0] + red[1] + red[2] + red[3];
    const float sc = rsqrtf(tot * (1.f / 2048.f) + 1e-6f);
    const uint4 g = *(const uint4*)&gate[base];
    float gv[8];
    gv[0] = bf2f(g.x & 0xffff); gv[1] = bf2f(g.x >> 16);
    gv[2] = bf2f(g.y & 0xffff); gv[3] = bf2f(g.y >> 16);
    gv[4] = bf2f(g.z & 0xffff); gv[5] = bf2f(g.z >> 16);
    gv[6] = bf2f(g.w & 0xffff); gv[7] = bf2f(g.w >> 16);
    const float4 w0 = *(const float4*)&nw[tid * 8];
    const float4 w1 = *(const float4*)&nw[tid * 8 + 4];
    const float wv[8] = {w0.x, w0.y, w0.z, w0.w, w1.x, w1.y, w1.z, w1.w};
    u16 o[8];
    #pragma unroll
    for (int i = 0; i < 8; i++) o[i] = f2bf(gv[i] * x[i] * sc * wv[i]);
    uint4 ov;
    ov.x = (unsigned)o[0] | ((unsigned)o[1] << 16);
    ov.y = (unsigned)o[2] | ((unsigned)o[3] << 16);
    ov.z = (unsigned)o[4] | ((unsigned)o[5] << 16);
    ov.w = (unsigned)o[6] | ((unsigned)o[7] << 16);
    *(uint4*)&y[base] = ov;
}

// ---------------------------------------------------------------------------
extern "C" void kernel_launch(void* const* d_in, const int* in_sizes, int n_in,
                              void* d_out, int out_size, void* d_ws, size_t ws_size,
                              hipStream_t stream) {
    const float* hidden = (const float*)d_in[0];
    const float* slope  = (const float*)d_in[1];
    const float* w_qkv  = (const float*)d_in[2];
    const float* w_gate = (const float*)d_in[3];
    const float* w_out  = (const float*)d_in[4];
    const float* norm_w = (const float*)d_in[5];
    float* out = (float*)d_out;

    // 7 slots x 33,554,432 B = 234,881,024 B total
    char* w = (char*)d_ws;
    u16* qb   = (u16*)(w);                 // S0: q                 [QKV .. fused_pv]
    u16* kb   = (u16*)(w +  33554432);     // S1: k                 [QKV .. fused_pv]
    u16* kTs  = (u16*)(w +  67108864);     // S2: (ST / y slot)
    u16* hid_bf = (u16*)(w + 100663296);   // S3: hidden bf16       [cast .. QKV]
    u16* vT   = (u16*)(w + 134217728);     // S4: vT (via QKV)      [QKV .. fused_pv]
    u16* gate = (u16*)(w + 167772160);     // S5: gate (via QKV)    [QKV .. rms]
    u16* wqkv_bf  = (u16*)(w + 201326592); // S6: w_qkv bf16 25.17M [cast .. QKV]
    u16* wgate_bf = (u16*)(w + 201326592 + 25165824); // S6 tail 8.39M, contiguous
    // aliases (disjoint lifetimes):
    float* KVT  = (float*)hid_bf;          // S3: KV^T fp32         [kvt .. scan]
    u16*   ST   = kTs;                     // S2: S^T bf16 16.8M    [scan .. fused_pv]
    u16*   wout_bf = kb;                   // S1: w_out bf16        [rms .. OUT]
    u16*   attn = wqkv_bf;                 // S6: attn              [fused_pv .. rms]
    u16*   y    = kTs;                     // S2: y                 [rms .. OUT]

    static bool s_attr = false;
    if (!s_attr) {
        (void)hipFuncSetAttribute((const void*)gemm256<0>,
                                  hipFuncAttributeMaxDynamicSharedMemorySize, 131072);
        (void)hipFuncSetAttribute((const void*)gemm256<1>,
                                  hipFuncAttributeMaxDynamicSharedMemorySize, 131072);
        s_attr = true;
    }

    // fused casts: hidden | w_qkv | w_gate in one launch
    castk3<<<32768, 256, 0, stream>>>(hidden, hid_bf, w_qkv, wqkv_bf, w_gate, wgate_bf);

    // fused qkv+gate: B = [w_qkv ; w_gate] (8192 x 2048 contiguous)
    gemm256<0><<<dim3(1024), dim3(512), 131072, stream>>>(hid_bf, wqkv_bf, qb, vT, gate);
    kvt_fused       <<<512,             256, 0, stream>>>(vT, kb, KVT, slope);
    scan_kv         <<<512,             256, 0, stream>>>(KVT, ST, slope);
    fused_pv        <<<dim3(2, 1, 512), 256, 0, stream>>>(qb, kb, ST, vT, attn, slope);
    rmsnorm_gate    <<<8192,            256, 0, stream>>>(attn, gate, norm_w, y, w_out, wout_bf);
    gemm256<1><<<dim3(256), dim3(512), 131072, stream>>>(y, wout_bf, (void*)out, nullptr, nullptr);
}